// Round 1
// baseline (3099.452 us; speedup 1.0000x reference)
//
#include <hip/hip_runtime.h>

#define NN 150000
#define EE 600000
#define INC 64
#define HC 128
#define OC 10
#define BSZ 50000

typedef long long ll;

__global__ __launch_bounds__(256) void k_fill1(float* d, int n) {
  int i = blockIdx.x * 256 + threadIdx.x;
  if (i < n) d[i] = 1.0f;
}

__global__ __launch_bounds__(256) void k_count(const int* __restrict__ col, float* deg, int e) {
  int i = blockIdx.x * 256 + threadIdx.x;
  if (i < e) atomicAdd(&deg[col[i]], 1.0f);
}

__global__ __launch_bounds__(256) void k_rsqrt(float* d, int n) {
  int i = blockIdx.x * 256 + threadIdx.x;
  if (i < n) d[i] = rsqrtf(d[i]);
}

// Y[nrows][128] = X[nrows][K] @ W[K][128]
// MODE 1: also Y2 = dis[row]^2 * Y   (self-loop init for GCN aggregation)
// MODE 2: Y = relu(Y + bias)
template<int K, int MODE>
__global__ __launch_bounds__(256) void k_gemm(const float* X, const float* __restrict__ W,
                                              const float* __restrict__ bias,
                                              const float* __restrict__ dis,
                                              float* __restrict__ Y, float* Y2, int nrows) {
  constexpr int KC = 64;
  __shared__ float sX[128][KC + 4];   // stride 68 floats: 16B-aligned rows, conflict-free strided reads
  __shared__ float sW[KC][HC];
  const int t = threadIdx.x;
  const int row0 = blockIdx.x * 128;
  const int rg = t >> 4;    // 0..15 ; rows rg + 16*r
  const int cg = t & 15;    // 0..15 ; cols cg*8 .. cg*8+7
  float acc[8][8];
#pragma unroll
  for (int r = 0; r < 8; ++r)
#pragma unroll
    for (int j = 0; j < 8; ++j) acc[r][j] = 0.f;

  for (int kc = 0; kc < K; kc += KC) {
    __syncthreads();
#pragma unroll
    for (int i = 0; i < 8; ++i) {   // stage X tile: 128 rows x 64 k
      int f = t + i * 256;
      int r = f >> 4;
      int c4 = (f & 15) << 2;
      float4 v = make_float4(0.f, 0.f, 0.f, 0.f);
      if (row0 + r < nrows) v = *(const float4*)(X + (ll)(row0 + r) * K + kc + c4);
      sX[r][c4] = v.x; sX[r][c4 + 1] = v.y; sX[r][c4 + 2] = v.z; sX[r][c4 + 3] = v.w;
    }
#pragma unroll
    for (int i = 0; i < 8; ++i) {   // stage W tile: 64 k x 128 cols
      int f = t + i * 256;
      int r = f >> 5;
      int c4 = (f & 31) << 2;
      *(float4*)&sW[r][c4] = *(const float4*)(W + (ll)(kc + r) * HC + c4);
    }
    __syncthreads();
#pragma unroll
    for (int k4 = 0; k4 < KC / 4; ++k4) {
      float4 xv[8];
#pragma unroll
      for (int r = 0; r < 8; ++r) xv[r] = *(const float4*)&sX[rg + 16 * r][k4 * 4];
#pragma unroll
      for (int kk = 0; kk < 4; ++kk) {
        const int k = k4 * 4 + kk;
        const float4 w0 = *(const float4*)&sW[k][cg * 8];
        const float4 w1 = *(const float4*)&sW[k][cg * 8 + 4];
#pragma unroll
        for (int r = 0; r < 8; ++r) {
          const float xs = (kk == 0) ? xv[r].x : (kk == 1) ? xv[r].y : (kk == 2) ? xv[r].z : xv[r].w;
          acc[r][0] = fmaf(xs, w0.x, acc[r][0]);
          acc[r][1] = fmaf(xs, w0.y, acc[r][1]);
          acc[r][2] = fmaf(xs, w0.z, acc[r][2]);
          acc[r][3] = fmaf(xs, w0.w, acc[r][3]);
          acc[r][4] = fmaf(xs, w1.x, acc[r][4]);
          acc[r][5] = fmaf(xs, w1.y, acc[r][5]);
          acc[r][6] = fmaf(xs, w1.z, acc[r][6]);
          acc[r][7] = fmaf(xs, w1.w, acc[r][7]);
        }
      }
    }
  }

  float4 bv0 = make_float4(0, 0, 0, 0), bv1 = make_float4(0, 0, 0, 0);
  if (MODE == 2) {
    bv0 = *(const float4*)(bias + cg * 8);
    bv1 = *(const float4*)(bias + cg * 8 + 4);
  }
#pragma unroll
  for (int r = 0; r < 8; ++r) {
    const int row = row0 + rg + 16 * r;
    if (row >= nrows) continue;
    float o[8];
#pragma unroll
    for (int j = 0; j < 8; ++j) o[j] = acc[r][j];
    if (MODE == 2) {
      o[0] = fmaxf(o[0] + bv0.x, 0.f); o[1] = fmaxf(o[1] + bv0.y, 0.f);
      o[2] = fmaxf(o[2] + bv0.z, 0.f); o[3] = fmaxf(o[3] + bv0.w, 0.f);
      o[4] = fmaxf(o[4] + bv1.x, 0.f); o[5] = fmaxf(o[5] + bv1.y, 0.f);
      o[6] = fmaxf(o[6] + bv1.z, 0.f); o[7] = fmaxf(o[7] + bv1.w, 0.f);
    }
    float* yp = Y + (ll)row * HC + cg * 8;
    *(float4*)yp       = make_float4(o[0], o[1], o[2], o[3]);
    *(float4*)(yp + 4) = make_float4(o[4], o[5], o[6], o[7]);
    if (MODE == 1) {
      const float dv = dis[row];
      const float d2 = dv * dv;
      float* y2 = Y2 + (ll)row * HC + cg * 8;
      *(float4*)y2       = make_float4(o[0] * d2, o[1] * d2, o[2] * d2, o[3] * d2);
      *(float4*)(y2 + 4) = make_float4(o[4] * d2, o[5] * d2, o[6] * d2, o[7] * d2);
    }
  }
}

// out[col[e]] += dis[row[e]]*dis[col[e]] * xw[row[e]]  (32 threads/edge, float4 each)
__global__ __launch_bounds__(256) void k_scatter(const float* __restrict__ xw,
                                                 const int* __restrict__ ei,
                                                 const float* __restrict__ dis,
                                                 float* out, int e) {
  int tid = blockIdx.x * 256 + threadIdx.x;
  int eidx = tid >> 5;
  int c = (tid & 31) << 2;
  if (eidx >= e) return;
  int r = ei[eidx];
  int cl = ei[EE + eidx];
  float nrm = dis[r] * dis[cl];
  float4 v = *(const float4*)(xw + (ll)r * HC + c);
  float* o = out + (ll)cl * HC + c;
  atomicAdd(o + 0, nrm * v.x);
  atomicAdd(o + 1, nrm * v.y);
  atomicAdd(o + 2, nrm * v.z);
  atomicAdd(o + 3, nrm * v.w);
}

__global__ __launch_bounds__(256) void k_bias_relu(float* h, const float* __restrict__ b, int n4) {
  int i = blockIdx.x * 256 + threadIdx.x;
  if (i >= n4) return;
  float4 v = *(float4*)(h + (ll)i * 4);
  int c = (i * 4) & 127;
  v.x = fmaxf(v.x + b[c], 0.f);
  v.y = fmaxf(v.y + b[c + 1], 0.f);
  v.z = fmaxf(v.z + b[c + 2], 0.f);
  v.w = fmaxf(v.w + b[c + 3], 0.f);
  *(float4*)(h + (ll)i * 4) = v;
}

// per row (wave): z2 = z @ Wc2 + bc2 ; out = log_softmax(z2)
__global__ __launch_bounds__(256) void k_head(const float* __restrict__ Z,
                                              const float* __restrict__ Wc2,
                                              const float* __restrict__ bc2,
                                              float* __restrict__ out, int nrows) {
  __shared__ float sW[HC * OC];
  __shared__ float sB[OC];
  for (int i = threadIdx.x; i < HC * OC; i += 256) sW[i] = Wc2[i];
  if (threadIdx.x < OC) sB[threadIdx.x] = bc2[threadIdx.x];
  __syncthreads();
  const int wid = threadIdx.x >> 6;
  const int lane = threadIdx.x & 63;
  const int row = blockIdx.x * 4 + wid;
  if (row >= nrows) return;
  const float z0 = Z[(ll)row * HC + lane];
  const float z1 = Z[(ll)row * HC + 64 + lane];
  float a[OC];
#pragma unroll
  for (int o = 0; o < OC; ++o)
    a[o] = z0 * sW[lane * OC + o] + z1 * sW[(lane + 64) * OC + o];
#pragma unroll
  for (int o = 0; o < OC; ++o)
#pragma unroll
    for (int m = 32; m; m >>= 1) a[o] += __shfl_xor(a[o], m, 64);
  float mx = -1e30f;
#pragma unroll
  for (int o = 0; o < OC; ++o) { a[o] += sB[o]; mx = fmaxf(mx, a[o]); }
  float s = 0.f;
#pragma unroll
  for (int o = 0; o < OC; ++o) s += expf(a[o] - mx);
  const float lse = mx + logf(s);
  float v = 0.f;
#pragma unroll
  for (int o = 0; o < OC; ++o) v = (lane == o) ? a[o] - lse : v;
  if (lane < OC) out[(ll)row * OC + lane] = v;
}

extern "C" void kernel_launch(void* const* d_in, const int* in_sizes, int n_in,
                              void* d_out, int out_size, void* d_ws, size_t ws_size,
                              hipStream_t stream) {
  const float* x   = (const float*)d_in[0];
  const int*   ei  = (const int*)d_in[1];   // [2][E] int32
  const float* W1  = (const float*)d_in[2];
  const float* b1  = (const float*)d_in[3];
  const float* W2  = (const float*)d_in[4];
  const float* b2  = (const float*)d_in[5];
  const float* Wc1 = (const float*)d_in[6];
  const float* bc1 = (const float*)d_in[7];
  const float* Wc2 = (const float*)d_in[8];
  const float* bc2 = (const float*)d_in[9];
  float* out = (float*)d_out;

  char* ws = (char*)d_ws;
  float* bufA = (float*)(ws);                    // xw scratch [N][128]  76.8 MB
  float* bufB = (float*)(ws + 76800000LL);       // agg / h    [N][128]  76.8 MB
  float* bufC = (float*)(ws + 153600000LL);      // z          [BSZ][128] 25.6 MB
  float* dis  = (float*)(ws + 179200000LL);      // [N]

  // degree -> dis = rsqrt(deg)
  k_fill1<<<(NN + 255) / 256, 256, 0, stream>>>(dis, NN);
  k_count<<<(EE + 255) / 256, 256, 0, stream>>>(ei + EE, dis, EE);
  k_rsqrt<<<(NN + 255) / 256, 256, 0, stream>>>(dis, NN);

  // layer 1: xw1 = x@W1 -> bufA ; bufB = dis^2*xw1 ; scatter ; relu(+b1)
  k_gemm<INC, 1><<<(NN + 127) / 128, 256, 0, stream>>>(x, W1, nullptr, dis, bufA, bufB, NN);
  k_scatter<<<EE * 32 / 256, 256, 0, stream>>>(bufA, ei, dis, bufB, EE);
  k_bias_relu<<<NN * HC / 4 / 256, 256, 0, stream>>>(bufB, b1, NN * HC / 4);

  // layer 2 (bufB in: h1; bufA out: xw2; self-loop back into bufB in-place per-block safe)
  k_gemm<HC, 1><<<(NN + 127) / 128, 256, 0, stream>>>(bufB, W2, nullptr, dis, bufA, bufB, NN);
  k_scatter<<<EE * 32 / 256, 256, 0, stream>>>(bufA, ei, dis, bufB, EE);
  k_bias_relu<<<NN * HC / 4 / 256, 256, 0, stream>>>(bufB, b2, NN * HC / 4);

  // classifier: z = relu(flat@Wc1 + bc1), flat = bufB viewed [BSZ][384]
  k_gemm<HC * 3, 2><<<(BSZ + 127) / 128, 256, 0, stream>>>(bufB, Wc1, bc1, nullptr, bufC, nullptr, BSZ);
  k_head<<<BSZ / 4, 256, 0, stream>>>(bufC, Wc2, bc2, out, BSZ);
}

// Round 2
// 1147.191 us; speedup vs baseline: 2.7018x; 2.7018x over previous
//
#include <hip/hip_runtime.h>

#define NN 150000
#define EE 600000
#define INC 64
#define HC 128
#define OC 10
#define BSZ 50000

typedef long long ll;

// ---------- CSR build ----------

__global__ __launch_bounds__(256) void k_zero_i(int* d, int n) {
  int i = blockIdx.x * 256 + threadIdx.x;
  if (i < n) d[i] = 0;
}

__global__ __launch_bounds__(256) void k_count(const int* __restrict__ col, int* cnt, int e) {
  int i = blockIdx.x * 256 + threadIdx.x;
  if (i < e) atomicAdd(&cnt[col[i]], 1);
}

__global__ __launch_bounds__(256) void k_dis(const int* __restrict__ cnt, float* dis, int n) {
  int i = blockIdx.x * 256 + threadIdx.x;
  if (i < n) dis[i] = rsqrtf((float)(1 + cnt[i]));
}

// exclusive scan, 1024 elems/block (256 thr x 4)
__global__ __launch_bounds__(256) void k_scan1(const int* __restrict__ cnt, int* ex, int* bsum, int n) {
  __shared__ int s[256];
  const int t = threadIdx.x;
  const int base = blockIdx.x * 1024 + t * 4;
  int v[4], tot = 0;
#pragma unroll
  for (int i = 0; i < 4; ++i) { v[i] = (base + i < n) ? cnt[base + i] : 0; tot += v[i]; }
  s[t] = tot;
  __syncthreads();
#pragma unroll
  for (int off = 1; off < 256; off <<= 1) {
    int x = (t >= off) ? s[t - off] : 0;
    __syncthreads();
    s[t] += x;
    __syncthreads();
  }
  int run = s[t] - tot;
#pragma unroll
  for (int i = 0; i < 4; ++i) {
    if (base + i < n) ex[base + i] = run;
    run += v[i];
  }
  if (t == 255) bsum[blockIdx.x] = s[255];
}

__global__ __launch_bounds__(256) void k_scan2(int* bsum, int nb) {
  __shared__ int s[256];
  const int t = threadIdx.x;
  int v = (t < nb) ? bsum[t] : 0;
  s[t] = v;
  __syncthreads();
#pragma unroll
  for (int off = 1; off < 256; off <<= 1) {
    int x = (t >= off) ? s[t - off] : 0;
    __syncthreads();
    s[t] += x;
    __syncthreads();
  }
  if (t < nb) bsum[t] = s[t] - v;
}

__global__ __launch_bounds__(256) void k_scan3(int* rp, const int* __restrict__ bsum, int n, int e) {
  const int base = blockIdx.x * 1024 + threadIdx.x * 4;
  const int off = bsum[blockIdx.x];
#pragma unroll
  for (int i = 0; i < 4; ++i)
    if (base + i < n) rp[base + i] += off;
  if (blockIdx.x == 0 && threadIdx.x == 0) rp[n] = e;
}

__global__ __launch_bounds__(256) void k_fill_csr(const int* __restrict__ ei,
                                                  const int* __restrict__ rp,
                                                  int* fill, int* csr, int e) {
  int i = blockIdx.x * 256 + threadIdx.x;
  if (i >= e) return;
  int r = ei[i];
  int c = ei[EE + i];
  int slot = rp[c] + atomicAdd(&fill[c], 1);
  csr[slot] = r;
}

// ---------- GEMM: Y[nrows][128] = X[nrows][K] @ W[K][128] ----------
// MODE 0: plain ; MODE 2: Y = relu(Y + bias)
template<int K, int MODE>
__global__ __launch_bounds__(256) void k_gemm(const float* X, const float* __restrict__ W,
                                              const float* __restrict__ bias,
                                              float* __restrict__ Y, int nrows) {
  constexpr int KC = 64;
  __shared__ float sX[128][KC + 4];
  __shared__ float sW[KC][HC];
  const int t = threadIdx.x;
  const int row0 = blockIdx.x * 128;
  const int rg = t >> 4;
  const int cg = t & 15;
  float acc[8][8];
#pragma unroll
  for (int r = 0; r < 8; ++r)
#pragma unroll
    for (int j = 0; j < 8; ++j) acc[r][j] = 0.f;

  for (int kc = 0; kc < K; kc += KC) {
    __syncthreads();
#pragma unroll
    for (int i = 0; i < 8; ++i) {
      int f = t + i * 256;
      int r = f >> 4;
      int c4 = (f & 15) << 2;
      float4 v = make_float4(0.f, 0.f, 0.f, 0.f);
      if (row0 + r < nrows) v = *(const float4*)(X + (ll)(row0 + r) * K + kc + c4);
      sX[r][c4] = v.x; sX[r][c4 + 1] = v.y; sX[r][c4 + 2] = v.z; sX[r][c4 + 3] = v.w;
    }
#pragma unroll
    for (int i = 0; i < 8; ++i) {
      int f = t + i * 256;
      int r = f >> 5;
      int c4 = (f & 31) << 2;
      *(float4*)&sW[r][c4] = *(const float4*)(W + (ll)(kc + r) * HC + c4);
    }
    __syncthreads();
#pragma unroll
    for (int k4 = 0; k4 < KC / 4; ++k4) {
      float4 xv[8];
#pragma unroll
      for (int r = 0; r < 8; ++r) xv[r] = *(const float4*)&sX[rg + 16 * r][k4 * 4];
#pragma unroll
      for (int kk = 0; kk < 4; ++kk) {
        const int k = k4 * 4 + kk;
        const float4 w0 = *(const float4*)&sW[k][cg * 8];
        const float4 w1 = *(const float4*)&sW[k][cg * 8 + 4];
#pragma unroll
        for (int r = 0; r < 8; ++r) {
          const float xs = (kk == 0) ? xv[r].x : (kk == 1) ? xv[r].y : (kk == 2) ? xv[r].z : xv[r].w;
          acc[r][0] = fmaf(xs, w0.x, acc[r][0]);
          acc[r][1] = fmaf(xs, w0.y, acc[r][1]);
          acc[r][2] = fmaf(xs, w0.z, acc[r][2]);
          acc[r][3] = fmaf(xs, w0.w, acc[r][3]);
          acc[r][4] = fmaf(xs, w1.x, acc[r][4]);
          acc[r][5] = fmaf(xs, w1.y, acc[r][5]);
          acc[r][6] = fmaf(xs, w1.z, acc[r][6]);
          acc[r][7] = fmaf(xs, w1.w, acc[r][7]);
        }
      }
    }
  }

  float4 bv0 = make_float4(0, 0, 0, 0), bv1 = make_float4(0, 0, 0, 0);
  if (MODE == 2) {
    bv0 = *(const float4*)(bias + cg * 8);
    bv1 = *(const float4*)(bias + cg * 8 + 4);
  }
#pragma unroll
  for (int r = 0; r < 8; ++r) {
    const int row = row0 + rg + 16 * r;
    if (row >= nrows) continue;
    float o[8];
#pragma unroll
    for (int j = 0; j < 8; ++j) o[j] = acc[r][j];
    if (MODE == 2) {
      o[0] = fmaxf(o[0] + bv0.x, 0.f); o[1] = fmaxf(o[1] + bv0.y, 0.f);
      o[2] = fmaxf(o[2] + bv0.z, 0.f); o[3] = fmaxf(o[3] + bv0.w, 0.f);
      o[4] = fmaxf(o[4] + bv1.x, 0.f); o[5] = fmaxf(o[5] + bv1.y, 0.f);
      o[6] = fmaxf(o[6] + bv1.z, 0.f); o[7] = fmaxf(o[7] + bv1.w, 0.f);
    }
    float* yp = Y + (ll)row * HC + cg * 8;
    *(float4*)yp       = make_float4(o[0], o[1], o[2], o[3]);
    *(float4*)(yp + 4) = make_float4(o[4], o[5], o[6], o[7]);
  }
}

// ---------- gather aggregation: one wave per dest node ----------
// out[c] = relu( bias + dis[c]^2*xw[c] + sum_e dis[src]*dis[c]*xw[src] )
__global__ __launch_bounds__(256) void k_gather(const float* __restrict__ xw,
                                                const int* __restrict__ csr,
                                                const int* __restrict__ rp,
                                                const float* __restrict__ dis,
                                                const float* __restrict__ bias,
                                                float* __restrict__ out, int n) {
  const int wid = blockIdx.x * 4 + (threadIdx.x >> 6);
  const int lane = threadIdx.x & 63;
  if (wid >= n) return;
  const int s = rp[wid], e = rp[wid + 1];
  const float dc = dis[wid];
  float2 acc = ((const float2*)(xw + (ll)wid * HC))[lane];
  acc.x *= dc * dc;
  acc.y *= dc * dc;
  for (int j = s; j < e; ++j) {
    const int r = csr[j];
    const float nrm = dis[r] * dc;
    const float2 v = ((const float2*)(xw + (ll)r * HC))[lane];
    acc.x = fmaf(nrm, v.x, acc.x);
    acc.y = fmaf(nrm, v.y, acc.y);
  }
  const float2 b = ((const float2*)bias)[lane];
  acc.x = fmaxf(acc.x + b.x, 0.f);
  acc.y = fmaxf(acc.y + b.y, 0.f);
  ((float2*)(out + (ll)wid * HC))[lane] = acc;
}

// ---------- head: z @ Wc2 + bc2 -> log_softmax ----------
__global__ __launch_bounds__(256) void k_head(const float* __restrict__ Z,
                                              const float* __restrict__ Wc2,
                                              const float* __restrict__ bc2,
                                              float* __restrict__ out, int nrows) {
  __shared__ float sW[HC * OC];
  __shared__ float sB[OC];
  for (int i = threadIdx.x; i < HC * OC; i += 256) sW[i] = Wc2[i];
  if (threadIdx.x < OC) sB[threadIdx.x] = bc2[threadIdx.x];
  __syncthreads();
  const int wid = threadIdx.x >> 6;
  const int lane = threadIdx.x & 63;
  const int row = blockIdx.x * 4 + wid;
  if (row >= nrows) return;
  const float z0 = Z[(ll)row * HC + lane];
  const float z1 = Z[(ll)row * HC + 64 + lane];
  float a[OC];
#pragma unroll
  for (int o = 0; o < OC; ++o)
    a[o] = z0 * sW[lane * OC + o] + z1 * sW[(lane + 64) * OC + o];
#pragma unroll
  for (int o = 0; o < OC; ++o)
#pragma unroll
    for (int m = 32; m; m >>= 1) a[o] += __shfl_xor(a[o], m, 64);
  float mx = -1e30f;
#pragma unroll
  for (int o = 0; o < OC; ++o) { a[o] += sB[o]; mx = fmaxf(mx, a[o]); }
  float s = 0.f;
#pragma unroll
  for (int o = 0; o < OC; ++o) s += expf(a[o] - mx);
  const float lse = mx + logf(s);
  float v = 0.f;
#pragma unroll
  for (int o = 0; o < OC; ++o) v = (lane == o) ? a[o] - lse : v;
  if (lane < OC) out[(ll)row * OC + lane] = v;
}

extern "C" void kernel_launch(void* const* d_in, const int* in_sizes, int n_in,
                              void* d_out, int out_size, void* d_ws, size_t ws_size,
                              hipStream_t stream) {
  const float* x   = (const float*)d_in[0];
  const int*   ei  = (const int*)d_in[1];   // [2][E] int32
  const float* W1  = (const float*)d_in[2];
  const float* b1  = (const float*)d_in[3];
  const float* W2  = (const float*)d_in[4];
  const float* b2  = (const float*)d_in[5];
  const float* Wc1 = (const float*)d_in[6];
  const float* bc1 = (const float*)d_in[7];
  const float* Wc2 = (const float*)d_in[8];
  const float* bc2 = (const float*)d_in[9];
  float* out = (float*)d_out;

  char* ws = (char*)d_ws;
  float* bufA = (float*)(ws);                 // xw scratch [N][128]  76.8 MB
  float* bufB = (float*)(ws + 76800000LL);    // h          [N][128]  76.8 MB
  float* bufC = (float*)(ws + 153600000LL);   // z [BSZ][128] 25.6 MB (reused below pre-head)
  // CSR scratch aliased into bufC region (dead until the head GEMM):
  float* dis  = (float*)(ws + 153600000LL);              // N floats
  int*   rp   = (int*)  (ws + 153600000LL + 600064LL);   // N+1 ints
  int*   csr  = (int*)  (ws + 153600000LL + 1200128LL);  // E ints
  int*   cnt  = (int*)  (ws + 153600000LL + 3600128LL);  // N ints
  int*   fill = (int*)  (ws + 153600000LL + 4200192LL);  // N ints
  int*   bsum = (int*)  (ws + 153600000LL + 4800256LL);  // 256 ints

  const int nb = (NN + 1023) / 1024;  // 147 scan blocks

  // CSR build (cnt+fill contiguous -> one zero pass)
  k_zero_i<<<(2 * 150016 + 255) / 256, 256, 0, stream>>>(cnt, 2 * 150016);
  k_count<<<(EE + 255) / 256, 256, 0, stream>>>(ei + EE, cnt, EE);
  k_dis<<<(NN + 255) / 256, 256, 0, stream>>>(cnt, dis, NN);
  k_scan1<<<nb, 256, 0, stream>>>(cnt, rp, bsum, NN);
  k_scan2<<<1, 256, 0, stream>>>(bsum, nb);
  k_scan3<<<nb, 256, 0, stream>>>(rp, bsum, NN, EE);
  k_fill_csr<<<(EE + 255) / 256, 256, 0, stream>>>(ei, rp, fill, csr, EE);

  // layer 1
  k_gemm<INC, 0><<<(NN + 127) / 128, 256, 0, stream>>>(x, W1, nullptr, bufA, NN);
  k_gather<<<(NN + 3) / 4, 256, 0, stream>>>(bufA, csr, rp, dis, b1, bufB, NN);

  // layer 2
  k_gemm<HC, 0><<<(NN + 127) / 128, 256, 0, stream>>>(bufB, W2, nullptr, bufA, NN);
  k_gather<<<(NN + 3) / 4, 256, 0, stream>>>(bufA, csr, rp, dis, b2, bufB, NN);

  // classifier: z = relu(flat@Wc1 + bc1), flat = bufB viewed [BSZ][384]
  k_gemm<HC * 3, 2><<<(BSZ + 127) / 128, 256, 0, stream>>>(bufB, Wc1, bc1, bufC, BSZ);
  k_head<<<BSZ / 4, 256, 0, stream>>>(bufC, Wc2, bc2, out, BSZ);
}

// Round 3
// 382.097 us; speedup vs baseline: 8.1117x; 3.0024x over previous
//
#include <hip/hip_runtime.h>

#define NN 150000
#define EE 600000
#define INC 64
#define HC 128
#define OC 10
#define BSZ 50000

typedef long long ll;
typedef __attribute__((ext_vector_type(8))) short short8v;
typedef __attribute__((ext_vector_type(4))) float f32x4;

__device__ __forceinline__ ushort f2bf(float f) {
  uint u = __float_as_uint(f);
  uint r = (u + 0x7fffu + ((u >> 16) & 1u)) >> 16;
  return (ushort)r;
}
__device__ __forceinline__ float bf2f(ushort h) {
  return __uint_as_float(((uint)h) << 16);
}

// ---------- CSR build ----------

__global__ __launch_bounds__(256) void k_zero_i(int* d, int n) {
  int i = blockIdx.x * 256 + threadIdx.x;
  if (i < n) d[i] = 0;
}

__global__ __launch_bounds__(256) void k_count(const int* __restrict__ col, int* cnt, int e) {
  int i = blockIdx.x * 256 + threadIdx.x;
  if (i < e) atomicAdd(&cnt[col[i]], 1);
}

__global__ __launch_bounds__(256) void k_dis(const int* __restrict__ cnt, float* dis, int n) {
  int i = blockIdx.x * 256 + threadIdx.x;
  if (i < n) dis[i] = rsqrtf((float)(1 + cnt[i]));
}

__global__ __launch_bounds__(256) void k_scan1(const int* __restrict__ cnt, int* ex, int* bsum, int n) {
  __shared__ int s[256];
  const int t = threadIdx.x;
  const int base = blockIdx.x * 1024 + t * 4;
  int v[4], tot = 0;
#pragma unroll
  for (int i = 0; i < 4; ++i) { v[i] = (base + i < n) ? cnt[base + i] : 0; tot += v[i]; }
  s[t] = tot;
  __syncthreads();
#pragma unroll
  for (int off = 1; off < 256; off <<= 1) {
    int x = (t >= off) ? s[t - off] : 0;
    __syncthreads();
    s[t] += x;
    __syncthreads();
  }
  int run = s[t] - tot;
#pragma unroll
  for (int i = 0; i < 4; ++i) {
    if (base + i < n) ex[base + i] = run;
    run += v[i];
  }
  if (t == 255) bsum[blockIdx.x] = s[255];
}

__global__ __launch_bounds__(256) void k_scan2(int* bsum, int nb) {
  __shared__ int s[256];
  const int t = threadIdx.x;
  int v = (t < nb) ? bsum[t] : 0;
  s[t] = v;
  __syncthreads();
#pragma unroll
  for (int off = 1; off < 256; off <<= 1) {
    int x = (t >= off) ? s[t - off] : 0;
    __syncthreads();
    s[t] += x;
    __syncthreads();
  }
  if (t < nb) bsum[t] = s[t] - v;
}

__global__ __launch_bounds__(256) void k_scan3(int* rp, const int* __restrict__ bsum, int n, int e) {
  const int base = blockIdx.x * 1024 + threadIdx.x * 4;
  const int off = bsum[blockIdx.x];
#pragma unroll
  for (int i = 0; i < 4; ++i)
    if (base + i < n) rp[base + i] += off;
  if (blockIdx.x == 0 && threadIdx.x == 0) rp[n] = e;
}

__global__ __launch_bounds__(256) void k_fill_csr(const int* __restrict__ ei,
                                                  const int* __restrict__ rp,
                                                  int* fill, int* csr, int e) {
  int i = blockIdx.x * 256 + threadIdx.x;
  if (i >= e) return;
  int r = ei[i];
  int c = ei[EE + i];
  int slot = rp[c] + atomicAdd(&fill[c], 1);
  csr[slot] = r;
}

// ---------- weight prep: W[K][128] -> Wt_hi/Wt_lo[col][K] (bf16 split, transposed) ----------
__global__ __launch_bounds__(256) void k_wprep(const float* __restrict__ W,
                                               ushort* __restrict__ th, ushort* __restrict__ tl, int K) {
  int t = blockIdx.x * 256 + threadIdx.x;
  if (t >= K * 128) return;
  int col = t & 127;
  int k = t >> 7;
  float v = W[(ll)k * 128 + col];
  ushort h = f2bf(v);
  th[(ll)col * K + k] = h;
  tl[(ll)col * K + k] = f2bf(v - bf2f(h));
}

// ---------- MFMA GEMM: Y[nrows][128] = X[nrows][K] @ W[K][128] ----------
// split-bf16: C = Ah*Bh + Ah*Bl + Al*Bh  (fp32 accumulate)
// ASRC 0: X fp32, split in-register. ASRC 1: X given as bf16 hi/lo arrays.
// MODE 0: write fp32 Y. MODE 2: Y = relu(Y + bias).
template<int K, int ASRC, int MODE>
__global__ __launch_bounds__(256) void k_gemm(const float* __restrict__ Xf,
                                              const ushort* __restrict__ Xh,
                                              const ushort* __restrict__ Xl,
                                              const ushort* __restrict__ Wth,
                                              const ushort* __restrict__ Wtl,
                                              const float* __restrict__ bias,
                                              float* __restrict__ Y, int nrows) {
  __shared__ ushort sAh[128][40];  // [row][k], stride 40 (80B) -> 2-way conflicts only
  __shared__ ushort sAl[128][40];
  __shared__ ushort sBh[128][40];  // [col][k]
  __shared__ ushort sBl[128][40];
  const int t = threadIdx.x;
  const int lane = t & 63;
  const int wid = t >> 6;
  const int wr = wid >> 1, wc = wid & 1;
  const int row0 = blockIdx.x * 128;

  f32x4 acc[4][4];
#pragma unroll
  for (int m = 0; m < 4; ++m)
#pragma unroll
    for (int n = 0; n < 4; ++n) acc[m][n] = (f32x4){0.f, 0.f, 0.f, 0.f};

  const int srow = t >> 1;        // staging row/col 0..127
  const int shalf = t & 1;        // k half: 0 or 1 (16 elems each)

  for (int kc = 0; kc < K; kc += 32) {
    __syncthreads();
    // ---- stage A tile (128 rows x 32 k) ----
    if (ASRC == 0) {
      float f[16];
      const ll rg = row0 + srow;
      if (rg < nrows) {
        const float4* p = (const float4*)(Xf + rg * K + kc + shalf * 16);
#pragma unroll
        for (int i = 0; i < 4; ++i) {
          float4 v = p[i];
          f[i * 4] = v.x; f[i * 4 + 1] = v.y; f[i * 4 + 2] = v.z; f[i * 4 + 3] = v.w;
        }
      } else {
#pragma unroll
        for (int i = 0; i < 16; ++i) f[i] = 0.f;
      }
      union { ushort u[16]; short8v v[2]; } hu, lu;
#pragma unroll
      for (int i = 0; i < 16; ++i) {
        ushort h = f2bf(f[i]);
        hu.u[i] = h;
        lu.u[i] = f2bf(f[i] - bf2f(h));
      }
      *(short8v*)&sAh[srow][shalf * 16] = hu.v[0];
      *(short8v*)&sAh[srow][shalf * 16 + 8] = hu.v[1];
      *(short8v*)&sAl[srow][shalf * 16] = lu.v[0];
      *(short8v*)&sAl[srow][shalf * 16 + 8] = lu.v[1];
    } else {
      short8v h0 = {0,0,0,0,0,0,0,0}, h1 = h0, l0 = h0, l1 = h0;
      const ll rg = row0 + srow;
      if (rg < nrows) {
        const short8v* ph = (const short8v*)(Xh + rg * K + kc + shalf * 16);
        const short8v* pl = (const short8v*)(Xl + rg * K + kc + shalf * 16);
        h0 = ph[0]; h1 = ph[1];
        l0 = pl[0]; l1 = pl[1];
      }
      *(short8v*)&sAh[srow][shalf * 16] = h0;
      *(short8v*)&sAh[srow][shalf * 16 + 8] = h1;
      *(short8v*)&sAl[srow][shalf * 16] = l0;
      *(short8v*)&sAl[srow][shalf * 16 + 8] = l1;
    }
    // ---- stage B tile (128 cols x 32 k) from pre-split transposed weights ----
    {
      const short8v* ph = (const short8v*)(Wth + (ll)srow * K + kc + shalf * 16);
      const short8v* pl = (const short8v*)(Wtl + (ll)srow * K + kc + shalf * 16);
      short8v h0 = ph[0], h1 = ph[1], l0 = pl[0], l1 = pl[1];
      *(short8v*)&sBh[srow][shalf * 16] = h0;
      *(short8v*)&sBh[srow][shalf * 16 + 8] = h1;
      *(short8v*)&sBl[srow][shalf * 16] = l0;
      *(short8v*)&sBl[srow][shalf * 16 + 8] = l1;
    }
    __syncthreads();
    // ---- fragments + MFMA ----
    const int kq = (lane >> 4) * 8;   // k-offset for this lane group
    const int fr = lane & 15;
    short8v ah[4], al[4], bh[4], bl[4];
#pragma unroll
    for (int m = 0; m < 4; ++m) {
      const int r = wr * 64 + m * 16 + fr;
      ah[m] = *(const short8v*)&sAh[r][kq];
      al[m] = *(const short8v*)&sAl[r][kq];
    }
#pragma unroll
    for (int n = 0; n < 4; ++n) {
      const int c = wc * 64 + n * 16 + fr;
      bh[n] = *(const short8v*)&sBh[c][kq];
      bl[n] = *(const short8v*)&sBl[c][kq];
    }
#pragma unroll
    for (int m = 0; m < 4; ++m)
#pragma unroll
      for (int n = 0; n < 4; ++n) {
        acc[m][n] = __builtin_amdgcn_mfma_f32_16x16x32_bf16(ah[m], bh[n], acc[m][n], 0, 0, 0);
        acc[m][n] = __builtin_amdgcn_mfma_f32_16x16x32_bf16(ah[m], bl[n], acc[m][n], 0, 0, 0);
        acc[m][n] = __builtin_amdgcn_mfma_f32_16x16x32_bf16(al[m], bh[n], acc[m][n], 0, 0, 0);
      }
  }

  // ---- write out: D row=(lane>>4)*4+q, col=lane&15 within each 16x16 frag ----
#pragma unroll
  for (int m = 0; m < 4; ++m)
#pragma unroll
    for (int q = 0; q < 4; ++q) {
      const int rl = wr * 64 + m * 16 + (lane >> 4) * 4 + q;
      const ll rg = row0 + rl;
      if (rg >= nrows) continue;
#pragma unroll
      for (int n = 0; n < 4; ++n) {
        const int col = wc * 64 + n * 16 + (lane & 15);
        float v = acc[m][n][q];
        if (MODE == 2) v = fmaxf(v + bias[col], 0.f);
        Y[rg * HC + col] = v;
      }
    }
}

// ---------- gather aggregation: one wave per dest node, writes bf16 hi/lo ----------
__global__ __launch_bounds__(256) void k_gather(const float* __restrict__ xw,
                                                const int* __restrict__ csr,
                                                const int* __restrict__ rp,
                                                const float* __restrict__ dis,
                                                const float* __restrict__ bias,
                                                ushort* __restrict__ hh,
                                                ushort* __restrict__ hl, int n) {
  const int wid = blockIdx.x * 4 + (threadIdx.x >> 6);
  const int lane = threadIdx.x & 63;
  if (wid >= n) return;
  const int s = rp[wid], e = rp[wid + 1];
  const float dc = dis[wid];
  float2 acc = ((const float2*)(xw + (ll)wid * HC))[lane];
  acc.x *= dc * dc;
  acc.y *= dc * dc;
  for (int j = s; j < e; ++j) {
    const int r = csr[j];
    const float nrm = dis[r] * dc;
    const float2 v = ((const float2*)(xw + (ll)r * HC))[lane];
    acc.x = fmaf(nrm, v.x, acc.x);
    acc.y = fmaf(nrm, v.y, acc.y);
  }
  const float2 b = ((const float2*)bias)[lane];
  const float r0 = fmaxf(acc.x + b.x, 0.f);
  const float r1 = fmaxf(acc.y + b.y, 0.f);
  const ushort h0 = f2bf(r0), h1 = f2bf(r1);
  const ushort l0 = f2bf(r0 - bf2f(h0)), l1 = f2bf(r1 - bf2f(h1));
  ((uint*)(hh + (ll)wid * HC))[lane] = (uint)h0 | ((uint)h1 << 16);
  ((uint*)(hl + (ll)wid * HC))[lane] = (uint)l0 | ((uint)l1 << 16);
}

// ---------- head: z @ Wc2 + bc2 -> log_softmax ----------
__global__ __launch_bounds__(256) void k_head(const float* __restrict__ Z,
                                              const float* __restrict__ Wc2,
                                              const float* __restrict__ bc2,
                                              float* __restrict__ out, int nrows) {
  __shared__ float sW[HC * OC];
  __shared__ float sB[OC];
  for (int i = threadIdx.x; i < HC * OC; i += 256) sW[i] = Wc2[i];
  if (threadIdx.x < OC) sB[threadIdx.x] = bc2[threadIdx.x];
  __syncthreads();
  const int wid = threadIdx.x >> 6;
  const int lane = threadIdx.x & 63;
  const int row = blockIdx.x * 4 + wid;
  if (row >= nrows) return;
  const float z0 = Z[(ll)row * HC + lane];
  const float z1 = Z[(ll)row * HC + 64 + lane];
  float a[OC];
#pragma unroll
  for (int o = 0; o < OC; ++o)
    a[o] = z0 * sW[lane * OC + o] + z1 * sW[(lane + 64) * OC + o];
#pragma unroll
  for (int o = 0; o < OC; ++o)
#pragma unroll
    for (int m = 32; m; m >>= 1) a[o] += __shfl_xor(a[o], m, 64);
  float mx = -1e30f;
#pragma unroll
  for (int o = 0; o < OC; ++o) { a[o] += sB[o]; mx = fmaxf(mx, a[o]); }
  float s = 0.f;
#pragma unroll
  for (int o = 0; o < OC; ++o) s += expf(a[o] - mx);
  const float lse = mx + logf(s);
  float v = 0.f;
#pragma unroll
  for (int o = 0; o < OC; ++o) v = (lane == o) ? a[o] - lse : v;
  if (lane < OC) out[(ll)row * OC + lane] = v;
}

extern "C" void kernel_launch(void* const* d_in, const int* in_sizes, int n_in,
                              void* d_out, int out_size, void* d_ws, size_t ws_size,
                              hipStream_t stream) {
  const float* x   = (const float*)d_in[0];
  const int*   ei  = (const int*)d_in[1];   // [2][E] int32
  const float* W1  = (const float*)d_in[2];
  const float* b1  = (const float*)d_in[3];
  const float* W2  = (const float*)d_in[4];
  const float* b2  = (const float*)d_in[5];
  const float* Wc1 = (const float*)d_in[6];
  const float* bc1 = (const float*)d_in[7];
  const float* Wc2 = (const float*)d_in[8];
  const float* bc2 = (const float*)d_in[9];
  float* out = (float*)d_out;

  char* ws = (char*)d_ws;
  float*  bufA = (float*)(ws);                        // xw fp32 [N][128] 76.8MB ; later z [BSZ][128]
  ushort* hh   = (ushort*)(ws + 76800000LL);          // h hi bf16 [N][128] 38.4MB
  ushort* hl   = (ushort*)(ws + 115200000LL);         // h lo bf16 [N][128] 38.4MB
  const ll CSRB = 153600000LL;
  float* dis  = (float*)(ws + CSRB);                  // N floats
  int*   rp   = (int*)  (ws + CSRB + 600064LL);       // N+1
  int*   csr  = (int*)  (ws + CSRB + 1200128LL);      // E
  int*   cnt  = (int*)  (ws + CSRB + 3600128LL);      // 150016
  int*   fill = (int*)  (ws + CSRB + 4200192LL);      // 150016
  int*   bsum = (int*)  (ws + CSRB + 4800256LL);      // 256
  ushort* Wt1h = (ushort*)(ws + CSRB + 4801280LL);    // 128*64
  ushort* Wt1l = (ushort*)(ws + CSRB + 4817664LL);
  ushort* Wt2h = (ushort*)(ws + CSRB + 4834048LL);    // 128*128
  ushort* Wt2l = (ushort*)(ws + CSRB + 4866816LL);
  ushort* Wtc1h = (ushort*)(ws + CSRB + 4899584LL);   // 128*384
  ushort* Wtc1l = (ushort*)(ws + CSRB + 4997888LL);   // end ~158.7MB
  float* zbuf = bufA;                                 // z aliases bufA (dead by then)

  const int nb = (NN + 1023) / 1024;

  // CSR build
  k_zero_i<<<(2 * 150016 + 255) / 256, 256, 0, stream>>>(cnt, 2 * 150016);
  k_count<<<(EE + 255) / 256, 256, 0, stream>>>(ei + EE, cnt, EE);
  k_dis<<<(NN + 255) / 256, 256, 0, stream>>>(cnt, dis, NN);
  k_scan1<<<nb, 256, 0, stream>>>(cnt, rp, bsum, NN);
  k_scan2<<<1, 256, 0, stream>>>(bsum, nb);
  k_scan3<<<nb, 256, 0, stream>>>(rp, bsum, NN, EE);
  k_fill_csr<<<(EE + 255) / 256, 256, 0, stream>>>(ei, rp, fill, csr, EE);

  // weight split+transpose
  k_wprep<<<(INC * 128 + 255) / 256, 256, 0, stream>>>(W1, Wt1h, Wt1l, INC);
  k_wprep<<<(HC * 128 + 255) / 256, 256, 0, stream>>>(W2, Wt2h, Wt2l, HC);
  k_wprep<<<(3 * HC * 128 + 255) / 256, 256, 0, stream>>>(Wc1, Wtc1h, Wtc1l, 3 * HC);

  // layer 1: xw = x @ W1 (fp32 A split in-register)
  k_gemm<INC, 0, 0><<<(NN + 127) / 128, 256, 0, stream>>>(x, nullptr, nullptr, Wt1h, Wt1l, nullptr, bufA, NN);
  k_gather<<<(NN + 3) / 4, 256, 0, stream>>>(bufA, csr, rp, dis, b1, hh, hl, NN);

  // layer 2: xw = h @ W2 (bf16 A)
  k_gemm<HC, 1, 0><<<(NN + 127) / 128, 256, 0, stream>>>(nullptr, hh, hl, Wt2h, Wt2l, nullptr, bufA, NN);
  k_gather<<<(NN + 3) / 4, 256, 0, stream>>>(bufA, csr, rp, dis, b2, hh, hl, NN);

  // classifier: z = relu(flat @ Wc1 + bc1), flat = h viewed [BSZ][384]
  k_gemm<3 * HC, 1, 2><<<(BSZ + 127) / 128, 256, 0, stream>>>(nullptr, hh, hl, Wtc1h, Wtc1l, bc1, zbuf, BSZ);
  k_head<<<BSZ / 4, 256, 0, stream>>>(zbuf, Wc2, bc2, out, BSZ);
}

// Round 4
// 345.980 us; speedup vs baseline: 8.9585x; 1.1044x over previous
//
#include <hip/hip_runtime.h>

#define NN 150000
#define EE 600000
#define INC 64
#define HC 128
#define OC 10
#define BSZ 50000

typedef long long ll;
typedef __attribute__((ext_vector_type(8))) short short8v;
typedef __attribute__((ext_vector_type(4))) float f32x4;

__device__ __forceinline__ ushort f2bf(float f) {
  uint u = __float_as_uint(f);
  uint r = (u + 0x7fffu + ((u >> 16) & 1u)) >> 16;
  return (ushort)r;
}
__device__ __forceinline__ float bf2f(ushort h) {
  return __uint_as_float(((uint)h) << 16);
}

// ---------- CSR build ----------

__global__ __launch_bounds__(256) void k_zero_i(int* d, int n) {
  int i = blockIdx.x * 256 + threadIdx.x;
  if (i < n) d[i] = 0;
}

__global__ __launch_bounds__(256) void k_count(const int* __restrict__ col, int* cnt, int e) {
  int i = blockIdx.x * 256 + threadIdx.x;
  if (i < e) atomicAdd(&cnt[col[i]], 1);
}

// exclusive scan over cnt (1024/block) + dis = rsqrt(1+cnt)
__global__ __launch_bounds__(256) void k_scan1(const int* __restrict__ cnt, int* ex, int* bsum,
                                               float* __restrict__ dis, int n) {
  __shared__ int s[256];
  const int t = threadIdx.x;
  const int base = blockIdx.x * 1024 + t * 4;
  int v[4], tot = 0;
#pragma unroll
  for (int i = 0; i < 4; ++i) {
    v[i] = (base + i < n) ? cnt[base + i] : 0;
    tot += v[i];
    if (base + i < n) dis[base + i] = rsqrtf((float)(1 + v[i]));
  }
  s[t] = tot;
  __syncthreads();
#pragma unroll
  for (int off = 1; off < 256; off <<= 1) {
    int x = (t >= off) ? s[t - off] : 0;
    __syncthreads();
    s[t] += x;
    __syncthreads();
  }
  int run = s[t] - tot;
#pragma unroll
  for (int i = 0; i < 4; ++i) {
    if (base + i < n) ex[base + i] = run;
    run += v[i];
  }
  if (t == 255) bsum[blockIdx.x] = s[255];
}

__global__ __launch_bounds__(256) void k_scan2(int* bsum, int nb) {
  __shared__ int s[256];
  const int t = threadIdx.x;
  int v = (t < nb) ? bsum[t] : 0;
  s[t] = v;
  __syncthreads();
#pragma unroll
  for (int off = 1; off < 256; off <<= 1) {
    int x = (t >= off) ? s[t - off] : 0;
    __syncthreads();
    s[t] += x;
    __syncthreads();
  }
  if (t < nb) bsum[t] = s[t] - v;
}

__global__ __launch_bounds__(256) void k_scan3(int* rp, const int* __restrict__ bsum, int n, int e) {
  const int base = blockIdx.x * 1024 + threadIdx.x * 4;
  const int off = bsum[blockIdx.x];
#pragma unroll
  for (int i = 0; i < 4; ++i)
    if (base + i < n) rp[base + i] += off;
  if (blockIdx.x == 0 && threadIdx.x == 0) rp[n] = e;
}

__global__ __launch_bounds__(256) void k_fill_csr(const int* __restrict__ ei,
                                                  const int* __restrict__ rp,
                                                  int* fill, int* csr, int e) {
  int i = blockIdx.x * 256 + threadIdx.x;
  if (i >= e) return;
  int r = ei[i];
  int c = ei[EE + i];
  int slot = rp[c] + atomicAdd(&fill[c], 1);
  csr[slot] = r;
}

// ---------- weight prep (all 3 weights in one kernel) ----------
__global__ __launch_bounds__(256) void k_wprep_all(const float* __restrict__ W1,
                                                   const float* __restrict__ W2,
                                                   const float* __restrict__ Wc1,
                                                   ushort* t1h, ushort* t1l,
                                                   ushort* t2h, ushort* t2l,
                                                   ushort* tch, ushort* tcl) {
  int t = blockIdx.x * 256 + threadIdx.x;
  const float* W; ushort* th; ushort* tl; int K, idx;
  if (t < 64 * 128)                { W = W1;  th = t1h; tl = t1l; K = 64;  idx = t; }
  else if (t < (64 + 128) * 128)   { W = W2;  th = t2h; tl = t2l; K = 128; idx = t - 64 * 128; }
  else if (t < (64 + 128 + 384) * 128) { W = Wc1; th = tch; tl = tcl; K = 384; idx = t - (64 + 128) * 128; }
  else return;
  int col = idx & 127;
  int k = idx >> 7;
  float v = W[(ll)k * 128 + col];
  ushort h = f2bf(v);
  th[(ll)col * K + k] = h;
  tl[(ll)col * K + k] = f2bf(v - bf2f(h));
}

// ---------- MFMA GEMM: Y[nrows][128] = X[nrows][K] @ W[K][128] ----------
// split-bf16: C = Ah*Bh + Ah*Bl + Al*Bh  (fp32 accumulate)
// ASRC 0: X fp32, split in-register. ASRC 1: X bf16 hi/lo arrays.
// MODE 1: Y = dis[row] * Y   (pre-scaled for gather).  MODE 2: Y = relu(Y + bias).
template<int K, int ASRC, int MODE>
__global__ __launch_bounds__(256) void k_gemm(const float* __restrict__ Xf,
                                              const ushort* __restrict__ Xh,
                                              const ushort* __restrict__ Xl,
                                              const ushort* __restrict__ Wth,
                                              const ushort* __restrict__ Wtl,
                                              const float* __restrict__ bias,
                                              const float* __restrict__ dis,
                                              float* __restrict__ Y, int nrows) {
  __shared__ ushort sAh[128][40];
  __shared__ ushort sAl[128][40];
  __shared__ ushort sBh[128][40];
  __shared__ ushort sBl[128][40];
  const int t = threadIdx.x;
  const int lane = t & 63;
  const int wid = t >> 6;
  const int wr = wid >> 1, wc = wid & 1;
  const int row0 = blockIdx.x * 128;

  f32x4 acc[4][4];
#pragma unroll
  for (int m = 0; m < 4; ++m)
#pragma unroll
    for (int n = 0; n < 4; ++n) acc[m][n] = (f32x4){0.f, 0.f, 0.f, 0.f};

  const int srow = t >> 1;
  const int shalf = t & 1;

  for (int kc = 0; kc < K; kc += 32) {
    __syncthreads();
    if (ASRC == 0) {
      float f[16];
      const ll rg = row0 + srow;
      if (rg < nrows) {
        const float4* p = (const float4*)(Xf + rg * K + kc + shalf * 16);
#pragma unroll
        for (int i = 0; i < 4; ++i) {
          float4 v = p[i];
          f[i * 4] = v.x; f[i * 4 + 1] = v.y; f[i * 4 + 2] = v.z; f[i * 4 + 3] = v.w;
        }
      } else {
#pragma unroll
        for (int i = 0; i < 16; ++i) f[i] = 0.f;
      }
      union { ushort u[16]; short8v v[2]; } hu, lu;
#pragma unroll
      for (int i = 0; i < 16; ++i) {
        ushort h = f2bf(f[i]);
        hu.u[i] = h;
        lu.u[i] = f2bf(f[i] - bf2f(h));
      }
      *(short8v*)&sAh[srow][shalf * 16] = hu.v[0];
      *(short8v*)&sAh[srow][shalf * 16 + 8] = hu.v[1];
      *(short8v*)&sAl[srow][shalf * 16] = lu.v[0];
      *(short8v*)&sAl[srow][shalf * 16 + 8] = lu.v[1];
    } else {
      short8v h0 = {0,0,0,0,0,0,0,0}, h1 = h0, l0 = h0, l1 = h0;
      const ll rg = row0 + srow;
      if (rg < nrows) {
        const short8v* ph = (const short8v*)(Xh + rg * K + kc + shalf * 16);
        const short8v* pl = (const short8v*)(Xl + rg * K + kc + shalf * 16);
        h0 = ph[0]; h1 = ph[1];
        l0 = pl[0]; l1 = pl[1];
      }
      *(short8v*)&sAh[srow][shalf * 16] = h0;
      *(short8v*)&sAh[srow][shalf * 16 + 8] = h1;
      *(short8v*)&sAl[srow][shalf * 16] = l0;
      *(short8v*)&sAl[srow][shalf * 16 + 8] = l1;
    }
    {
      const short8v* ph = (const short8v*)(Wth + (ll)srow * K + kc + shalf * 16);
      const short8v* pl = (const short8v*)(Wtl + (ll)srow * K + kc + shalf * 16);
      short8v h0 = ph[0], h1 = ph[1], l0 = pl[0], l1 = pl[1];
      *(short8v*)&sBh[srow][shalf * 16] = h0;
      *(short8v*)&sBh[srow][shalf * 16 + 8] = h1;
      *(short8v*)&sBl[srow][shalf * 16] = l0;
      *(short8v*)&sBl[srow][shalf * 16 + 8] = l1;
    }
    __syncthreads();
    const int kq = (lane >> 4) * 8;
    const int fr = lane & 15;
    short8v ah[4], al[4], bh[4], bl[4];
#pragma unroll
    for (int m = 0; m < 4; ++m) {
      const int r = wr * 64 + m * 16 + fr;
      ah[m] = *(const short8v*)&sAh[r][kq];
      al[m] = *(const short8v*)&sAl[r][kq];
    }
#pragma unroll
    for (int n = 0; n < 4; ++n) {
      const int c = wc * 64 + n * 16 + fr;
      bh[n] = *(const short8v*)&sBh[c][kq];
      bl[n] = *(const short8v*)&sBl[c][kq];
    }
#pragma unroll
    for (int m = 0; m < 4; ++m)
#pragma unroll
      for (int n = 0; n < 4; ++n) {
        acc[m][n] = __builtin_amdgcn_mfma_f32_16x16x32_bf16(ah[m], bh[n], acc[m][n], 0, 0, 0);
        acc[m][n] = __builtin_amdgcn_mfma_f32_16x16x32_bf16(ah[m], bl[n], acc[m][n], 0, 0, 0);
        acc[m][n] = __builtin_amdgcn_mfma_f32_16x16x32_bf16(al[m], bh[n], acc[m][n], 0, 0, 0);
      }
  }

#pragma unroll
  for (int m = 0; m < 4; ++m)
#pragma unroll
    for (int q = 0; q < 4; ++q) {
      const int rl = wr * 64 + m * 16 + (lane >> 4) * 4 + q;
      const ll rg = row0 + rl;
      if (rg >= nrows) continue;
      const float ds = (MODE == 1) ? dis[rg] : 0.f;
#pragma unroll
      for (int n = 0; n < 4; ++n) {
        const int col = wc * 64 + n * 16 + (lane & 15);
        float v = acc[m][n][q];
        if (MODE == 1) v *= ds;
        if (MODE == 2) v = fmaxf(v + bias[col], 0.f);
        Y[rg * HC + col] = v;
      }
    }
}

// ---------- gather: out[c] = relu(b + dis[c]*(xw'[c] + sum_src xw'[src])) ----------
// xw' rows already pre-scaled by dis[src] in the GEMM epilogue -> no per-edge dis reads.
__global__ __launch_bounds__(256) void k_gather(const float* __restrict__ xw,
                                                const int* __restrict__ csr,
                                                const int* __restrict__ rp,
                                                const float* __restrict__ dis,
                                                const float* __restrict__ bias,
                                                ushort* __restrict__ hh,
                                                ushort* __restrict__ hl, int n) {
  const int wid = blockIdx.x * 4 + (threadIdx.x >> 6);
  const int lane = threadIdx.x & 63;
  if (wid >= n) return;
  const int s = rp[wid], e = rp[wid + 1];
  float2 acc = ((const float2*)(xw + (ll)wid * HC))[lane];  // self term (pre-scaled)
  int j = s;
  for (; j + 1 < e; j += 2) {
    const int r0 = csr[j];
    const int r1 = csr[j + 1];
    const float2 v0 = ((const float2*)(xw + (ll)r0 * HC))[lane];
    const float2 v1 = ((const float2*)(xw + (ll)r1 * HC))[lane];
    acc.x += v0.x + v1.x;
    acc.y += v0.y + v1.y;
  }
  if (j < e) {
    const int r = csr[j];
    const float2 v = ((const float2*)(xw + (ll)r * HC))[lane];
    acc.x += v.x;
    acc.y += v.y;
  }
  const float dc = dis[wid];
  const float2 b = ((const float2*)bias)[lane];
  const float r0 = fmaxf(fmaf(dc, acc.x, b.x), 0.f);
  const float r1 = fmaxf(fmaf(dc, acc.y, b.y), 0.f);
  const ushort h0 = f2bf(r0), h1 = f2bf(r1);
  const ushort l0 = f2bf(r0 - bf2f(h0)), l1 = f2bf(r1 - bf2f(h1));
  ((uint*)(hh + (ll)wid * HC))[lane] = (uint)h0 | ((uint)h1 << 16);
  ((uint*)(hl + (ll)wid * HC))[lane] = (uint)l0 | ((uint)l1 << 16);
}

// ---------- head: z @ Wc2 + bc2 -> log_softmax ----------
__global__ __launch_bounds__(256) void k_head(const float* __restrict__ Z,
                                              const float* __restrict__ Wc2,
                                              const float* __restrict__ bc2,
                                              float* __restrict__ out, int nrows) {
  __shared__ float sW[HC * OC];
  __shared__ float sB[OC];
  for (int i = threadIdx.x; i < HC * OC; i += 256) sW[i] = Wc2[i];
  if (threadIdx.x < OC) sB[threadIdx.x] = bc2[threadIdx.x];
  __syncthreads();
  const int wid = threadIdx.x >> 6;
  const int lane = threadIdx.x & 63;
  const int row = blockIdx.x * 4 + wid;
  if (row >= nrows) return;
  const float z0 = Z[(ll)row * HC + lane];
  const float z1 = Z[(ll)row * HC + 64 + lane];
  float a[OC];
#pragma unroll
  for (int o = 0; o < OC; ++o)
    a[o] = z0 * sW[lane * OC + o] + z1 * sW[(lane + 64) * OC + o];
#pragma unroll
  for (int o = 0; o < OC; ++o)
#pragma unroll
    for (int m = 32; m; m >>= 1) a[o] += __shfl_xor(a[o], m, 64);
  float mx = -1e30f;
#pragma unroll
  for (int o = 0; o < OC; ++o) { a[o] += sB[o]; mx = fmaxf(mx, a[o]); }
  float s = 0.f;
#pragma unroll
  for (int o = 0; o < OC; ++o) s += expf(a[o] - mx);
  const float lse = mx + logf(s);
  float v = 0.f;
#pragma unroll
  for (int o = 0; o < OC; ++o) v = (lane == o) ? a[o] - lse : v;
  if (lane < OC) out[(ll)row * OC + lane] = v;
}

extern "C" void kernel_launch(void* const* d_in, const int* in_sizes, int n_in,
                              void* d_out, int out_size, void* d_ws, size_t ws_size,
                              hipStream_t stream) {
  const float* x   = (const float*)d_in[0];
  const int*   ei  = (const int*)d_in[1];   // [2][E] int32
  const float* W1  = (const float*)d_in[2];
  const float* b1  = (const float*)d_in[3];
  const float* W2  = (const float*)d_in[4];
  const float* b2  = (const float*)d_in[5];
  const float* Wc1 = (const float*)d_in[6];
  const float* bc1 = (const float*)d_in[7];
  const float* Wc2 = (const float*)d_in[8];
  const float* bc2 = (const float*)d_in[9];
  float* out = (float*)d_out;

  char* ws = (char*)d_ws;
  float*  bufA = (float*)(ws);                        // xw' fp32 [N][128] 76.8MB ; later z [BSZ][128]
  ushort* hh   = (ushort*)(ws + 76800000LL);          // h hi bf16 [N][128] 38.4MB
  ushort* hl   = (ushort*)(ws + 115200000LL);         // h lo bf16 [N][128] 38.4MB
  const ll CSRB = 153600000LL;
  float* dis  = (float*)(ws + CSRB);                  // N floats
  int*   rp   = (int*)  (ws + CSRB + 600064LL);       // N+1
  int*   csr  = (int*)  (ws + CSRB + 1200128LL);      // E
  int*   cnt  = (int*)  (ws + CSRB + 3600128LL);      // 150016
  int*   fill = (int*)  (ws + CSRB + 4200192LL);      // 150016
  int*   bsum = (int*)  (ws + CSRB + 4800256LL);      // 256
  ushort* Wt1h = (ushort*)(ws + CSRB + 4801280LL);    // 128*64
  ushort* Wt1l = (ushort*)(ws + CSRB + 4817664LL);
  ushort* Wt2h = (ushort*)(ws + CSRB + 4834048LL);    // 128*128
  ushort* Wt2l = (ushort*)(ws + CSRB + 4866816LL);
  ushort* Wtc1h = (ushort*)(ws + CSRB + 4899584LL);   // 128*384
  ushort* Wtc1l = (ushort*)(ws + CSRB + 4997888LL);
  float* zbuf = bufA;

  const int nb = (NN + 1023) / 1024;

  // CSR build
  k_zero_i<<<(2 * 150016 + 255) / 256, 256, 0, stream>>>(cnt, 2 * 150016);
  k_count<<<(EE + 255) / 256, 256, 0, stream>>>(ei + EE, cnt, EE);
  k_scan1<<<nb, 256, 0, stream>>>(cnt, rp, bsum, dis, NN);
  k_scan2<<<1, 256, 0, stream>>>(bsum, nb);
  k_scan3<<<nb, 256, 0, stream>>>(rp, bsum, NN, EE);
  k_fill_csr<<<(EE + 255) / 256, 256, 0, stream>>>(ei, rp, fill, csr, EE);

  // weight split+transpose (all in one)
  k_wprep_all<<<((64 + 128 + 384) * 128 + 255) / 256, 256, 0, stream>>>(
      W1, W2, Wc1, Wt1h, Wt1l, Wt2h, Wt2l, Wtc1h, Wtc1l);

  // layer 1: xw' = dis.row * (x @ W1)
  k_gemm<INC, 0, 1><<<(NN + 127) / 128, 256, 0, stream>>>(x, nullptr, nullptr, Wt1h, Wt1l, nullptr, dis, bufA, NN);
  k_gather<<<(NN + 3) / 4, 256, 0, stream>>>(bufA, csr, rp, dis, b1, hh, hl, NN);

  // layer 2: xw' = dis.row * (h @ W2)
  k_gemm<HC, 1, 1><<<(NN + 127) / 128, 256, 0, stream>>>(nullptr, hh, hl, Wt2h, Wt2l, nullptr, dis, bufA, NN);
  k_gather<<<(NN + 3) / 4, 256, 0, stream>>>(bufA, csr, rp, dis, b2, hh, hl, NN);

  // classifier: z = relu(flat @ Wc1 + bc1), flat = h viewed [BSZ][384]
  k_gemm<3 * HC, 1, 2><<<(BSZ + 127) / 128, 256, 0, stream>>>(nullptr, hh, hl, Wtc1h, Wtc1l, bc1, nullptr, zbuf, BSZ);
  k_head<<<BSZ / 4, 256, 0, stream>>>(zbuf, Wc2, bc2, out, BSZ);
}

// Round 5
// 314.444 us; speedup vs baseline: 9.8569x; 1.1003x over previous
//
#include <hip/hip_runtime.h>

#define NN 150000
#define EE 600000
#define INC 64
#define HC 128
#define OC 10
#define BSZ 50000

typedef long long ll;
typedef _Float16 f16;
typedef __attribute__((ext_vector_type(8))) short short8v;
typedef __attribute__((ext_vector_type(4))) float f32x4;

__device__ __forceinline__ ushort f2bf(float f) {
  uint u = __float_as_uint(f);
  uint r = (u + 0x7fffu + ((u >> 16) & 1u)) >> 16;
  return (ushort)r;
}
__device__ __forceinline__ float bf2f(ushort h) {
  return __uint_as_float(((uint)h) << 16);
}
__device__ __forceinline__ float h2f(ushort u) {
  f16 h;
  __builtin_memcpy(&h, &u, 2);
  return (float)h;
}
__device__ __forceinline__ ushort f2h(float f) {
  f16 h = (f16)f;
  ushort u;
  __builtin_memcpy(&u, &h, 2);
  return u;
}

// ---------- CSR build ----------

__global__ __launch_bounds__(256) void k_zero_i(int* d, int n) {
  int i = blockIdx.x * 256 + threadIdx.x;
  if (i < n) d[i] = 0;
}

__global__ __launch_bounds__(256) void k_count(const int* __restrict__ col, int* cnt, int e) {
  int i = blockIdx.x * 256 + threadIdx.x;
  if (i < e) atomicAdd(&cnt[col[i]], 1);
}

__global__ __launch_bounds__(256) void k_scan1(const int* __restrict__ cnt, int* ex, int* bsum,
                                               float* __restrict__ dis, int n) {
  __shared__ int s[256];
  const int t = threadIdx.x;
  const int base = blockIdx.x * 1024 + t * 4;
  int v[4], tot = 0;
#pragma unroll
  for (int i = 0; i < 4; ++i) {
    v[i] = (base + i < n) ? cnt[base + i] : 0;
    tot += v[i];
    if (base + i < n) dis[base + i] = rsqrtf((float)(1 + v[i]));
  }
  s[t] = tot;
  __syncthreads();
#pragma unroll
  for (int off = 1; off < 256; off <<= 1) {
    int x = (t >= off) ? s[t - off] : 0;
    __syncthreads();
    s[t] += x;
    __syncthreads();
  }
  int run = s[t] - tot;
#pragma unroll
  for (int i = 0; i < 4; ++i) {
    if (base + i < n) ex[base + i] = run;
    run += v[i];
  }
  if (t == 255) bsum[blockIdx.x] = s[255];
}

__global__ __launch_bounds__(256) void k_scan2(int* bsum, int nb) {
  __shared__ int s[256];
  const int t = threadIdx.x;
  int v = (t < nb) ? bsum[t] : 0;
  s[t] = v;
  __syncthreads();
#pragma unroll
  for (int off = 1; off < 256; off <<= 1) {
    int x = (t >= off) ? s[t - off] : 0;
    __syncthreads();
    s[t] += x;
    __syncthreads();
  }
  if (t < nb) bsum[t] = s[t] - v;
}

__global__ __launch_bounds__(256) void k_scan3(int* rp, const int* __restrict__ bsum, int n, int e) {
  const int base = blockIdx.x * 1024 + threadIdx.x * 4;
  const int off = bsum[blockIdx.x];
#pragma unroll
  for (int i = 0; i < 4; ++i)
    if (base + i < n) rp[base + i] += off;
  if (blockIdx.x == 0 && threadIdx.x == 0) rp[n] = e;
}

__global__ __launch_bounds__(256) void k_fill_csr(const int* __restrict__ ei,
                                                  const int* __restrict__ rp,
                                                  int* fill, int* csr, int e) {
  int i = blockIdx.x * 256 + threadIdx.x;
  if (i >= e) return;
  int r = ei[i];
  int c = ei[EE + i];
  int slot = rp[c] + atomicAdd(&fill[c], 1);
  csr[slot] = r;
}

// ---------- weight prep (all 3 weights in one kernel) ----------
__global__ __launch_bounds__(256) void k_wprep_all(const float* __restrict__ W1,
                                                   const float* __restrict__ W2,
                                                   const float* __restrict__ Wc1,
                                                   ushort* t1h, ushort* t1l,
                                                   ushort* t2h, ushort* t2l,
                                                   ushort* tch, ushort* tcl) {
  int t = blockIdx.x * 256 + threadIdx.x;
  const float* W; ushort* th; ushort* tl; int K, idx;
  if (t < 64 * 128)                { W = W1;  th = t1h; tl = t1l; K = 64;  idx = t; }
  else if (t < (64 + 128) * 128)   { W = W2;  th = t2h; tl = t2l; K = 128; idx = t - 64 * 128; }
  else if (t < (64 + 128 + 384) * 128) { W = Wc1; th = tch; tl = tcl; K = 384; idx = t - (64 + 128) * 128; }
  else return;
  int col = idx & 127;
  int k = idx >> 7;
  float v = W[(ll)k * 128 + col];
  ushort h = f2bf(v);
  th[(ll)col * K + k] = h;
  tl[(ll)col * K + k] = f2bf(v - bf2f(h));
}

// ---------- MFMA GEMM: Y[nrows][128] = X[nrows][K] @ W[K][128] ----------
// split-bf16: C = Ah*Bh + Ah*Bl + Al*Bh  (fp32 accumulate)
// ASRC 0: X fp32, split in-register. ASRC 2: X fp16, split in-register (exact).
// MODE 1: Y16 = fp16( dis[row] * Y ).  MODE 2: Yf = relu(Y + bias) fp32.
template<int K, int ASRC, int MODE>
__global__ __launch_bounds__(256) void k_gemm(const float* __restrict__ Xf,
                                              const ushort* __restrict__ Xh16,
                                              const ushort* __restrict__ Wth,
                                              const ushort* __restrict__ Wtl,
                                              const float* __restrict__ bias,
                                              const float* __restrict__ dis,
                                              float* __restrict__ Yf,
                                              ushort* __restrict__ Y16, int nrows) {
  __shared__ ushort sAh[128][40];
  __shared__ ushort sAl[128][40];
  __shared__ ushort sBh[128][40];
  __shared__ ushort sBl[128][40];
  const int t = threadIdx.x;
  const int lane = t & 63;
  const int wid = t >> 6;
  const int wr = wid >> 1, wc = wid & 1;
  const int row0 = blockIdx.x * 128;

  f32x4 acc[4][4];
#pragma unroll
  for (int m = 0; m < 4; ++m)
#pragma unroll
    for (int n = 0; n < 4; ++n) acc[m][n] = (f32x4){0.f, 0.f, 0.f, 0.f};

  const int srow = t >> 1;
  const int shalf = t & 1;

  for (int kc = 0; kc < K; kc += 32) {
    __syncthreads();
    // ---- stage A tile (128 rows x 32 k): load 16 elems, split to bf16 hi/lo ----
    {
      float f[16];
      const ll rg = row0 + srow;
      if (rg < nrows) {
        if (ASRC == 0) {
          const float4* p = (const float4*)(Xf + rg * K + kc + shalf * 16);
#pragma unroll
          for (int i = 0; i < 4; ++i) {
            float4 v = p[i];
            f[i * 4] = v.x; f[i * 4 + 1] = v.y; f[i * 4 + 2] = v.z; f[i * 4 + 3] = v.w;
          }
        } else {
          const short8v* p = (const short8v*)(Xh16 + rg * K + kc + shalf * 16);
          union { short8v v[2]; ushort u[16]; } raw;
          raw.v[0] = p[0]; raw.v[1] = p[1];
#pragma unroll
          for (int i = 0; i < 16; ++i) f[i] = h2f(raw.u[i]);
        }
      } else {
#pragma unroll
        for (int i = 0; i < 16; ++i) f[i] = 0.f;
      }
      union { ushort u[16]; short8v v[2]; } hu, lu;
#pragma unroll
      for (int i = 0; i < 16; ++i) {
        ushort h = f2bf(f[i]);
        hu.u[i] = h;
        lu.u[i] = f2bf(f[i] - bf2f(h));
      }
      *(short8v*)&sAh[srow][shalf * 16] = hu.v[0];
      *(short8v*)&sAh[srow][shalf * 16 + 8] = hu.v[1];
      *(short8v*)&sAl[srow][shalf * 16] = lu.v[0];
      *(short8v*)&sAl[srow][shalf * 16 + 8] = lu.v[1];
    }
    // ---- stage B tile from pre-split transposed weights ----
    {
      const short8v* ph = (const short8v*)(Wth + (ll)srow * K + kc + shalf * 16);
      const short8v* pl = (const short8v*)(Wtl + (ll)srow * K + kc + shalf * 16);
      short8v h0 = ph[0], h1 = ph[1], l0 = pl[0], l1 = pl[1];
      *(short8v*)&sBh[srow][shalf * 16] = h0;
      *(short8v*)&sBh[srow][shalf * 16 + 8] = h1;
      *(short8v*)&sBl[srow][shalf * 16] = l0;
      *(short8v*)&sBl[srow][shalf * 16 + 8] = l1;
    }
    __syncthreads();
    const int kq = (lane >> 4) * 8;
    const int fr = lane & 15;
    short8v ah[4], al[4], bh[4], bl[4];
#pragma unroll
    for (int m = 0; m < 4; ++m) {
      const int r = wr * 64 + m * 16 + fr;
      ah[m] = *(const short8v*)&sAh[r][kq];
      al[m] = *(const short8v*)&sAl[r][kq];
    }
#pragma unroll
    for (int n = 0; n < 4; ++n) {
      const int c = wc * 64 + n * 16 + fr;
      bh[n] = *(const short8v*)&sBh[c][kq];
      bl[n] = *(const short8v*)&sBl[c][kq];
    }
#pragma unroll
    for (int m = 0; m < 4; ++m)
#pragma unroll
      for (int n = 0; n < 4; ++n) {
        acc[m][n] = __builtin_amdgcn_mfma_f32_16x16x32_bf16(ah[m], bh[n], acc[m][n], 0, 0, 0);
        acc[m][n] = __builtin_amdgcn_mfma_f32_16x16x32_bf16(ah[m], bl[n], acc[m][n], 0, 0, 0);
        acc[m][n] = __builtin_amdgcn_mfma_f32_16x16x32_bf16(al[m], bh[n], acc[m][n], 0, 0, 0);
      }
  }

#pragma unroll
  for (int m = 0; m < 4; ++m)
#pragma unroll
    for (int q = 0; q < 4; ++q) {
      const int rl = wr * 64 + m * 16 + (lane >> 4) * 4 + q;
      const ll rg = row0 + rl;
      if (rg >= nrows) continue;
      const float ds = (MODE == 1) ? dis[rg] : 0.f;
#pragma unroll
      for (int n = 0; n < 4; ++n) {
        const int col = wc * 64 + n * 16 + (lane & 15);
        float v = acc[m][n][q];
        if (MODE == 1) {
          Y16[rg * HC + col] = f2h(v * ds);
        } else {
          Yf[rg * HC + col] = fmaxf(v + bias[col], 0.f);
        }
      }
    }
}

// ---------- gather: h[c] = fp16( relu(b + dis[c]*(xw'[c] + sum_src xw'[src])) ) ----------
// xw' fp16, rows pre-scaled by dis[src]. Each lane owns 2 channels (one uint).
__global__ __launch_bounds__(256) void k_gather(const ushort* __restrict__ xw16,
                                                const int* __restrict__ csr,
                                                const int* __restrict__ rp,
                                                const float* __restrict__ dis,
                                                const float* __restrict__ bias,
                                                ushort* __restrict__ h16, int n) {
  const int wid = blockIdx.x * 4 + (threadIdx.x >> 6);
  const int lane = threadIdx.x & 63;
  if (wid >= n) return;
  const int s = rp[wid], e = rp[wid + 1];
  const uint* xwu = (const uint*)xw16;   // 64 uints per row
  uint sv = xwu[(ll)wid * 64 + lane];
  float2 acc = make_float2(h2f((ushort)(sv & 0xffff)), h2f((ushort)(sv >> 16)));
  int j = s;
  for (; j + 1 < e; j += 2) {
    const int r0 = csr[j];
    const int r1 = csr[j + 1];
    const uint v0 = xwu[(ll)r0 * 64 + lane];
    const uint v1 = xwu[(ll)r1 * 64 + lane];
    acc.x += h2f((ushort)(v0 & 0xffff)) + h2f((ushort)(v1 & 0xffff));
    acc.y += h2f((ushort)(v0 >> 16)) + h2f((ushort)(v1 >> 16));
  }
  if (j < e) {
    const uint v = xwu[(ll)csr[j] * 64 + lane];
    acc.x += h2f((ushort)(v & 0xffff));
    acc.y += h2f((ushort)(v >> 16));
  }
  const float dc = dis[wid];
  const float2 b = ((const float2*)bias)[lane];
  const float r0 = fmaxf(fmaf(dc, acc.x, b.x), 0.f);
  const float r1 = fmaxf(fmaf(dc, acc.y, b.y), 0.f);
  ((uint*)h16)[(ll)wid * 64 + lane] = (uint)f2h(r0) | ((uint)f2h(r1) << 16);
}

// ---------- head: z @ Wc2 + bc2 -> log_softmax ----------
__global__ __launch_bounds__(256) void k_head(const float* __restrict__ Z,
                                              const float* __restrict__ Wc2,
                                              const float* __restrict__ bc2,
                                              float* __restrict__ out, int nrows) {
  __shared__ float sW[HC * OC];
  __shared__ float sB[OC];
  for (int i = threadIdx.x; i < HC * OC; i += 256) sW[i] = Wc2[i];
  if (threadIdx.x < OC) sB[threadIdx.x] = bc2[threadIdx.x];
  __syncthreads();
  const int wid = threadIdx.x >> 6;
  const int lane = threadIdx.x & 63;
  const int row = blockIdx.x * 4 + wid;
  if (row >= nrows) return;
  const float z0 = Z[(ll)row * HC + lane];
  const float z1 = Z[(ll)row * HC + 64 + lane];
  float a[OC];
#pragma unroll
  for (int o = 0; o < OC; ++o)
    a[o] = z0 * sW[lane * OC + o] + z1 * sW[(lane + 64) * OC + o];
#pragma unroll
  for (int o = 0; o < OC; ++o)
#pragma unroll
    for (int m = 32; m; m >>= 1) a[o] += __shfl_xor(a[o], m, 64);
  float mx = -1e30f;
#pragma unroll
  for (int o = 0; o < OC; ++o) { a[o] += sB[o]; mx = fmaxf(mx, a[o]); }
  float s = 0.f;
#pragma unroll
  for (int o = 0; o < OC; ++o) s += expf(a[o] - mx);
  const float lse = mx + logf(s);
  float v = 0.f;
#pragma unroll
  for (int o = 0; o < OC; ++o) v = (lane == o) ? a[o] - lse : v;
  if (lane < OC) out[(ll)row * OC + lane] = v;
}

extern "C" void kernel_launch(void* const* d_in, const int* in_sizes, int n_in,
                              void* d_out, int out_size, void* d_ws, size_t ws_size,
                              hipStream_t stream) {
  const float* x   = (const float*)d_in[0];
  const int*   ei  = (const int*)d_in[1];   // [2][E] int32
  const float* W1  = (const float*)d_in[2];
  const float* b1  = (const float*)d_in[3];
  const float* W2  = (const float*)d_in[4];
  const float* b2  = (const float*)d_in[5];
  const float* Wc1 = (const float*)d_in[6];
  const float* bc1 = (const float*)d_in[7];
  const float* Wc2 = (const float*)d_in[8];
  const float* bc2 = (const float*)d_in[9];
  float* out = (float*)d_out;

  char* ws = (char*)d_ws;
  ushort* xw16 = (ushort*)(ws);                       // xw' fp16 [N][128] 38.4MB
  ushort* h16  = (ushort*)(ws + 38400000LL);          // h   fp16 [N][128] 38.4MB
  float*  zbuf = (float*)(ws + 76800000LL);           // z fp32 [BSZ][128] 25.6MB
  const ll CSRB = 102400000LL;
  float* dis  = (float*)(ws + CSRB);                  // N floats
  int*   rp   = (int*)  (ws + CSRB + 600064LL);       // N+1
  int*   csr  = (int*)  (ws + CSRB + 1200128LL);      // E
  int*   cnt  = (int*)  (ws + CSRB + 3600128LL);      // 150016
  int*   fill = (int*)  (ws + CSRB + 4200192LL);      // 150016
  int*   bsum = (int*)  (ws + CSRB + 4800256LL);      // 256
  ushort* Wt1h = (ushort*)(ws + CSRB + 4801280LL);    // 128*64
  ushort* Wt1l = (ushort*)(ws + CSRB + 4817664LL);
  ushort* Wt2h = (ushort*)(ws + CSRB + 4834048LL);    // 128*128
  ushort* Wt2l = (ushort*)(ws + CSRB + 4866816LL);
  ushort* Wtc1h = (ushort*)(ws + CSRB + 4899584LL);   // 128*384
  ushort* Wtc1l = (ushort*)(ws + CSRB + 4997888LL);

  const int nb = (NN + 1023) / 1024;

  // CSR build
  k_zero_i<<<(2 * 150016 + 255) / 256, 256, 0, stream>>>(cnt, 2 * 150016);
  k_count<<<(EE + 255) / 256, 256, 0, stream>>>(ei + EE, cnt, EE);
  k_scan1<<<nb, 256, 0, stream>>>(cnt, rp, bsum, dis, NN);
  k_scan2<<<1, 256, 0, stream>>>(bsum, nb);
  k_scan3<<<nb, 256, 0, stream>>>(rp, bsum, NN, EE);
  k_fill_csr<<<(EE + 255) / 256, 256, 0, stream>>>(ei, rp, fill, csr, EE);

  // weight split+transpose
  k_wprep_all<<<((64 + 128 + 384) * 128 + 255) / 256, 256, 0, stream>>>(
      W1, W2, Wc1, Wt1h, Wt1l, Wt2h, Wt2l, Wtc1h, Wtc1l);

  // layer 1: xw' = fp16(dis.row * (x @ W1))
  k_gemm<INC, 0, 1><<<(NN + 127) / 128, 256, 0, stream>>>(x, nullptr, Wt1h, Wt1l, nullptr, dis, nullptr, xw16, NN);
  k_gather<<<(NN + 3) / 4, 256, 0, stream>>>(xw16, csr, rp, dis, b1, h16, NN);

  // layer 2: xw' = fp16(dis.row * (h @ W2))
  k_gemm<HC, 2, 1><<<(NN + 127) / 128, 256, 0, stream>>>(nullptr, h16, Wt2h, Wt2l, nullptr, dis, nullptr, xw16, NN);
  k_gather<<<(NN + 3) / 4, 256, 0, stream>>>(xw16, csr, rp, dis, b2, h16, NN);

  // classifier: z = relu(flat @ Wc1 + bc1), flat = h16 viewed [BSZ][384]
  k_gemm<3 * HC, 2, 2><<<(BSZ + 127) / 128, 256, 0, stream>>>(nullptr, h16, Wtc1h, Wtc1l, bc1, nullptr, zbuf, nullptr, BSZ);
  k_head<<<BSZ / 4, 256, 0, stream>>>(zbuf, Wc2, bc2, out, BSZ);
}

// Round 6
// 296.409 us; speedup vs baseline: 10.4567x; 1.0608x over previous
//
#include <hip/hip_runtime.h>

#define NN 150000
#define EE 600000
#define INC 64
#define HC 128
#define OC 10
#define BSZ 50000

typedef long long ll;
typedef _Float16 f16;
typedef __attribute__((ext_vector_type(8))) short short8v;
typedef __attribute__((ext_vector_type(4))) float f32x4;

__device__ __forceinline__ ushort f2bf(float f) {
  uint u = __float_as_uint(f);
  uint r = (u + 0x7fffu + ((u >> 16) & 1u)) >> 16;
  return (ushort)r;
}
__device__ __forceinline__ float bf2f(ushort h) {
  return __uint_as_float(((uint)h) << 16);
}
__device__ __forceinline__ float h2f(ushort u) {
  f16 h;
  __builtin_memcpy(&h, &u, 2);
  return (float)h;
}
__device__ __forceinline__ ushort f2h(float f) {
  f16 h = (f16)f;
  ushort u;
  __builtin_memcpy(&u, &h, 2);
  return u;
}

// ---------- CSR build ----------

__global__ __launch_bounds__(256) void k_zero_i(int* d, int n) {
  int i = blockIdx.x * 256 + threadIdx.x;
  if (i < n) d[i] = 0;
}

__global__ __launch_bounds__(256) void k_count(const int* __restrict__ col, int* cnt, int e) {
  int i = blockIdx.x * 256 + threadIdx.x;
  if (i < e) atomicAdd(&cnt[col[i]], 1);
}

__global__ __launch_bounds__(256) void k_scan1(const int* __restrict__ cnt, int* ex, int* bsum,
                                               float* __restrict__ dis, int n) {
  __shared__ int s[256];
  const int t = threadIdx.x;
  const int base = blockIdx.x * 1024 + t * 4;
  int v[4], tot = 0;
#pragma unroll
  for (int i = 0; i < 4; ++i) {
    v[i] = (base + i < n) ? cnt[base + i] : 0;
    tot += v[i];
    if (base + i < n) dis[base + i] = rsqrtf((float)(1 + v[i]));
  }
  s[t] = tot;
  __syncthreads();
#pragma unroll
  for (int off = 1; off < 256; off <<= 1) {
    int x = (t >= off) ? s[t - off] : 0;
    __syncthreads();
    s[t] += x;
    __syncthreads();
  }
  int run = s[t] - tot;
#pragma unroll
  for (int i = 0; i < 4; ++i) {
    if (base + i < n) ex[base + i] = run;
    run += v[i];
  }
  if (t == 255) bsum[blockIdx.x] = s[255];
}

__global__ __launch_bounds__(256) void k_scan2(int* bsum, int nb) {
  __shared__ int s[256];
  const int t = threadIdx.x;
  int v = (t < nb) ? bsum[t] : 0;
  s[t] = v;
  __syncthreads();
#pragma unroll
  for (int off = 1; off < 256; off <<= 1) {
    int x = (t >= off) ? s[t - off] : 0;
    __syncthreads();
    s[t] += x;
    __syncthreads();
  }
  if (t < nb) bsum[t] = s[t] - v;
}

__global__ __launch_bounds__(256) void k_scan3(int* rp, const int* __restrict__ bsum, int n, int e) {
  const int base = blockIdx.x * 1024 + threadIdx.x * 4;
  const int off = bsum[blockIdx.x];
#pragma unroll
  for (int i = 0; i < 4; ++i)
    if (base + i < n) rp[base + i] += off;
  if (blockIdx.x == 0 && threadIdx.x == 0) rp[n] = e;
}

__global__ __launch_bounds__(256) void k_fill_csr(const int* __restrict__ ei,
                                                  const int* __restrict__ rp,
                                                  int* fill, int* csr, int e) {
  int i = blockIdx.x * 256 + threadIdx.x;
  if (i >= e) return;
  int r = ei[i];
  int c = ei[EE + i];
  int slot = rp[c] + atomicAdd(&fill[c], 1);
  csr[slot] = r;
}

// ---------- weight prep (all 3 weights in one kernel) ----------
__global__ __launch_bounds__(256) void k_wprep_all(const float* __restrict__ W1,
                                                   const float* __restrict__ W2,
                                                   const float* __restrict__ Wc1,
                                                   ushort* t1h, ushort* t1l,
                                                   ushort* t2h, ushort* t2l,
                                                   ushort* tch, ushort* tcl) {
  int t = blockIdx.x * 256 + threadIdx.x;
  const float* W; ushort* th; ushort* tl; int K, idx;
  if (t < 64 * 128)                { W = W1;  th = t1h; tl = t1l; K = 64;  idx = t; }
  else if (t < (64 + 128) * 128)   { W = W2;  th = t2h; tl = t2l; K = 128; idx = t - 64 * 128; }
  else if (t < (64 + 128 + 384) * 128) { W = Wc1; th = tch; tl = tcl; K = 384; idx = t - (64 + 128) * 128; }
  else return;
  int col = idx & 127;
  int k = idx >> 7;
  float v = W[(ll)k * 128 + col];
  ushort h = f2bf(v);
  th[(ll)col * K + k] = h;
  tl[(ll)col * K + k] = f2bf(v - bf2f(h));
}

// ---------- MFMA GEMM: Y[nrows][128] = X[nrows][K] @ W[K][128] ----------
// split-bf16: C = Ah*Bh + Ah*Bl + Al*Bh  (fp32 accumulate)
// ASRC 0: X fp32, split in-register. ASRC 2: X fp16, split in-register (exact).
// MODE 1: Y16 = fp16( dis[row] * Y ).  MODE 2: Yf = relu(Y + bias) fp32.
template<int K, int ASRC, int MODE>
__global__ __launch_bounds__(256) void k_gemm(const float* __restrict__ Xf,
                                              const ushort* __restrict__ Xh16,
                                              const ushort* __restrict__ Wth,
                                              const ushort* __restrict__ Wtl,
                                              const float* __restrict__ bias,
                                              const float* __restrict__ dis,
                                              float* __restrict__ Yf,
                                              ushort* __restrict__ Y16, int nrows) {
  __shared__ ushort sAh[128][40];
  __shared__ ushort sAl[128][40];
  __shared__ ushort sBh[128][40];
  __shared__ ushort sBl[128][40];
  const int t = threadIdx.x;
  const int lane = t & 63;
  const int wid = t >> 6;
  const int wr = wid >> 1, wc = wid & 1;
  const int row0 = blockIdx.x * 128;

  f32x4 acc[4][4];
#pragma unroll
  for (int m = 0; m < 4; ++m)
#pragma unroll
    for (int n = 0; n < 4; ++n) acc[m][n] = (f32x4){0.f, 0.f, 0.f, 0.f};

  const int srow = t >> 1;
  const int shalf = t & 1;

  for (int kc = 0; kc < K; kc += 32) {
    __syncthreads();
    // ---- stage A tile (128 rows x 32 k): load 16 elems, split to bf16 hi/lo ----
    {
      float f[16];
      const ll rg = row0 + srow;
      if (rg < nrows) {
        if (ASRC == 0) {
          const float4* p = (const float4*)(Xf + rg * K + kc + shalf * 16);
#pragma unroll
          for (int i = 0; i < 4; ++i) {
            float4 v = p[i];
            f[i * 4] = v.x; f[i * 4 + 1] = v.y; f[i * 4 + 2] = v.z; f[i * 4 + 3] = v.w;
          }
        } else {
          const short8v* p = (const short8v*)(Xh16 + rg * K + kc + shalf * 16);
          union { short8v v[2]; ushort u[16]; } raw;
          raw.v[0] = p[0]; raw.v[1] = p[1];
#pragma unroll
          for (int i = 0; i < 16; ++i) f[i] = h2f(raw.u[i]);
        }
      } else {
#pragma unroll
        for (int i = 0; i < 16; ++i) f[i] = 0.f;
      }
      union { ushort u[16]; short8v v[2]; } hu, lu;
#pragma unroll
      for (int i = 0; i < 16; ++i) {
        ushort h = f2bf(f[i]);
        hu.u[i] = h;
        lu.u[i] = f2bf(f[i] - bf2f(h));
      }
      *(short8v*)&sAh[srow][shalf * 16] = hu.v[0];
      *(short8v*)&sAh[srow][shalf * 16 + 8] = hu.v[1];
      *(short8v*)&sAl[srow][shalf * 16] = lu.v[0];
      *(short8v*)&sAl[srow][shalf * 16 + 8] = lu.v[1];
    }
    // ---- stage B tile from pre-split transposed weights ----
    {
      const short8v* ph = (const short8v*)(Wth + (ll)srow * K + kc + shalf * 16);
      const short8v* pl = (const short8v*)(Wtl + (ll)srow * K + kc + shalf * 16);
      short8v h0 = ph[0], h1 = ph[1], l0 = pl[0], l1 = pl[1];
      *(short8v*)&sBh[srow][shalf * 16] = h0;
      *(short8v*)&sBh[srow][shalf * 16 + 8] = h1;
      *(short8v*)&sBl[srow][shalf * 16] = l0;
      *(short8v*)&sBl[srow][shalf * 16 + 8] = l1;
    }
    __syncthreads();
    const int kq = (lane >> 4) * 8;
    const int fr = lane & 15;
    short8v ah[4], al[4], bh[4], bl[4];
#pragma unroll
    for (int m = 0; m < 4; ++m) {
      const int r = wr * 64 + m * 16 + fr;
      ah[m] = *(const short8v*)&sAh[r][kq];
      al[m] = *(const short8v*)&sAl[r][kq];
    }
#pragma unroll
    for (int n = 0; n < 4; ++n) {
      const int c = wc * 64 + n * 16 + fr;
      bh[n] = *(const short8v*)&sBh[c][kq];
      bl[n] = *(const short8v*)&sBl[c][kq];
    }
#pragma unroll
    for (int m = 0; m < 4; ++m)
#pragma unroll
      for (int n = 0; n < 4; ++n) {
        acc[m][n] = __builtin_amdgcn_mfma_f32_16x16x32_bf16(ah[m], bh[n], acc[m][n], 0, 0, 0);
        acc[m][n] = __builtin_amdgcn_mfma_f32_16x16x32_bf16(ah[m], bl[n], acc[m][n], 0, 0, 0);
        acc[m][n] = __builtin_amdgcn_mfma_f32_16x16x32_bf16(al[m], bh[n], acc[m][n], 0, 0, 0);
      }
  }

#pragma unroll
  for (int m = 0; m < 4; ++m)
#pragma unroll
    for (int q = 0; q < 4; ++q) {
      const int rl = wr * 64 + m * 16 + (lane >> 4) * 4 + q;
      const ll rg = row0 + rl;
      if (rg >= nrows) continue;
      const float ds = (MODE == 1) ? dis[rg] : 0.f;
#pragma unroll
      for (int n = 0; n < 4; ++n) {
        const int col = wc * 64 + n * 16 + (lane & 15);
        float v = acc[m][n][q];
        if (MODE == 1) {
          Y16[rg * HC + col] = f2h(v * ds);
        } else {
          Yf[rg * HC + col] = fmaxf(v + bias[col], 0.f);
        }
      }
    }
}

// ---------- gather v2: parallel index prefetch + 4-deep independent row loads ----------
// h[c] = fp16( relu(b + dis[c]*(xw'[c] + sum_src xw'[src])) ); xw' pre-scaled by dis[src].
__global__ __launch_bounds__(256) void k_gather(const ushort* __restrict__ xw16,
                                                const int* __restrict__ csr,
                                                const int* __restrict__ rp,
                                                const float* __restrict__ dis,
                                                const float* __restrict__ bias,
                                                ushort* __restrict__ h16, int n) {
  const int wid = blockIdx.x * 4 + (threadIdx.x >> 6);
  const int lane = threadIdx.x & 63;
  if (wid >= n) return;
  const int s = rp[wid], e = rp[wid + 1];
  const int deg = e - s;
  const uint* xwu = (const uint*)xw16;   // 64 uints per row

  // prefetch all edge indices for this node in ONE parallel load (deg<=64 fast path)
  int myidx = 0;
  if (lane < deg) myidx = csr[s + lane];

  uint sv = xwu[(ll)wid * 64 + lane];    // self term (pre-scaled by dis)
  float2 acc = make_float2(h2f((ushort)(sv & 0xffff)), h2f((ushort)(sv >> 16)));

  const int dfast = (deg < 64) ? deg : 64;
  int j = 0;
  for (; j + 4 <= dfast; j += 4) {       // 4 independent row loads in flight
    const int r0 = __shfl(myidx, j);
    const int r1 = __shfl(myidx, j + 1);
    const int r2 = __shfl(myidx, j + 2);
    const int r3 = __shfl(myidx, j + 3);
    const uint v0 = xwu[(ll)r0 * 64 + lane];
    const uint v1 = xwu[(ll)r1 * 64 + lane];
    const uint v2 = xwu[(ll)r2 * 64 + lane];
    const uint v3 = xwu[(ll)r3 * 64 + lane];
    acc.x += (h2f((ushort)(v0 & 0xffff)) + h2f((ushort)(v1 & 0xffff)))
           + (h2f((ushort)(v2 & 0xffff)) + h2f((ushort)(v3 & 0xffff)));
    acc.y += (h2f((ushort)(v0 >> 16)) + h2f((ushort)(v1 >> 16)))
           + (h2f((ushort)(v2 >> 16)) + h2f((ushort)(v3 >> 16)));
  }
  for (; j < dfast; ++j) {
    const int r = __shfl(myidx, j);
    const uint v = xwu[(ll)r * 64 + lane];
    acc.x += h2f((ushort)(v & 0xffff));
    acc.y += h2f((ushort)(v >> 16));
  }
  for (; j < deg; ++j) {                 // rare spill path (deg > 64)
    const uint v = xwu[(ll)csr[s + j] * 64 + lane];
    acc.x += h2f((ushort)(v & 0xffff));
    acc.y += h2f((ushort)(v >> 16));
  }

  const float dc = dis[wid];
  const float2 b = ((const float2*)bias)[lane];
  const float r0 = fmaxf(fmaf(dc, acc.x, b.x), 0.f);
  const float r1 = fmaxf(fmaf(dc, acc.y, b.y), 0.f);
  ((uint*)h16)[(ll)wid * 64 + lane] = (uint)f2h(r0) | ((uint)f2h(r1) << 16);
}

// ---------- head: z @ Wc2 + bc2 -> log_softmax ----------
__global__ __launch_bounds__(256) void k_head(const float* __restrict__ Z,
                                              const float* __restrict__ Wc2,
                                              const float* __restrict__ bc2,
                                              float* __restrict__ out, int nrows) {
  __shared__ float sW[HC * OC];
  __shared__ float sB[OC];
  for (int i = threadIdx.x; i < HC * OC; i += 256) sW[i] = Wc2[i];
  if (threadIdx.x < OC) sB[threadIdx.x] = bc2[threadIdx.x];
  __syncthreads();
  const int wid = threadIdx.x >> 6;
  const int lane = threadIdx.x & 63;
  const int row = blockIdx.x * 4 + wid;
  if (row >= nrows) return;
  const float z0 = Z[(ll)row * HC + lane];
  const float z1 = Z[(ll)row * HC + 64 + lane];
  float a[OC];
#pragma unroll
  for (int o = 0; o < OC; ++o)
    a[o] = z0 * sW[lane * OC + o] + z1 * sW[(lane + 64) * OC + o];
#pragma unroll
  for (int o = 0; o < OC; ++o)
#pragma unroll
    for (int m = 32; m; m >>= 1) a[o] += __shfl_xor(a[o], m, 64);
  float mx = -1e30f;
#pragma unroll
  for (int o = 0; o < OC; ++o) { a[o] += sB[o]; mx = fmaxf(mx, a[o]); }
  float s = 0.f;
#pragma unroll
  for (int o = 0; o < OC; ++o) s += expf(a[o] - mx);
  const float lse = mx + logf(s);
  float v = 0.f;
#pragma unroll
  for (int o = 0; o < OC; ++o) v = (lane == o) ? a[o] - lse : v;
  if (lane < OC) out[(ll)row * OC + lane] = v;
}

extern "C" void kernel_launch(void* const* d_in, const int* in_sizes, int n_in,
                              void* d_out, int out_size, void* d_ws, size_t ws_size,
                              hipStream_t stream) {
  const float* x   = (const float*)d_in[0];
  const int*   ei  = (const int*)d_in[1];   // [2][E] int32
  const float* W1  = (const float*)d_in[2];
  const float* b1  = (const float*)d_in[3];
  const float* W2  = (const float*)d_in[4];
  const float* b2  = (const float*)d_in[5];
  const float* Wc1 = (const float*)d_in[6];
  const float* bc1 = (const float*)d_in[7];
  const float* Wc2 = (const float*)d_in[8];
  const float* bc2 = (const float*)d_in[9];
  float* out = (float*)d_out;

  char* ws = (char*)d_ws;
  ushort* xw16 = (ushort*)(ws);                       // xw' fp16 [N][128] 38.4MB
  ushort* h16  = (ushort*)(ws + 38400000LL);          // h   fp16 [N][128] 38.4MB
  float*  zbuf = (float*)(ws + 76800000LL);           // z fp32 [BSZ][128] 25.6MB
  const ll CSRB = 102400000LL;
  float* dis  = (float*)(ws + CSRB);                  // N floats
  int*   rp   = (int*)  (ws + CSRB + 600064LL);       // N+1
  int*   csr  = (int*)  (ws + CSRB + 1200128LL);      // E
  int*   cnt  = (int*)  (ws + CSRB + 3600128LL);      // 150016
  int*   fill = (int*)  (ws + CSRB + 4200192LL);      // 150016
  int*   bsum = (int*)  (ws + CSRB + 4800256LL);      // 256
  ushort* Wt1h = (ushort*)(ws + CSRB + 4801280LL);    // 128*64
  ushort* Wt1l = (ushort*)(ws + CSRB + 4817664LL);
  ushort* Wt2h = (ushort*)(ws + CSRB + 4834048LL);    // 128*128
  ushort* Wt2l = (ushort*)(ws + CSRB + 4866816LL);
  ushort* Wtc1h = (ushort*)(ws + CSRB + 4899584LL);   // 128*384
  ushort* Wtc1l = (ushort*)(ws + CSRB + 4997888LL);

  const int nb = (NN + 1023) / 1024;

  // CSR build
  k_zero_i<<<(2 * 150016 + 255) / 256, 256, 0, stream>>>(cnt, 2 * 150016);
  k_count<<<(EE + 255) / 256, 256, 0, stream>>>(ei + EE, cnt, EE);
  k_scan1<<<nb, 256, 0, stream>>>(cnt, rp, bsum, dis, NN);
  k_scan2<<<1, 256, 0, stream>>>(bsum, nb);
  k_scan3<<<nb, 256, 0, stream>>>(rp, bsum, NN, EE);
  k_fill_csr<<<(EE + 255) / 256, 256, 0, stream>>>(ei, rp, fill, csr, EE);

  // weight split+transpose
  k_wprep_all<<<((64 + 128 + 384) * 128 + 255) / 256, 256, 0, stream>>>(
      W1, W2, Wc1, Wt1h, Wt1l, Wt2h, Wt2l, Wtc1h, Wtc1l);

  // layer 1: xw' = fp16(dis.row * (x @ W1))
  k_gemm<INC, 0, 1><<<(NN + 127) / 128, 256, 0, stream>>>(x, nullptr, Wt1h, Wt1l, nullptr, dis, nullptr, xw16, NN);
  k_gather<<<(NN + 3) / 4, 256, 0, stream>>>(xw16, csr, rp, dis, b1, h16, NN);

  // layer 2: xw' = fp16(dis.row * (h @ W2))
  k_gemm<HC, 2, 1><<<(NN + 127) / 128, 256, 0, stream>>>(nullptr, h16, Wt2h, Wt2l, nullptr, dis, nullptr, xw16, NN);
  k_gather<<<(NN + 3) / 4, 256, 0, stream>>>(xw16, csr, rp, dis, b2, h16, NN);

  // classifier: z = relu(flat @ Wc1 + bc1), flat = h16 viewed [BSZ][384]
  k_gemm<3 * HC, 2, 2><<<(BSZ + 127) / 128, 256, 0, stream>>>(nullptr, h16, Wtc1h, Wtc1l, bc1, nullptr, zbuf, nullptr, BSZ);
  k_head<<<BSZ / 4, 256, 0, stream>>>(zbuf, Wc2, bc2, out, BSZ);
}

// Round 7
// 265.337 us; speedup vs baseline: 11.6812x; 1.1171x over previous
//
#include <hip/hip_runtime.h>

#define NN 150000
#define EE 600000
#define INC 64
#define HC 128
#define OC 10
#define BSZ 50000

typedef long long ll;
typedef _Float16 f16;
typedef __attribute__((ext_vector_type(8))) short short8v;
typedef __attribute__((ext_vector_type(4))) float f32x4;

__device__ __forceinline__ ushort f2bf(float f) {
  uint u = __float_as_uint(f);
  uint r = (u + 0x7fffu + ((u >> 16) & 1u)) >> 16;
  return (ushort)r;
}
__device__ __forceinline__ float bf2f(ushort h) {
  return __uint_as_float(((uint)h) << 16);
}
__device__ __forceinline__ float h2f(ushort u) {
  f16 h;
  __builtin_memcpy(&h, &u, 2);
  return (float)h;
}
__device__ __forceinline__ ushort f2h(float f) {
  f16 h = (f16)f;
  ushort u;
  __builtin_memcpy(&u, &h, 2);
  return u;
}

// ---------- CSR build ----------

__global__ __launch_bounds__(256) void k_zero_i(int* d, int n) {
  int i = blockIdx.x * 256 + threadIdx.x;
  if (i < n) d[i] = 0;
}

__global__ __launch_bounds__(256) void k_count(const int* __restrict__ col, int* cnt, int e) {
  int i = blockIdx.x * 256 + threadIdx.x;
  if (i < e) atomicAdd(&cnt[col[i]], 1);
}

__global__ __launch_bounds__(256) void k_scan1(const int* __restrict__ cnt, int* ex, int* bsum,
                                               float* __restrict__ dis, int n) {
  __shared__ int s[256];
  const int t = threadIdx.x;
  const int base = blockIdx.x * 1024 + t * 4;
  int v[4], tot = 0;
#pragma unroll
  for (int i = 0; i < 4; ++i) {
    v[i] = (base + i < n) ? cnt[base + i] : 0;
    tot += v[i];
    if (base + i < n) dis[base + i] = rsqrtf((float)(1 + v[i]));
  }
  s[t] = tot;
  __syncthreads();
#pragma unroll
  for (int off = 1; off < 256; off <<= 1) {
    int x = (t >= off) ? s[t - off] : 0;
    __syncthreads();
    s[t] += x;
    __syncthreads();
  }
  int run = s[t] - tot;
#pragma unroll
  for (int i = 0; i < 4; ++i) {
    if (base + i < n) ex[base + i] = run;
    run += v[i];
  }
  if (t == 255) bsum[blockIdx.x] = s[255];
}

__global__ __launch_bounds__(256) void k_scan2(int* bsum, int nb) {
  __shared__ int s[256];
  const int t = threadIdx.x;
  int v = (t < nb) ? bsum[t] : 0;
  s[t] = v;
  __syncthreads();
#pragma unroll
  for (int off = 1; off < 256; off <<= 1) {
    int x = (t >= off) ? s[t - off] : 0;
    __syncthreads();
    s[t] += x;
    __syncthreads();
  }
  if (t < nb) bsum[t] = s[t] - v;
}

__global__ __launch_bounds__(256) void k_scan3(int* rp, const int* __restrict__ bsum, int n, int e) {
  const int base = blockIdx.x * 1024 + threadIdx.x * 4;
  const int off = bsum[blockIdx.x];
#pragma unroll
  for (int i = 0; i < 4; ++i)
    if (base + i < n) rp[base + i] += off;
  if (blockIdx.x == 0 && threadIdx.x == 0) rp[n] = e;
}

__global__ __launch_bounds__(256) void k_fill_csr(const int* __restrict__ ei,
                                                  const int* __restrict__ rp,
                                                  int* fill, int* csr, int e) {
  int i = blockIdx.x * 256 + threadIdx.x;
  if (i >= e) return;
  int r = ei[i];
  int c = ei[EE + i];
  int slot = rp[c] + atomicAdd(&fill[c], 1);
  csr[slot] = r;
}

// ---------- weight prep (all 3 weights in one kernel) ----------
__global__ __launch_bounds__(256) void k_wprep_all(const float* __restrict__ W1,
                                                   const float* __restrict__ W2,
                                                   const float* __restrict__ Wc1,
                                                   ushort* t1h, ushort* t1l,
                                                   ushort* t2h, ushort* t2l,
                                                   ushort* tch, ushort* tcl) {
  int t = blockIdx.x * 256 + threadIdx.x;
  const float* W; ushort* th; ushort* tl; int K, idx;
  if (t < 64 * 128)                { W = W1;  th = t1h; tl = t1l; K = 64;  idx = t; }
  else if (t < (64 + 128) * 128)   { W = W2;  th = t2h; tl = t2l; K = 128; idx = t - 64 * 128; }
  else if (t < (64 + 128 + 384) * 128) { W = Wc1; th = tch; tl = tcl; K = 384; idx = t - (64 + 128) * 128; }
  else return;
  int col = idx & 127;
  int k = idx >> 7;
  float v = W[(ll)k * 128 + col];
  ushort h = f2bf(v);
  th[(ll)col * K + k] = h;
  tl[(ll)col * K + k] = f2bf(v - bf2f(h));
}

// ---------- MFMA GEMM: Y[nrows][128] = X[nrows][K] @ W[K][128] ----------
// split-bf16: C = Ah*Bh + Ah*Bl + Al*Bh  (fp32 accumulate)
// ASRC 0: X fp32, split in-register. ASRC 2: X fp16, split in-register (exact).
// MODE 1: Y16 = fp16( dis[row] * Y ).  MODE 2: Yf = relu(Y + bias) fp32.
template<int K, int ASRC, int MODE>
__global__ __launch_bounds__(256) void k_gemm(const float* __restrict__ Xf,
                                              const ushort* __restrict__ Xh16,
                                              const ushort* __restrict__ Wth,
                                              const ushort* __restrict__ Wtl,
                                              const float* __restrict__ bias,
                                              const float* __restrict__ dis,
                                              float* __restrict__ Yf,
                                              ushort* __restrict__ Y16, int nrows) {
  __shared__ ushort sAh[128][40];
  __shared__ ushort sAl[128][40];
  __shared__ ushort sBh[128][40];
  __shared__ ushort sBl[128][40];
  const int t = threadIdx.x;
  const int lane = t & 63;
  const int wid = t >> 6;
  const int wr = wid >> 1, wc = wid & 1;
  const int row0 = blockIdx.x * 128;

  f32x4 acc[4][4];
#pragma unroll
  for (int m = 0; m < 4; ++m)
#pragma unroll
    for (int n = 0; n < 4; ++n) acc[m][n] = (f32x4){0.f, 0.f, 0.f, 0.f};

  const int srow = t >> 1;
  const int shalf = t & 1;

  for (int kc = 0; kc < K; kc += 32) {
    __syncthreads();
    // ---- stage A tile (128 rows x 32 k): load 16 elems, split to bf16 hi/lo ----
    {
      float f[16];
      const ll rg = row0 + srow;
      if (rg < nrows) {
        if (ASRC == 0) {
          const float4* p = (const float4*)(Xf + rg * K + kc + shalf * 16);
#pragma unroll
          for (int i = 0; i < 4; ++i) {
            float4 v = p[i];
            f[i * 4] = v.x; f[i * 4 + 1] = v.y; f[i * 4 + 2] = v.z; f[i * 4 + 3] = v.w;
          }
        } else {
          const short8v* p = (const short8v*)(Xh16 + rg * K + kc + shalf * 16);
          union { short8v v[2]; ushort u[16]; } raw;
          raw.v[0] = p[0]; raw.v[1] = p[1];
#pragma unroll
          for (int i = 0; i < 16; ++i) f[i] = h2f(raw.u[i]);
        }
      } else {
#pragma unroll
        for (int i = 0; i < 16; ++i) f[i] = 0.f;
      }
      union { ushort u[16]; short8v v[2]; } hu, lu;
#pragma unroll
      for (int i = 0; i < 16; ++i) {
        ushort h = f2bf(f[i]);
        hu.u[i] = h;
        lu.u[i] = f2bf(f[i] - bf2f(h));
      }
      *(short8v*)&sAh[srow][shalf * 16] = hu.v[0];
      *(short8v*)&sAh[srow][shalf * 16 + 8] = hu.v[1];
      *(short8v*)&sAl[srow][shalf * 16] = lu.v[0];
      *(short8v*)&sAl[srow][shalf * 16 + 8] = lu.v[1];
    }
    // ---- stage B tile from pre-split transposed weights ----
    {
      const short8v* ph = (const short8v*)(Wth + (ll)srow * K + kc + shalf * 16);
      const short8v* pl = (const short8v*)(Wtl + (ll)srow * K + kc + shalf * 16);
      short8v h0 = ph[0], h1 = ph[1], l0 = pl[0], l1 = pl[1];
      *(short8v*)&sBh[srow][shalf * 16] = h0;
      *(short8v*)&sBh[srow][shalf * 16 + 8] = h1;
      *(short8v*)&sBl[srow][shalf * 16] = l0;
      *(short8v*)&sBl[srow][shalf * 16 + 8] = l1;
    }
    __syncthreads();
    const int kq = (lane >> 4) * 8;
    const int fr = lane & 15;
    short8v ah[4], al[4], bh[4], bl[4];
#pragma unroll
    for (int m = 0; m < 4; ++m) {
      const int r = wr * 64 + m * 16 + fr;
      ah[m] = *(const short8v*)&sAh[r][kq];
      al[m] = *(const short8v*)&sAl[r][kq];
    }
#pragma unroll
    for (int n = 0; n < 4; ++n) {
      const int c = wc * 64 + n * 16 + fr;
      bh[n] = *(const short8v*)&sBh[c][kq];
      bl[n] = *(const short8v*)&sBl[c][kq];
    }
#pragma unroll
    for (int m = 0; m < 4; ++m)
#pragma unroll
      for (int n = 0; n < 4; ++n) {
        acc[m][n] = __builtin_amdgcn_mfma_f32_16x16x32_bf16(ah[m], bh[n], acc[m][n], 0, 0, 0);
        acc[m][n] = __builtin_amdgcn_mfma_f32_16x16x32_bf16(ah[m], bl[n], acc[m][n], 0, 0, 0);
        acc[m][n] = __builtin_amdgcn_mfma_f32_16x16x32_bf16(al[m], bh[n], acc[m][n], 0, 0, 0);
      }
  }

#pragma unroll
  for (int m = 0; m < 4; ++m)
#pragma unroll
    for (int q = 0; q < 4; ++q) {
      const int rl = wr * 64 + m * 16 + (lane >> 4) * 4 + q;
      const ll rg = row0 + rl;
      if (rg >= nrows) continue;
      const float ds = (MODE == 1) ? dis[rg] : 0.f;
#pragma unroll
      for (int n = 0; n < 4; ++n) {
        const int col = wc * 64 + n * 16 + (lane & 15);
        float v = acc[m][n][q];
        if (MODE == 1) {
          Y16[rg * HC + col] = f2h(v * ds);
        } else {
          Yf[rg * HC + col] = fmaxf(v + bias[col], 0.f);
        }
      }
    }
}

// ---------- gather v3: quarter-wave per node (16 lanes x uint4 = 256B row) ----------
// 4 independent node chains per wave -> 4x outstanding-load concurrency.
// h[c] = fp16( relu(b + dis[c]*(xw'[c] + sum_src xw'[src])) ); xw' pre-scaled by dis[src].
__global__ __launch_bounds__(256) void k_gather(const ushort* __restrict__ xw16,
                                                const int* __restrict__ csr,
                                                const int* __restrict__ rp,
                                                const float* __restrict__ dis,
                                                const float* __restrict__ bias,
                                                ushort* __restrict__ h16, int n) {
  const int node = blockIdx.x * 16 + (threadIdx.x >> 4);   // 16 nodes / 256-thr block
  const int lane = threadIdx.x & 63;
  const int sl = lane & 15;                                 // sublane in 16-lane group
  if (node >= n) return;
  const int s = rp[node], e = rp[node + 1];
  const int deg = e - s;

  // prefetch this node's edge indices (one coalesced load covers deg<=16; P(deg>16)~0)
  int myidx = 0;
  if (sl < deg) myidx = csr[s + sl];

  const uint4* xwq = (const uint4*)xw16;                    // 16 uint4 per row
  uint4 sv = xwq[(ll)node * 16 + sl];                       // self term (pre-scaled)
  float a0 = h2f((ushort)(sv.x & 0xffff)), a1 = h2f((ushort)(sv.x >> 16));
  float a2 = h2f((ushort)(sv.y & 0xffff)), a3 = h2f((ushort)(sv.y >> 16));
  float a4 = h2f((ushort)(sv.z & 0xffff)), a5 = h2f((ushort)(sv.z >> 16));
  float a6 = h2f((ushort)(sv.w & 0xffff)), a7 = h2f((ushort)(sv.w >> 16));

  const int gbase = lane & 48;                              // group's base lane in wave
  const int dfast = (deg < 16) ? deg : 16;
  int j = 0;
  for (; j + 2 <= dfast; j += 2) {                          // 2-deep unroll x 4 groups = 8 rows in flight/wave
    const int r0 = __shfl(myidx, gbase + j);
    const int r1 = __shfl(myidx, gbase + j + 1);
    const uint4 v0 = xwq[(ll)r0 * 16 + sl];
    const uint4 v1 = xwq[(ll)r1 * 16 + sl];
    a0 += h2f((ushort)(v0.x & 0xffff)) + h2f((ushort)(v1.x & 0xffff));
    a1 += h2f((ushort)(v0.x >> 16))    + h2f((ushort)(v1.x >> 16));
    a2 += h2f((ushort)(v0.y & 0xffff)) + h2f((ushort)(v1.y & 0xffff));
    a3 += h2f((ushort)(v0.y >> 16))    + h2f((ushort)(v1.y >> 16));
    a4 += h2f((ushort)(v0.z & 0xffff)) + h2f((ushort)(v1.z & 0xffff));
    a5 += h2f((ushort)(v0.z >> 16))    + h2f((ushort)(v1.z >> 16));
    a6 += h2f((ushort)(v0.w & 0xffff)) + h2f((ushort)(v1.w & 0xffff));
    a7 += h2f((ushort)(v0.w >> 16))    + h2f((ushort)(v1.w >> 16));
  }
  if (j < dfast) {
    const int r = __shfl(myidx, gbase + j);
    const uint4 v = xwq[(ll)r * 16 + sl];
    a0 += h2f((ushort)(v.x & 0xffff)); a1 += h2f((ushort)(v.x >> 16));
    a2 += h2f((ushort)(v.y & 0xffff)); a3 += h2f((ushort)(v.y >> 16));
    a4 += h2f((ushort)(v.z & 0xffff)); a5 += h2f((ushort)(v.z >> 16));
    a6 += h2f((ushort)(v.w & 0xffff)); a7 += h2f((ushort)(v.w >> 16));
    ++j;
  }
  for (j = 16; j < deg; ++j) {                              // rare spill (deg > 16)
    const uint4 v = xwq[(ll)csr[s + j] * 16 + sl];
    a0 += h2f((ushort)(v.x & 0xffff)); a1 += h2f((ushort)(v.x >> 16));
    a2 += h2f((ushort)(v.y & 0xffff)); a3 += h2f((ushort)(v.y >> 16));
    a4 += h2f((ushort)(v.z & 0xffff)); a5 += h2f((ushort)(v.z >> 16));
    a6 += h2f((ushort)(v.w & 0xffff)); a7 += h2f((ushort)(v.w >> 16));
  }

  const float dc = dis[node];
  const float4* bias4 = (const float4*)bias;
  const float4 b0 = bias4[sl * 2];
  const float4 b1 = bias4[sl * 2 + 1];
  uint4 o;
  o.x = (uint)f2h(fmaxf(fmaf(dc, a0, b0.x), 0.f)) | ((uint)f2h(fmaxf(fmaf(dc, a1, b0.y), 0.f)) << 16);
  o.y = (uint)f2h(fmaxf(fmaf(dc, a2, b0.z), 0.f)) | ((uint)f2h(fmaxf(fmaf(dc, a3, b0.w), 0.f)) << 16);
  o.z = (uint)f2h(fmaxf(fmaf(dc, a4, b1.x), 0.f)) | ((uint)f2h(fmaxf(fmaf(dc, a5, b1.y), 0.f)) << 16);
  o.w = (uint)f2h(fmaxf(fmaf(dc, a6, b1.z), 0.f)) | ((uint)f2h(fmaxf(fmaf(dc, a7, b1.w), 0.f)) << 16);
  ((uint4*)h16)[(ll)node * 16 + sl] = o;
}

// ---------- head: z @ Wc2 + bc2 -> log_softmax ----------
__global__ __launch_bounds__(256) void k_head(const float* __restrict__ Z,
                                              const float* __restrict__ Wc2,
                                              const float* __restrict__ bc2,
                                              float* __restrict__ out, int nrows) {
  __shared__ float sW[HC * OC];
  __shared__ float sB[OC];
  for (int i = threadIdx.x; i < HC * OC; i += 256) sW[i] = Wc2[i];
  if (threadIdx.x < OC) sB[threadIdx.x] = bc2[threadIdx.x];
  __syncthreads();
  const int wid = threadIdx.x >> 6;
  const int lane = threadIdx.x & 63;
  const int row = blockIdx.x * 4 + wid;
  if (row >= nrows) return;
  const float z0 = Z[(ll)row * HC + lane];
  const float z1 = Z[(ll)row * HC + 64 + lane];
  float a[OC];
#pragma unroll
  for (int o = 0; o < OC; ++o)
    a[o] = z0 * sW[lane * OC + o] + z1 * sW[(lane + 64) * OC + o];
#pragma unroll
  for (int o = 0; o < OC; ++o)
#pragma unroll
    for (int m = 32; m; m >>= 1) a[o] += __shfl_xor(a[o], m, 64);
  float mx = -1e30f;
#pragma unroll
  for (int o = 0; o < OC; ++o) { a[o] += sB[o]; mx = fmaxf(mx, a[o]); }
  float s = 0.f;
#pragma unroll
  for (int o = 0; o < OC; ++o) s += expf(a[o] - mx);
  const float lse = mx + logf(s);
  float v = 0.f;
#pragma unroll
  for (int o = 0; o < OC; ++o) v = (lane == o) ? a[o] - lse : v;
  if (lane < OC) out[(ll)row * OC + lane] = v;
}

extern "C" void kernel_launch(void* const* d_in, const int* in_sizes, int n_in,
                              void* d_out, int out_size, void* d_ws, size_t ws_size,
                              hipStream_t stream) {
  const float* x   = (const float*)d_in[0];
  const int*   ei  = (const int*)d_in[1];   // [2][E] int32
  const float* W1  = (const float*)d_in[2];
  const float* b1  = (const float*)d_in[3];
  const float* W2  = (const float*)d_in[4];
  const float* b2  = (const float*)d_in[5];
  const float* Wc1 = (const float*)d_in[6];
  const float* bc1 = (const float*)d_in[7];
  const float* Wc2 = (const float*)d_in[8];
  const float* bc2 = (const float*)d_in[9];
  float* out = (float*)d_out;

  char* ws = (char*)d_ws;
  ushort* xw16 = (ushort*)(ws);                       // xw' fp16 [N][128] 38.4MB
  ushort* h16  = (ushort*)(ws + 38400000LL);          // h   fp16 [N][128] 38.4MB
  float*  zbuf = (float*)(ws + 76800000LL);           // z fp32 [BSZ][128] 25.6MB
  const ll CSRB = 102400000LL;
  float* dis  = (float*)(ws + CSRB);                  // N floats
  int*   rp   = (int*)  (ws + CSRB + 600064LL);       // N+1
  int*   csr  = (int*)  (ws + CSRB + 1200128LL);      // E
  int*   cnt  = (int*)  (ws + CSRB + 3600128LL);      // 150016
  int*   fill = (int*)  (ws + CSRB + 4200192LL);      // 150016
  int*   bsum = (int*)  (ws + CSRB + 4800256LL);      // 256
  ushort* Wt1h = (ushort*)(ws + CSRB + 4801280LL);    // 128*64
  ushort* Wt1l = (ushort*)(ws + CSRB + 4817664LL);
  ushort* Wt2h = (ushort*)(ws + CSRB + 4834048LL);    // 128*128
  ushort* Wt2l = (ushort*)(ws + CSRB + 4866816LL);
  ushort* Wtc1h = (ushort*)(ws + CSRB + 4899584LL);   // 128*384
  ushort* Wtc1l = (ushort*)(ws + CSRB + 4997888LL);

  const int nb = (NN + 1023) / 1024;

  // CSR build
  k_zero_i<<<(2 * 150016 + 255) / 256, 256, 0, stream>>>(cnt, 2 * 150016);
  k_count<<<(EE + 255) / 256, 256, 0, stream>>>(ei + EE, cnt, EE);
  k_scan1<<<nb, 256, 0, stream>>>(cnt, rp, bsum, dis, NN);
  k_scan2<<<1, 256, 0, stream>>>(bsum, nb);
  k_scan3<<<nb, 256, 0, stream>>>(rp, bsum, NN, EE);
  k_fill_csr<<<(EE + 255) / 256, 256, 0, stream>>>(ei, rp, fill, csr, EE);

  // weight split+transpose
  k_wprep_all<<<((64 + 128 + 384) * 128 + 255) / 256, 256, 0, stream>>>(
      W1, W2, Wc1, Wt1h, Wt1l, Wt2h, Wt2l, Wtc1h, Wtc1l);

  // layer 1: xw' = fp16(dis.row * (x @ W1))
  k_gemm<INC, 0, 1><<<(NN + 127) / 128, 256, 0, stream>>>(x, nullptr, Wt1h, Wt1l, nullptr, dis, nullptr, xw16, NN);
  k_gather<<<(NN + 15) / 16, 256, 0, stream>>>(xw16, csr, rp, dis, b1, h16, NN);

  // layer 2: xw' = fp16(dis.row * (h @ W2))
  k_gemm<HC, 2, 1><<<(NN + 127) / 128, 256, 0, stream>>>(nullptr, h16, Wt2h, Wt2l, nullptr, dis, nullptr, xw16, NN);
  k_gather<<<(NN + 15) / 16, 256, 0, stream>>>(xw16, csr, rp, dis, b2, h16, NN);

  // classifier: z = relu(flat @ Wc1 + bc1), flat = h16 viewed [BSZ][384]
  k_gemm<3 * HC, 2, 2><<<(BSZ + 127) / 128, 256, 0, stream>>>(nullptr, h16, Wtc1h, Wtc1l, bc1, nullptr, zbuf, nullptr, BSZ);
  k_head<<<BSZ / 4, 256, 0, stream>>>(zbuf, Wc2, bc2, out, BSZ);
}

// Round 8
// 233.615 us; speedup vs baseline: 13.2673x; 1.1358x over previous
//
#include <hip/hip_runtime.h>

#define NN 150000
#define EE 600000
#define INC 64
#define HC 128
#define OC 10
#define BSZ 50000

typedef long long ll;
typedef _Float16 f16;
typedef __attribute__((ext_vector_type(8))) short short8v;
typedef __attribute__((ext_vector_type(4))) float f32x4;

__device__ __forceinline__ ushort f2bf(float f) {
  uint u = __float_as_uint(f);
  uint r = (u + 0x7fffu + ((u >> 16) & 1u)) >> 16;
  return (ushort)r;
}
__device__ __forceinline__ float bf2f(ushort h) {
  return __uint_as_float(((uint)h) << 16);
}
__device__ __forceinline__ float h2f(ushort u) {
  f16 h;
  __builtin_memcpy(&h, &u, 2);
  return (float)h;
}
__device__ __forceinline__ ushort f2h(float f) {
  f16 h = (f16)f;
  ushort u;
  __builtin_memcpy(&u, &h, 2);
  return u;
}

// ---------- CSR build ----------

__global__ __launch_bounds__(256) void k_zero_i(int* d, int n) {
  int i = blockIdx.x * 256 + threadIdx.x;
  if (i < n) d[i] = 0;
}

__global__ __launch_bounds__(256) void k_count(const int* __restrict__ col, int* cnt, int e) {
  int i = blockIdx.x * 256 + threadIdx.x;
  if (i < e) atomicAdd(&cnt[col[i]], 1);
}

__global__ __launch_bounds__(256) void k_scan1(const int* __restrict__ cnt, int* ex, int* bsum,
                                               float* __restrict__ dis, int n) {
  __shared__ int s[256];
  const int t = threadIdx.x;
  const int base = blockIdx.x * 1024 + t * 4;
  int v[4], tot = 0;
#pragma unroll
  for (int i = 0; i < 4; ++i) {
    v[i] = (base + i < n) ? cnt[base + i] : 0;
    tot += v[i];
    if (base + i < n) dis[base + i] = rsqrtf((float)(1 + v[i]));
  }
  s[t] = tot;
  __syncthreads();
#pragma unroll
  for (int off = 1; off < 256; off <<= 1) {
    int x = (t >= off) ? s[t - off] : 0;
    __syncthreads();
    s[t] += x;
    __syncthreads();
  }
  int run = s[t] - tot;
#pragma unroll
  for (int i = 0; i < 4; ++i) {
    if (base + i < n) ex[base + i] = run;
    run += v[i];
  }
  if (t == 255) bsum[blockIdx.x] = s[255];
}

__global__ __launch_bounds__(256) void k_scan2(int* bsum, int nb) {
  __shared__ int s[256];
  const int t = threadIdx.x;
  int v = (t < nb) ? bsum[t] : 0;
  s[t] = v;
  __syncthreads();
#pragma unroll
  for (int off = 1; off < 256; off <<= 1) {
    int x = (t >= off) ? s[t - off] : 0;
    __syncthreads();
    s[t] += x;
    __syncthreads();
  }
  if (t < nb) bsum[t] = s[t] - v;
}

__global__ __launch_bounds__(256) void k_scan3(int* rp, const int* __restrict__ bsum, int n, int e) {
  const int base = blockIdx.x * 1024 + threadIdx.x * 4;
  const int off = bsum[blockIdx.x];
#pragma unroll
  for (int i = 0; i < 4; ++i)
    if (base + i < n) rp[base + i] += off;
  if (blockIdx.x == 0 && threadIdx.x == 0) rp[n] = e;
}

__global__ __launch_bounds__(256) void k_fill_csr(const int* __restrict__ ei,
                                                  const int* __restrict__ rp,
                                                  int* fill, int* csr, int e) {
  int i = blockIdx.x * 256 + threadIdx.x;
  if (i >= e) return;
  int r = ei[i];
  int c = ei[EE + i];
  int slot = rp[c] + atomicAdd(&fill[c], 1);
  csr[slot] = r;
}

// ---------- weight prep: W1, W2, Wc1 transposed+split; Wc2 transposed+split padded to 16 cols ----------
__global__ __launch_bounds__(256) void k_wprep_all(const float* __restrict__ W1,
                                                   const float* __restrict__ W2,
                                                   const float* __restrict__ Wc1,
                                                   const float* __restrict__ Wc2,
                                                   ushort* t1h, ushort* t1l,
                                                   ushort* t2h, ushort* t2l,
                                                   ushort* tch, ushort* tcl,
                                                   ushort* t2ch, ushort* t2cl) {
  int t = blockIdx.x * 256 + threadIdx.x;
  if (t < (64 + 128 + 384) * 128) {
    const float* W; ushort* th; ushort* tl; int K, idx;
    if (t < 64 * 128)              { W = W1;  th = t1h; tl = t1l; K = 64;  idx = t; }
    else if (t < (64 + 128) * 128) { W = W2;  th = t2h; tl = t2l; K = 128; idx = t - 64 * 128; }
    else                           { W = Wc1; th = tch; tl = tcl; K = 384; idx = t - (64 + 128) * 128; }
    int col = idx & 127;
    int k = idx >> 7;
    float v = W[(ll)k * 128 + col];
    ushort h = f2bf(v);
    th[(ll)col * K + k] = h;
    tl[(ll)col * K + k] = f2bf(v - bf2f(h));
  } else if (t < (64 + 128 + 384) * 128 + 16 * 128) {
    int idx = t - (64 + 128 + 384) * 128;   // 0..2047
    int col = idx >> 7;                     // 0..15
    int k = idx & 127;
    float v = (col < OC) ? Wc2[(ll)k * OC + col] : 0.f;
    ushort h = f2bf(v);
    t2ch[col * 128 + k] = h;
    t2cl[col * 128 + k] = f2bf(v - bf2f(h));
  }
}

// ---------- MFMA GEMM: Y[nrows][128] = X[nrows][K] @ W[K][128] ----------
// split-bf16: C = Ah*Bh + Ah*Bl + Al*Bh  (fp32 accumulate)
// ASRC 0: X fp32, split in-register. ASRC 2: X fp16, split in-register (exact).
// MODE 1: Y16 = fp16( dis[row] * Y ).  MODE 2: Yf = relu(Y+bias) fp32.  MODE 4: Y16 = fp16(relu(Y+bias)).
template<int K, int ASRC, int MODE>
__global__ __launch_bounds__(256) void k_gemm(const float* __restrict__ Xf,
                                              const ushort* __restrict__ Xh16,
                                              const ushort* __restrict__ Wth,
                                              const ushort* __restrict__ Wtl,
                                              const float* __restrict__ bias,
                                              const float* __restrict__ dis,
                                              float* __restrict__ Yf,
                                              ushort* __restrict__ Y16, int nrows) {
  __shared__ ushort sAh[128][40];
  __shared__ ushort sAl[128][40];
  __shared__ ushort sBh[128][40];
  __shared__ ushort sBl[128][40];
  const int t = threadIdx.x;
  const int lane = t & 63;
  const int wid = t >> 6;
  const int wr = wid >> 1, wc = wid & 1;
  const int row0 = blockIdx.x * 128;

  f32x4 acc[4][4];
#pragma unroll
  for (int m = 0; m < 4; ++m)
#pragma unroll
    for (int n = 0; n < 4; ++n) acc[m][n] = (f32x4){0.f, 0.f, 0.f, 0.f};

  const int srow = t >> 1;
  const int shalf = t & 1;

  for (int kc = 0; kc < K; kc += 32) {
    __syncthreads();
    // ---- stage A tile (128 rows x 32 k): load 16 elems, split to bf16 hi/lo ----
    {
      float f[16];
      const ll rg = row0 + srow;
      if (rg < nrows) {
        if (ASRC == 0) {
          const float4* p = (const float4*)(Xf + rg * K + kc + shalf * 16);
#pragma unroll
          for (int i = 0; i < 4; ++i) {
            float4 v = p[i];
            f[i * 4] = v.x; f[i * 4 + 1] = v.y; f[i * 4 + 2] = v.z; f[i * 4 + 3] = v.w;
          }
        } else {
          const short8v* p = (const short8v*)(Xh16 + rg * K + kc + shalf * 16);
          union { short8v v[2]; ushort u[16]; } raw;
          raw.v[0] = p[0]; raw.v[1] = p[1];
#pragma unroll
          for (int i = 0; i < 16; ++i) f[i] = h2f(raw.u[i]);
        }
      } else {
#pragma unroll
        for (int i = 0; i < 16; ++i) f[i] = 0.f;
      }
      union { ushort u[16]; short8v v[2]; } hu, lu;
#pragma unroll
      for (int i = 0; i < 16; ++i) {
        ushort h = f2bf(f[i]);
        hu.u[i] = h;
        lu.u[i] = f2bf(f[i] - bf2f(h));
      }
      *(short8v*)&sAh[srow][shalf * 16] = hu.v[0];
      *(short8v*)&sAh[srow][shalf * 16 + 8] = hu.v[1];
      *(short8v*)&sAl[srow][shalf * 16] = lu.v[0];
      *(short8v*)&sAl[srow][shalf * 16 + 8] = lu.v[1];
    }
    // ---- stage B tile from pre-split transposed weights ----
    {
      const short8v* ph = (const short8v*)(Wth + (ll)srow * K + kc + shalf * 16);
      const short8v* pl = (const short8v*)(Wtl + (ll)srow * K + kc + shalf * 16);
      short8v h0 = ph[0], h1 = ph[1], l0 = pl[0], l1 = pl[1];
      *(short8v*)&sBh[srow][shalf * 16] = h0;
      *(short8v*)&sBh[srow][shalf * 16 + 8] = h1;
      *(short8v*)&sBl[srow][shalf * 16] = l0;
      *(short8v*)&sBl[srow][shalf * 16 + 8] = l1;
    }
    __syncthreads();
    const int kq = (lane >> 4) * 8;
    const int fr = lane & 15;
    short8v ah[4], al[4], bh[4], bl[4];
#pragma unroll
    for (int m = 0; m < 4; ++m) {
      const int r = wr * 64 + m * 16 + fr;
      ah[m] = *(const short8v*)&sAh[r][kq];
      al[m] = *(const short8v*)&sAl[r][kq];
    }
#pragma unroll
    for (int n = 0; n < 4; ++n) {
      const int c = wc * 64 + n * 16 + fr;
      bh[n] = *(const short8v*)&sBh[c][kq];
      bl[n] = *(const short8v*)&sBl[c][kq];
    }
#pragma unroll
    for (int m = 0; m < 4; ++m)
#pragma unroll
      for (int n = 0; n < 4; ++n) {
        acc[m][n] = __builtin_amdgcn_mfma_f32_16x16x32_bf16(ah[m], bh[n], acc[m][n], 0, 0, 0);
        acc[m][n] = __builtin_amdgcn_mfma_f32_16x16x32_bf16(ah[m], bl[n], acc[m][n], 0, 0, 0);
        acc[m][n] = __builtin_amdgcn_mfma_f32_16x16x32_bf16(al[m], bh[n], acc[m][n], 0, 0, 0);
      }
  }

#pragma unroll
  for (int m = 0; m < 4; ++m)
#pragma unroll
    for (int q = 0; q < 4; ++q) {
      const int rl = wr * 64 + m * 16 + (lane >> 4) * 4 + q;
      const ll rg = row0 + rl;
      if (rg >= nrows) continue;
      const float ds = (MODE == 1) ? dis[rg] : 0.f;
#pragma unroll
      for (int n = 0; n < 4; ++n) {
        const int col = wc * 64 + n * 16 + (lane & 15);
        float v = acc[m][n][q];
        if (MODE == 1) {
          Y16[rg * HC + col] = f2h(v * ds);
        } else if (MODE == 2) {
          Yf[rg * HC + col] = fmaxf(v + bias[col], 0.f);
        } else if (MODE == 4) {
          Y16[rg * HC + col] = f2h(fmaxf(v + bias[col], 0.f));
        }
      }
    }
}

// ---------- gather v3: quarter-wave per node (16 lanes x uint4 = 256B row) ----------
__global__ __launch_bounds__(256) void k_gather(const ushort* __restrict__ xw16,
                                                const int* __restrict__ csr,
                                                const int* __restrict__ rp,
                                                const float* __restrict__ dis,
                                                const float* __restrict__ bias,
                                                ushort* __restrict__ h16, int n) {
  const int node = blockIdx.x * 16 + (threadIdx.x >> 4);   // 16 nodes / 256-thr block
  const int lane = threadIdx.x & 63;
  const int sl = lane & 15;                                 // sublane in 16-lane group
  if (node >= n) return;
  const int s = rp[node], e = rp[node + 1];
  const int deg = e - s;

  int myidx = 0;
  if (sl < deg) myidx = csr[s + sl];

  const uint4* xwq = (const uint4*)xw16;                    // 16 uint4 per row
  uint4 sv = xwq[(ll)node * 16 + sl];                       // self term (pre-scaled)
  float a0 = h2f((ushort)(sv.x & 0xffff)), a1 = h2f((ushort)(sv.x >> 16));
  float a2 = h2f((ushort)(sv.y & 0xffff)), a3 = h2f((ushort)(sv.y >> 16));
  float a4 = h2f((ushort)(sv.z & 0xffff)), a5 = h2f((ushort)(sv.z >> 16));
  float a6 = h2f((ushort)(sv.w & 0xffff)), a7 = h2f((ushort)(sv.w >> 16));

  const int gbase = lane & 48;
  const int dfast = (deg < 16) ? deg : 16;
  int j = 0;
  for (; j + 2 <= dfast; j += 2) {
    const int r0 = __shfl(myidx, gbase + j);
    const int r1 = __shfl(myidx, gbase + j + 1);
    const uint4 v0 = xwq[(ll)r0 * 16 + sl];
    const uint4 v1 = xwq[(ll)r1 * 16 + sl];
    a0 += h2f((ushort)(v0.x & 0xffff)) + h2f((ushort)(v1.x & 0xffff));
    a1 += h2f((ushort)(v0.x >> 16))    + h2f((ushort)(v1.x >> 16));
    a2 += h2f((ushort)(v0.y & 0xffff)) + h2f((ushort)(v1.y & 0xffff));
    a3 += h2f((ushort)(v0.y >> 16))    + h2f((ushort)(v1.y >> 16));
    a4 += h2f((ushort)(v0.z & 0xffff)) + h2f((ushort)(v1.z & 0xffff));
    a5 += h2f((ushort)(v0.z >> 16))    + h2f((ushort)(v1.z >> 16));
    a6 += h2f((ushort)(v0.w & 0xffff)) + h2f((ushort)(v1.w & 0xffff));
    a7 += h2f((ushort)(v0.w >> 16))    + h2f((ushort)(v1.w >> 16));
  }
  if (j < dfast) {
    const int r = __shfl(myidx, gbase + j);
    const uint4 v = xwq[(ll)r * 16 + sl];
    a0 += h2f((ushort)(v.x & 0xffff)); a1 += h2f((ushort)(v.x >> 16));
    a2 += h2f((ushort)(v.y & 0xffff)); a3 += h2f((ushort)(v.y >> 16));
    a4 += h2f((ushort)(v.z & 0xffff)); a5 += h2f((ushort)(v.z >> 16));
    a6 += h2f((ushort)(v.w & 0xffff)); a7 += h2f((ushort)(v.w >> 16));
    ++j;
  }
  for (j = 16; j < deg; ++j) {
    const uint4 v = xwq[(ll)csr[s + j] * 16 + sl];
    a0 += h2f((ushort)(v.x & 0xffff)); a1 += h2f((ushort)(v.x >> 16));
    a2 += h2f((ushort)(v.y & 0xffff)); a3 += h2f((ushort)(v.y >> 16));
    a4 += h2f((ushort)(v.z & 0xffff)); a5 += h2f((ushort)(v.z >> 16));
    a6 += h2f((ushort)(v.w & 0xffff)); a7 += h2f((ushort)(v.w >> 16));
  }

  const float dc = dis[node];
  const float4* bias4 = (const float4*)bias;
  const float4 b0 = bias4[sl * 2];
  const float4 b1 = bias4[sl * 2 + 1];
  uint4 o;
  o.x = (uint)f2h(fmaxf(fmaf(dc, a0, b0.x), 0.f)) | ((uint)f2h(fmaxf(fmaf(dc, a1, b0.y), 0.f)) << 16);
  o.y = (uint)f2h(fmaxf(fmaf(dc, a2, b0.z), 0.f)) | ((uint)f2h(fmaxf(fmaf(dc, a3, b0.w), 0.f)) << 16);
  o.z = (uint)f2h(fmaxf(fmaf(dc, a4, b1.x), 0.f)) | ((uint)f2h(fmaxf(fmaf(dc, a5, b1.y), 0.f)) << 16);
  o.w = (uint)f2h(fmaxf(fmaf(dc, a6, b1.z), 0.f)) | ((uint)f2h(fmaxf(fmaf(dc, a7, b1.w), 0.f)) << 16);
  ((uint4*)h16)[(ll)node * 16 + sl] = o;
}

// ---------- MFMA head: logits = z16 @ Wc2 + bc2 ; out = log_softmax ----------
// z16 fp16 [nrows][128]; Wc2t pre-split bf16 [16 cols][128 k] (cols 10..15 zero).
// Same fragment layout as k_gemm; 128 rows/block, wave wid owns rows wid*32..+31.
__global__ __launch_bounds__(256) void k_head_mfma(const ushort* __restrict__ Z16,
                                                   const ushort* __restrict__ Wth,
                                                   const ushort* __restrict__ Wtl,
                                                   const float* __restrict__ bc2,
                                                   float* __restrict__ out, int nrows) {
  __shared__ ushort sZh[128][40];
  __shared__ ushort sZl[128][40];
  __shared__ ushort sWh[16][132];
  __shared__ ushort sWl[16][132];
  __shared__ float ob[128 * OC];
  const int t = threadIdx.x;
  const int lane = t & 63;
  const int wid = t >> 6;
  const int row0 = blockIdx.x * 128;

  // stage Wc2t whole (16 cols x 128 k, hi+lo): thread t -> col t>>4, k (t&15)*8
  {
    const int col = t >> 4;
    const int k0 = (t & 15) * 8;
    *(short8v*)&sWh[col][k0] = *(const short8v*)(Wth + col * 128 + k0);
    *(short8v*)&sWl[col][k0] = *(const short8v*)(Wtl + col * 128 + k0);
  }

  f32x4 acc[2];
  acc[0] = (f32x4){0.f, 0.f, 0.f, 0.f};
  acc[1] = (f32x4){0.f, 0.f, 0.f, 0.f};

  const int srow = t >> 1;
  const int shalf = t & 1;

  for (int kc = 0; kc < HC; kc += 32) {
    __syncthreads();
    // stage A chunk: fp16 -> split bf16 hi/lo (exact)
    {
      float f[16];
      const ll rg = row0 + srow;
      if (rg < nrows) {
        const short8v* p = (const short8v*)(Z16 + rg * HC + kc + shalf * 16);
        union { short8v v[2]; ushort u[16]; } raw;
        raw.v[0] = p[0]; raw.v[1] = p[1];
#pragma unroll
        for (int i = 0; i < 16; ++i) f[i] = h2f(raw.u[i]);
      } else {
#pragma unroll
        for (int i = 0; i < 16; ++i) f[i] = 0.f;
      }
      union { ushort u[16]; short8v v[2]; } hu, lu;
#pragma unroll
      for (int i = 0; i < 16; ++i) {
        ushort h = f2bf(f[i]);
        hu.u[i] = h;
        lu.u[i] = f2bf(f[i] - bf2f(h));
      }
      *(short8v*)&sZh[srow][shalf * 16] = hu.v[0];
      *(short8v*)&sZh[srow][shalf * 16 + 8] = hu.v[1];
      *(short8v*)&sZl[srow][shalf * 16] = lu.v[0];
      *(short8v*)&sZl[srow][shalf * 16 + 8] = lu.v[1];
    }
    __syncthreads();
    const int kq = (lane >> 4) * 8;
    const int fr = lane & 15;
    const short8v bh = *(const short8v*)&sWh[fr][kc + kq];
    const short8v bl = *(const short8v*)&sWl[fr][kc + kq];
#pragma unroll
    for (int mt = 0; mt < 2; ++mt) {
      const int r = wid * 32 + mt * 16 + fr;
      const short8v ah = *(const short8v*)&sZh[r][kq];
      const short8v al = *(const short8v*)&sZl[r][kq];
      acc[mt] = __builtin_amdgcn_mfma_f32_16x16x32_bf16(ah, bh, acc[mt], 0, 0, 0);
      acc[mt] = __builtin_amdgcn_mfma_f32_16x16x32_bf16(ah, bl, acc[mt], 0, 0, 0);
      acc[mt] = __builtin_amdgcn_mfma_f32_16x16x32_bf16(al, bh, acc[mt], 0, 0, 0);
    }
  }

  // softmax over cols within each 16-lane group (cols 10..15 masked via bc2=-1e30)
  const int fr = lane & 15;
  const float bcv = (fr < OC) ? bc2[fr] : -1e30f;
#pragma unroll
  for (int mt = 0; mt < 2; ++mt)
#pragma unroll
    for (int q = 0; q < 4; ++q) {
      float a = acc[mt][q] + bcv;
      float mx = a;
#pragma unroll
      for (int m = 8; m; m >>= 1) mx = fmaxf(mx, __shfl_xor(mx, m, 64));
      float ex = expf(a - mx);
#pragma unroll
      for (int m = 8; m; m >>= 1) ex += __shfl_xor(ex, m, 64);
      const float res = a - mx - logf(ex);
      const int rl = wid * 32 + mt * 16 + (lane >> 4) * 4 + q;
      if (fr < OC) ob[rl * OC + fr] = res;
    }
  __syncthreads();
  const int rem = nrows - row0;
  const int cnt = ((rem < 128) ? rem : 128) * OC;
  for (int i = t; i < cnt; i += 256) out[(ll)row0 * OC + i] = ob[i];
}

extern "C" void kernel_launch(void* const* d_in, const int* in_sizes, int n_in,
                              void* d_out, int out_size, void* d_ws, size_t ws_size,
                              hipStream_t stream) {
  const float* x   = (const float*)d_in[0];
  const int*   ei  = (const int*)d_in[1];   // [2][E] int32
  const float* W1  = (const float*)d_in[2];
  const float* b1  = (const float*)d_in[3];
  const float* W2  = (const float*)d_in[4];
  const float* b2  = (const float*)d_in[5];
  const float* Wc1 = (const float*)d_in[6];
  const float* bc1 = (const float*)d_in[7];
  const float* Wc2 = (const float*)d_in[8];
  const float* bc2 = (const float*)d_in[9];
  float* out = (float*)d_out;

  char* ws = (char*)d_ws;
  ushort* xw16 = (ushort*)(ws);                       // xw' fp16 [N][128] 38.4MB ; later z16 [BSZ][128]
  ushort* h16  = (ushort*)(ws + 38400000LL);          // h   fp16 [N][128] 38.4MB
  const ll CSRB = 76800000LL;
  float* dis  = (float*)(ws + CSRB);                  // N floats
  int*   rp   = (int*)  (ws + CSRB + 600064LL);       // N+1
  int*   csr  = (int*)  (ws + CSRB + 1200128LL);      // E
  int*   cnt  = (int*)  (ws + CSRB + 3600128LL);      // 150016
  int*   fill = (int*)  (ws + CSRB + 4200192LL);      // 150016
  int*   bsum = (int*)  (ws + CSRB + 4800256LL);      // 256
  ushort* Wt1h = (ushort*)(ws + CSRB + 4801280LL);    // 128*64
  ushort* Wt1l = (ushort*)(ws + CSRB + 4817664LL);
  ushort* Wt2h = (ushort*)(ws + CSRB + 4834048LL);    // 128*128
  ushort* Wt2l = (ushort*)(ws + CSRB + 4866816LL);
  ushort* Wtc1h = (ushort*)(ws + CSRB + 4899584LL);   // 128*384
  ushort* Wtc1l = (ushort*)(ws + CSRB + 4997888LL);
  ushort* Wtc2h = (ushort*)(ws + CSRB + 5096192LL);   // 16*128
  ushort* Wtc2l = (ushort*)(ws + CSRB + 5100288LL);   // end ~82MB

  const int nb = (NN + 1023) / 1024;

  // CSR build
  k_zero_i<<<(2 * 150016 + 255) / 256, 256, 0, stream>>>(cnt, 2 * 150016);
  k_count<<<(EE + 255) / 256, 256, 0, stream>>>(ei + EE, cnt, EE);
  k_scan1<<<nb, 256, 0, stream>>>(cnt, rp, bsum, dis, NN);
  k_scan2<<<1, 256, 0, stream>>>(bsum, nb);
  k_scan3<<<nb, 256, 0, stream>>>(rp, bsum, NN, EE);
  k_fill_csr<<<(EE + 255) / 256, 256, 0, stream>>>(ei, rp, fill, csr, EE);

  // weight split+transpose (W1, W2, Wc1, Wc2)
  k_wprep_all<<<((64 + 128 + 384 + 16) * 128 + 255) / 256, 256, 0, stream>>>(
      W1, W2, Wc1, Wc2, Wt1h, Wt1l, Wt2h, Wt2l, Wtc1h, Wtc1l, Wtc2h, Wtc2l);

  // layer 1: xw' = fp16(dis.row * (x @ W1))
  k_gemm<INC, 0, 1><<<(NN + 127) / 128, 256, 0, stream>>>(x, nullptr, Wt1h, Wt1l, nullptr, dis, nullptr, xw16, NN);
  k_gather<<<(NN + 15) / 16, 256, 0, stream>>>(xw16, csr, rp, dis, b1, h16, NN);

  // layer 2: xw' = fp16(dis.row * (h @ W2))
  k_gemm<HC, 2, 1><<<(NN + 127) / 128, 256, 0, stream>>>(nullptr, h16, Wt2h, Wt2l, nullptr, dis, nullptr, xw16, NN);
  k_gather<<<(NN + 15) / 16, 256, 0, stream>>>(xw16, csr, rp, dis, b2, h16, NN);

  // classifier: z16 = fp16(relu(flat @ Wc1 + bc1)), flat = h16 viewed [BSZ][384]; z16 reuses xw16
  k_gemm<3 * HC, 2, 4><<<(BSZ + 127) / 128, 256, 0, stream>>>(nullptr, h16, Wtc1h, Wtc1l, bc1, nullptr, nullptr, xw16, BSZ);

  // head: out = log_softmax(z16 @ Wc2 + bc2)
  k_head_mfma<<<(BSZ + 127) / 128, 256, 0, stream>>>(xw16, Wtc2h, Wtc2l, bc2, out, BSZ);
}

// Round 9
// 204.553 us; speedup vs baseline: 15.1523x; 1.1421x over previous
//
#include <hip/hip_runtime.h>

#define NN 150000
#define EE 600000
#define INC 64
#define HC 128
#define OC 10
#define BSZ 50000

typedef long long ll;
typedef _Float16 f16;
typedef __attribute__((ext_vector_type(8))) short short8v;
typedef __attribute__((ext_vector_type(4))) float f32x4;

__device__ __forceinline__ ushort f2bf(float f) {
  uint u = __float_as_uint(f);
  uint r = (u + 0x7fffu + ((u >> 16) & 1u)) >> 16;
  return (ushort)r;
}
__device__ __forceinline__ float bf2f(ushort h) {
  return __uint_as_float(((uint)h) << 16);
}
__device__ __forceinline__ float h2f(ushort u) {
  f16 h;
  __builtin_memcpy(&h, &u, 2);
  return (float)h;
}
__device__ __forceinline__ ushort f2h(float f) {
  f16 h = (f16)f;
  ushort u;
  __builtin_memcpy(&u, &h, 2);
  return u;
}

// ---------- CSR build ----------

__global__ __launch_bounds__(256) void k_zero_i(int* d, int n) {
  int i = blockIdx.x * 256 + threadIdx.x;
  if (i < n) d[i] = 0;
}

// count + per-edge slot in one pass (slot write coalesced)
__global__ __launch_bounds__(256) void k_count(const int* __restrict__ col, int* cnt,
                                               int* __restrict__ slot, int e) {
  int i = blockIdx.x * 256 + threadIdx.x;
  if (i < e) slot[i] = atomicAdd(&cnt[col[i]], 1);
}

__global__ __launch_bounds__(256) void k_scan1(const int* __restrict__ cnt, int* ex, int* bsum,
                                               float* __restrict__ dis, int n) {
  __shared__ int s[256];
  const int t = threadIdx.x;
  const int base = blockIdx.x * 1024 + t * 4;
  int v[4], tot = 0;
#pragma unroll
  for (int i = 0; i < 4; ++i) {
    v[i] = (base + i < n) ? cnt[base + i] : 0;
    tot += v[i];
    if (base + i < n) dis[base + i] = rsqrtf((float)(1 + v[i]));
  }
  s[t] = tot;
  __syncthreads();
#pragma unroll
  for (int off = 1; off < 256; off <<= 1) {
    int x = (t >= off) ? s[t - off] : 0;
    __syncthreads();
    s[t] += x;
    __syncthreads();
  }
  int run = s[t] - tot;
#pragma unroll
  for (int i = 0; i < 4; ++i) {
    if (base + i < n) ex[base + i] = run;
    run += v[i];
  }
  if (t == 255) bsum[blockIdx.x] = s[255];
}

__global__ __launch_bounds__(256) void k_scan2(int* bsum, int nb) {
  __shared__ int s[256];
  const int t = threadIdx.x;
  int v = (t < nb) ? bsum[t] : 0;
  s[t] = v;
  __syncthreads();
#pragma unroll
  for (int off = 1; off < 256; off <<= 1) {
    int x = (t >= off) ? s[t - off] : 0;
    __syncthreads();
    s[t] += x;
    __syncthreads();
  }
  if (t < nb) bsum[t] = s[t] - v;
}

__global__ __launch_bounds__(256) void k_scan3(int* rp, const int* __restrict__ bsum, int n, int e) {
  const int base = blockIdx.x * 1024 + threadIdx.x * 4;
  const int off = bsum[blockIdx.x];
#pragma unroll
  for (int i = 0; i < 4; ++i)
    if (base + i < n) rp[base + i] += off;
  if (blockIdx.x == 0 && threadIdx.x == 0) rp[n] = e;
}

// csr[rp[c] + slot[i]] = row  (no atomic: slot precomputed)
__global__ __launch_bounds__(256) void k_fill_csr(const int* __restrict__ ei,
                                                  const int* __restrict__ rp,
                                                  const int* __restrict__ slot,
                                                  int* csr, int e) {
  int i = blockIdx.x * 256 + threadIdx.x;
  if (i >= e) return;
  int r = ei[i];
  int c = ei[EE + i];
  csr[rp[c] + slot[i]] = r;
}

// ---------- weight prep: transpose + bf16 (hi only); Wc2 padded to 16 cols ----------
__global__ __launch_bounds__(256) void k_wprep_all(const float* __restrict__ W1,
                                                   const float* __restrict__ W2,
                                                   const float* __restrict__ Wc1,
                                                   const float* __restrict__ Wc2,
                                                   ushort* t1h, ushort* t2h, ushort* tch,
                                                   ushort* t2ch) {
  int t = blockIdx.x * 256 + threadIdx.x;
  if (t < (64 + 128 + 384) * 128) {
    const float* W; ushort* th; int K, idx;
    if (t < 64 * 128)              { W = W1;  th = t1h; K = 64;  idx = t; }
    else if (t < (64 + 128) * 128) { W = W2;  th = t2h; K = 128; idx = t - 64 * 128; }
    else                           { W = Wc1; th = tch; K = 384; idx = t - (64 + 128) * 128; }
    int col = idx & 127;
    int k = idx >> 7;
    th[(ll)col * K + k] = f2bf(W[(ll)k * 128 + col]);
  } else if (t < (64 + 128 + 384) * 128 + 16 * 128) {
    int idx = t - (64 + 128 + 384) * 128;   // 0..2047
    int col = idx >> 7;                     // 0..15
    int k = idx & 127;
    float v = (col < OC) ? Wc2[(ll)k * OC + col] : 0.f;
    t2ch[col * 128 + k] = f2bf(v);
  }
}

// ---------- MFMA GEMM: Y[nrows][128] = X[nrows][K] @ W[K][128] ----------
// 2-term split: C = Ah*Bh + Al*Bh  (A exact fp16 split; B bf16). fp32 accumulate.
// ASRC 0: X fp32 (split in-register). ASRC 2: X fp16 (exact split).
// MODE 1: Y16 = fp16( dis[row] * Y ).  MODE 4: Y16 = fp16(relu(Y+bias)).
template<int K, int ASRC, int MODE>
__global__ __launch_bounds__(256) void k_gemm(const float* __restrict__ Xf,
                                              const ushort* __restrict__ Xh16,
                                              const ushort* __restrict__ Wth,
                                              const float* __restrict__ bias,
                                              const float* __restrict__ dis,
                                              ushort* __restrict__ Y16, int nrows) {
  __shared__ ushort sAh[128][40];
  __shared__ ushort sAl[128][40];
  __shared__ ushort sBh[128][40];
  const int t = threadIdx.x;
  const int lane = t & 63;
  const int wid = t >> 6;
  const int wr = wid >> 1, wc = wid & 1;
  const int row0 = blockIdx.x * 128;

  f32x4 acc[4][4];
#pragma unroll
  for (int m = 0; m < 4; ++m)
#pragma unroll
    for (int n = 0; n < 4; ++n) acc[m][n] = (f32x4){0.f, 0.f, 0.f, 0.f};

  const int srow = t >> 1;
  const int shalf = t & 1;

  for (int kc = 0; kc < K; kc += 32) {
    __syncthreads();
    // ---- stage A tile (128 rows x 32 k): split to bf16 hi/lo ----
    {
      float f[16];
      const ll rg = row0 + srow;
      if (rg < nrows) {
        if (ASRC == 0) {
          const float4* p = (const float4*)(Xf + rg * K + kc + shalf * 16);
#pragma unroll
          for (int i = 0; i < 4; ++i) {
            float4 v = p[i];
            f[i * 4] = v.x; f[i * 4 + 1] = v.y; f[i * 4 + 2] = v.z; f[i * 4 + 3] = v.w;
          }
        } else {
          const short8v* p = (const short8v*)(Xh16 + rg * K + kc + shalf * 16);
          union { short8v v[2]; ushort u[16]; } raw;
          raw.v[0] = p[0]; raw.v[1] = p[1];
#pragma unroll
          for (int i = 0; i < 16; ++i) f[i] = h2f(raw.u[i]);
        }
      } else {
#pragma unroll
        for (int i = 0; i < 16; ++i) f[i] = 0.f;
      }
      union { ushort u[16]; short8v v[2]; } hu, lu;
#pragma unroll
      for (int i = 0; i < 16; ++i) {
        ushort h = f2bf(f[i]);
        hu.u[i] = h;
        lu.u[i] = f2bf(f[i] - bf2f(h));
      }
      *(short8v*)&sAh[srow][shalf * 16] = hu.v[0];
      *(short8v*)&sAh[srow][shalf * 16 + 8] = hu.v[1];
      *(short8v*)&sAl[srow][shalf * 16] = lu.v[0];
      *(short8v*)&sAl[srow][shalf * 16 + 8] = lu.v[1];
    }
    // ---- stage B tile (bf16 hi only) ----
    {
      const short8v* ph = (const short8v*)(Wth + (ll)srow * K + kc + shalf * 16);
      short8v h0 = ph[0], h1 = ph[1];
      *(short8v*)&sBh[srow][shalf * 16] = h0;
      *(short8v*)&sBh[srow][shalf * 16 + 8] = h1;
    }
    __syncthreads();
    const int kq = (lane >> 4) * 8;
    const int fr = lane & 15;
    short8v ah[4], al[4], bh[4];
#pragma unroll
    for (int m = 0; m < 4; ++m) {
      const int r = wr * 64 + m * 16 + fr;
      ah[m] = *(const short8v*)&sAh[r][kq];
      al[m] = *(const short8v*)&sAl[r][kq];
    }
#pragma unroll
    for (int n = 0; n < 4; ++n) {
      const int c = wc * 64 + n * 16 + fr;
      bh[n] = *(const short8v*)&sBh[c][kq];
    }
#pragma unroll
    for (int m = 0; m < 4; ++m)
#pragma unroll
      for (int n = 0; n < 4; ++n) {
        acc[m][n] = __builtin_amdgcn_mfma_f32_16x16x32_bf16(ah[m], bh[n], acc[m][n], 0, 0, 0);
        acc[m][n] = __builtin_amdgcn_mfma_f32_16x16x32_bf16(al[m], bh[n], acc[m][n], 0, 0, 0);
      }
  }

#pragma unroll
  for (int m = 0; m < 4; ++m)
#pragma unroll
    for (int q = 0; q < 4; ++q) {
      const int rl = wr * 64 + m * 16 + (lane >> 4) * 4 + q;
      const ll rg = row0 + rl;
      if (rg >= nrows) continue;
      const float ds = (MODE == 1) ? dis[rg] : 0.f;
#pragma unroll
      for (int n = 0; n < 4; ++n) {
        const int col = wc * 64 + n * 16 + (lane & 15);
        float v = acc[m][n][q];
        if (MODE == 1) {
          Y16[rg * HC + col] = f2h(v * ds);
        } else {
          Y16[rg * HC + col] = f2h(fmaxf(v + bias[col], 0.f));
        }
      }
    }
}

// ---------- gather: quarter-wave per node, 4-deep row loads ----------
__global__ __launch_bounds__(256) void k_gather(const ushort* __restrict__ xw16,
                                                const int* __restrict__ csr,
                                                const int* __restrict__ rp,
                                                const float* __restrict__ dis,
                                                const float* __restrict__ bias,
                                                ushort* __restrict__ h16, int n) {
  const int node = blockIdx.x * 16 + (threadIdx.x >> 4);   // 16 nodes / 256-thr block
  const int lane = threadIdx.x & 63;
  const int sl = lane & 15;                                 // sublane in 16-lane group
  if (node >= n) return;
  const int s = rp[node], e = rp[node + 1];
  const int deg = e - s;

  int myidx = 0;
  if (sl < deg) myidx = csr[s + sl];

  const uint4* xwq = (const uint4*)xw16;                    // 16 uint4 per row
  uint4 sv = xwq[(ll)node * 16 + sl];                       // self term (pre-scaled)
  float a0 = h2f((ushort)(sv.x & 0xffff)), a1 = h2f((ushort)(sv.x >> 16));
  float a2 = h2f((ushort)(sv.y & 0xffff)), a3 = h2f((ushort)(sv.y >> 16));
  float a4 = h2f((ushort)(sv.z & 0xffff)), a5 = h2f((ushort)(sv.z >> 16));
  float a6 = h2f((ushort)(sv.w & 0xffff)), a7 = h2f((ushort)(sv.w >> 16));

  const int gbase = lane & 48;
  const int dfast = (deg < 16) ? deg : 16;
  int j = 0;
  for (; j + 4 <= dfast; j += 4) {                          // 4 rows in flight per group
    const int r0 = __shfl(myidx, gbase + j);
    const int r1 = __shfl(myidx, gbase + j + 1);
    const int r2 = __shfl(myidx, gbase + j + 2);
    const int r3 = __shfl(myidx, gbase + j + 3);
    const uint4 v0 = xwq[(ll)r0 * 16 + sl];
    const uint4 v1 = xwq[(ll)r1 * 16 + sl];
    const uint4 v2 = xwq[(ll)r2 * 16 + sl];
    const uint4 v3 = xwq[(ll)r3 * 16 + sl];
    a0 += (h2f((ushort)(v0.x & 0xffff)) + h2f((ushort)(v1.x & 0xffff)))
        + (h2f((ushort)(v2.x & 0xffff)) + h2f((ushort)(v3.x & 0xffff)));
    a1 += (h2f((ushort)(v0.x >> 16)) + h2f((ushort)(v1.x >> 16)))
        + (h2f((ushort)(v2.x >> 16)) + h2f((ushort)(v3.x >> 16)));
    a2 += (h2f((ushort)(v0.y & 0xffff)) + h2f((ushort)(v1.y & 0xffff)))
        + (h2f((ushort)(v2.y & 0xffff)) + h2f((ushort)(v3.y & 0xffff)));
    a3 += (h2f((ushort)(v0.y >> 16)) + h2f((ushort)(v1.y >> 16)))
        + (h2f((ushort)(v2.y >> 16)) + h2f((ushort)(v3.y >> 16)));
    a4 += (h2f((ushort)(v0.z & 0xffff)) + h2f((ushort)(v1.z & 0xffff)))
        + (h2f((ushort)(v2.z & 0xffff)) + h2f((ushort)(v3.z & 0xffff)));
    a5 += (h2f((ushort)(v0.z >> 16)) + h2f((ushort)(v1.z >> 16)))
        + (h2f((ushort)(v2.z >> 16)) + h2f((ushort)(v3.z >> 16)));
    a6 += (h2f((ushort)(v0.w & 0xffff)) + h2f((ushort)(v1.w & 0xffff)))
        + (h2f((ushort)(v2.w & 0xffff)) + h2f((ushort)(v3.w & 0xffff)));
    a7 += (h2f((ushort)(v0.w >> 16)) + h2f((ushort)(v1.w >> 16)))
        + (h2f((ushort)(v2.w >> 16)) + h2f((ushort)(v3.w >> 16)));
  }
  for (; j < dfast; ++j) {
    const int r = __shfl(myidx, gbase + j);
    const uint4 v = xwq[(ll)r * 16 + sl];
    a0 += h2f((ushort)(v.x & 0xffff)); a1 += h2f((ushort)(v.x >> 16));
    a2 += h2f((ushort)(v.y & 0xffff)); a3 += h2f((ushort)(v.y >> 16));
    a4 += h2f((ushort)(v.z & 0xffff)); a5 += h2f((ushort)(v.z >> 16));
    a6 += h2f((ushort)(v.w & 0xffff)); a7 += h2f((ushort)(v.w >> 16));
  }
  for (j = 16; j < deg; ++j) {                              // rare spill (deg > 16)
    const uint4 v = xwq[(ll)csr[s + j] * 16 + sl];
    a0 += h2f((ushort)(v.x & 0xffff)); a1 += h2f((ushort)(v.x >> 16));
    a2 += h2f((ushort)(v.y & 0xffff)); a3 += h2f((ushort)(v.y >> 16));
    a4 += h2f((ushort)(v.z & 0xffff)); a5 += h2f((ushort)(v.z >> 16));
    a6 += h2f((ushort)(v.w & 0xffff)); a7 += h2f((ushort)(v.w >> 16));
  }

  const float dc = dis[node];
  const float4* bias4 = (const float4*)bias;
  const float4 b0 = bias4[sl * 2];
  const float4 b1 = bias4[sl * 2 + 1];
  uint4 o;
  o.x = (uint)f2h(fmaxf(fmaf(dc, a0, b0.x), 0.f)) | ((uint)f2h(fmaxf(fmaf(dc, a1, b0.y), 0.f)) << 16);
  o.y = (uint)f2h(fmaxf(fmaf(dc, a2, b0.z), 0.f)) | ((uint)f2h(fmaxf(fmaf(dc, a3, b0.w), 0.f)) << 16);
  o.z = (uint)f2h(fmaxf(fmaf(dc, a4, b1.x), 0.f)) | ((uint)f2h(fmaxf(fmaf(dc, a5, b1.y), 0.f)) << 16);
  o.w = (uint)f2h(fmaxf(fmaf(dc, a6, b1.z), 0.f)) | ((uint)f2h(fmaxf(fmaf(dc, a7, b1.w), 0.f)) << 16);
  ((uint4*)h16)[(ll)node * 16 + sl] = o;
}

// ---------- MFMA head: logits = z16 @ Wc2 + bc2 ; out = log_softmax ----------
__global__ __launch_bounds__(256) void k_head_mfma(const ushort* __restrict__ Z16,
                                                   const ushort* __restrict__ Wth,
                                                   const float* __restrict__ bc2,
                                                   float* __restrict__ out, int nrows) {
  __shared__ ushort sZh[128][40];
  __shared__ ushort sZl[128][40];
  __shared__ ushort sWh[16][132];
  __shared__ float ob[128 * OC];
  const int t = threadIdx.x;
  const int lane = t & 63;
  const int wid = t >> 6;
  const int row0 = blockIdx.x * 128;

  {
    const int col = t >> 4;
    const int k0 = (t & 15) * 8;
    *(short8v*)&sWh[col][k0] = *(const short8v*)(Wth + col * 128 + k0);
  }

  f32x4 acc[2];
  acc[0] = (f32x4){0.f, 0.f, 0.f, 0.f};
  acc[1] = (f32x4){0.f, 0.f, 0.f, 0.f};

  const int srow = t >> 1;
  const int shalf = t & 1;

  for (int kc = 0; kc < HC; kc += 32) {
    __syncthreads();
    {
      float f[16];
      const ll rg = row0 + srow;
      if (rg < nrows) {
        const short8v* p = (const short8v*)(Z16 + rg * HC + kc + shalf * 16);
        union { short8v v[2]; ushort u[16]; } raw;
        raw.v[0] = p[0]; raw.v[1] = p[1];
#pragma unroll
        for (int i = 0; i < 16; ++i) f[i] = h2f(raw.u[i]);
      } else {
#pragma unroll
        for (int i = 0; i < 16; ++i) f[i] = 0.f;
      }
      union { ushort u[16]; short8v v[2]; } hu, lu;
#pragma unroll
      for (int i = 0; i < 16; ++i) {
        ushort h = f2bf(f[i]);
        hu.u[i] = h;
        lu.u[i] = f2bf(f[i] - bf2f(h));
      }
      *(short8v*)&sZh[srow][shalf * 16] = hu.v[0];
      *(short8v*)&sZh[srow][shalf * 16 + 8] = hu.v[1];
      *(short8v*)&sZl[srow][shalf * 16] = lu.v[0];
      *(short8v*)&sZl[srow][shalf * 16 + 8] = lu.v[1];
    }
    __syncthreads();
    const int kq = (lane >> 4) * 8;
    const int fr = lane & 15;
    const short8v bh = *(const short8v*)&sWh[fr][kc + kq];
#pragma unroll
    for (int mt = 0; mt < 2; ++mt) {
      const int r = wid * 32 + mt * 16 + fr;
      const short8v ah = *(const short8v*)&sZh[r][kq];
      const short8v al = *(const short8v*)&sZl[r][kq];
      acc[mt] = __builtin_amdgcn_mfma_f32_16x16x32_bf16(ah, bh, acc[mt], 0, 0, 0);
      acc[mt] = __builtin_amdgcn_mfma_f32_16x16x32_bf16(al, bh, acc[mt], 0, 0, 0);
    }
  }

  const int fr = lane & 15;
  const float bcv = (fr < OC) ? bc2[fr] : -1e30f;
#pragma unroll
  for (int mt = 0; mt < 2; ++mt)
#pragma unroll
    for (int q = 0; q < 4; ++q) {
      float a = acc[mt][q] + bcv;
      float mx = a;
#pragma unroll
      for (int m = 8; m; m >>= 1) mx = fmaxf(mx, __shfl_xor(mx, m, 64));
      float ex = expf(a - mx);
#pragma unroll
      for (int m = 8; m; m >>= 1) ex += __shfl_xor(ex, m, 64);
      const float res = a - mx - logf(ex);
      const int rl = wid * 32 + mt * 16 + (lane >> 4) * 4 + q;
      if (fr < OC) ob[rl * OC + fr] = res;
    }
  __syncthreads();
  const int rem = nrows - row0;
  const int cnt = ((rem < 128) ? rem : 128) * OC;
  for (int i = t; i < cnt; i += 256) out[(ll)row0 * OC + i] = ob[i];
}

extern "C" void kernel_launch(void* const* d_in, const int* in_sizes, int n_in,
                              void* d_out, int out_size, void* d_ws, size_t ws_size,
                              hipStream_t stream) {
  const float* x   = (const float*)d_in[0];
  const int*   ei  = (const int*)d_in[1];   // [2][E] int32
  const float* W1  = (const float*)d_in[2];
  const float* b1  = (const float*)d_in[3];
  const float* W2  = (const float*)d_in[4];
  const float* b2  = (const float*)d_in[5];
  const float* Wc1 = (const float*)d_in[6];
  const float* bc1 = (const float*)d_in[7];
  const float* Wc2 = (const float*)d_in[8];
  const float* bc2 = (const float*)d_in[9];
  float* out = (float*)d_out;

  char* ws = (char*)d_ws;
  ushort* xw16 = (ushort*)(ws);                       // xw' fp16 [N][128] 38.4MB ; later z16 [BSZ][128]
  ushort* h16  = (ushort*)(ws + 38400000LL);          // h   fp16 [N][128] 38.4MB
  const ll CSRB = 76800000LL;
  float* dis  = (float*)(ws + CSRB);                  // N floats
  int*   rp   = (int*)  (ws + CSRB + 600064LL);       // N+1
  int*   csr  = (int*)  (ws + CSRB + 1200128LL);      // E
  int*   cnt  = (int*)  (ws + CSRB + 3600128LL);      // 150016
  int*   slot = (int*)  (ws + CSRB + 4200192LL);      // E
  int*   bsum = (int*)  (ws + CSRB + 6600192LL);      // 256
  ushort* Wt1h  = (ushort*)(ws + CSRB + 6601216LL);   // 64*128
  ushort* Wt2h  = (ushort*)(ws + CSRB + 6617600LL);   // 128*128
  ushort* Wtc1h = (ushort*)(ws + CSRB + 6650368LL);   // 384*128
  ushort* Wtc2h = (ushort*)(ws + CSRB + 6748672LL);   // 16*128 ; end ~83.5MB

  const int nb = (NN + 1023) / 1024;

  // CSR build
  k_zero_i<<<(150016 + 255) / 256, 256, 0, stream>>>(cnt, 150016);
  k_count<<<(EE + 255) / 256, 256, 0, stream>>>(ei + EE, cnt, slot, EE);
  k_scan1<<<nb, 256, 0, stream>>>(cnt, rp, bsum, dis, NN);
  k_scan2<<<1, 256, 0, stream>>>(bsum, nb);
  k_scan3<<<nb, 256, 0, stream>>>(rp, bsum, NN, EE);
  k_fill_csr<<<(EE + 255) / 256, 256, 0, stream>>>(ei, rp, slot, csr, EE);

  // weight transpose + bf16 (hi only)
  k_wprep_all<<<((64 + 128 + 384 + 16) * 128 + 255) / 256, 256, 0, stream>>>(
      W1, W2, Wc1, Wc2, Wt1h, Wt2h, Wtc1h, Wtc2h);

  // layer 1: xw' = fp16(dis.row * (x @ W1))
  k_gemm<INC, 0, 1><<<(NN + 127) / 128, 256, 0, stream>>>(x, nullptr, Wt1h, nullptr, dis, xw16, NN);
  k_gather<<<(NN + 15) / 16, 256, 0, stream>>>(xw16, csr, rp, dis, b1, h16, NN);

  // layer 2: xw' = fp16(dis.row * (h @ W2))
  k_gemm<HC, 2, 1><<<(NN + 127) / 128, 256, 0, stream>>>(nullptr, h16, Wt2h, nullptr, dis, xw16, NN);
  k_gather<<<(NN + 15) / 16, 256, 0, stream>>>(xw16, csr, rp, dis, b2, h16, NN);

  // classifier: z16 = fp16(relu(flat @ Wc1 + bc1)), flat = h16 viewed [BSZ][384]; z16 reuses xw16
  k_gemm<3 * HC, 2, 4><<<(BSZ + 127) / 128, 256, 0, stream>>>(nullptr, h16, Wtc1h, bc1, nullptr, xw16, BSZ);

  // head: out = log_softmax(z16 @ Wc2 + bc2)
  k_head_mfma<<<(BSZ + 127) / 128, 256, 0, stream>>>(xw16, Wtc2h, bc2, out, BSZ);
}

// Round 10
// 189.810 us; speedup vs baseline: 16.3292x; 1.0777x over previous
//
#include <hip/hip_runtime.h>

#define NN 150000
#define EE 600000
#define INC 64
#define HC 128
#define OC 10
#define BSZ 50000

typedef long long ll;
typedef _Float16 f16;
typedef __attribute__((ext_vector_type(8))) short short8v;
typedef __attribute__((ext_vector_type(8))) _Float16 f16x8;
typedef __attribute__((ext_vector_type(4))) float f32x4;

__device__ __forceinline__ float h2f(ushort u) {
  f16 h;
  __builtin_memcpy(&h, &u, 2);
  return (float)h;
}
__device__ __forceinline__ ushort f2h(float f) {
  f16 h = (f16)f;
  ushort u;
  __builtin_memcpy(&u, &h, 2);
  return u;
}

// ---------- CSR build ----------

__global__ __launch_bounds__(256) void k_zero_i(int* d, int n) {
  int i = blockIdx.x * 256 + threadIdx.x;
  if (i < n) d[i] = 0;
}

// count + per-edge slot in one pass (slot write coalesced)
__global__ __launch_bounds__(256) void k_count(const int* __restrict__ col, int* cnt,
                                               int* __restrict__ slot, int e) {
  int i = blockIdx.x * 256 + threadIdx.x;
  if (i < e) slot[i] = atomicAdd(&cnt[col[i]], 1);
}

__global__ __launch_bounds__(256) void k_scan1(const int* __restrict__ cnt, int* ex, int* bsum,
                                               float* __restrict__ dis, int n) {
  __shared__ int s[256];
  const int t = threadIdx.x;
  const int base = blockIdx.x * 1024 + t * 4;
  int v[4], tot = 0;
#pragma unroll
  for (int i = 0; i < 4; ++i) {
    v[i] = (base + i < n) ? cnt[base + i] : 0;
    tot += v[i];
    if (base + i < n) dis[base + i] = rsqrtf((float)(1 + v[i]));
  }
  s[t] = tot;
  __syncthreads();
#pragma unroll
  for (int off = 1; off < 256; off <<= 1) {
    int x = (t >= off) ? s[t - off] : 0;
    __syncthreads();
    s[t] += x;
    __syncthreads();
  }
  int run = s[t] - tot;
#pragma unroll
  for (int i = 0; i < 4; ++i) {
    if (base + i < n) ex[base + i] = run;
    run += v[i];
  }
  if (t == 255) bsum[blockIdx.x] = s[255];
}

__global__ __launch_bounds__(256) void k_scan2(int* bsum, int nb) {
  __shared__ int s[256];
  const int t = threadIdx.x;
  int v = (t < nb) ? bsum[t] : 0;
  s[t] = v;
  __syncthreads();
#pragma unroll
  for (int off = 1; off < 256; off <<= 1) {
    int x = (t >= off) ? s[t - off] : 0;
    __syncthreads();
    s[t] += x;
    __syncthreads();
  }
  if (t < nb) bsum[t] = s[t] - v;
}

__global__ __launch_bounds__(256) void k_scan3(int* rp, const int* __restrict__ bsum, int n, int e) {
  const int base = blockIdx.x * 1024 + threadIdx.x * 4;
  const int off = bsum[blockIdx.x];
#pragma unroll
  for (int i = 0; i < 4; ++i)
    if (base + i < n) rp[base + i] += off;
  if (blockIdx.x == 0 && threadIdx.x == 0) rp[n] = e;
}

// csr[rp[c] + slot[i]] = row  (no atomic: slot precomputed)
__global__ __launch_bounds__(256) void k_fill_csr(const int* __restrict__ ei,
                                                  const int* __restrict__ rp,
                                                  const int* __restrict__ slot,
                                                  int* csr, int e) {
  int i = blockIdx.x * 256 + threadIdx.x;
  if (i >= e) return;
  int r = ei[i];
  int c = ei[EE + i];
  csr[rp[c] + slot[i]] = r;
}

// ---------- weight prep: transpose + fp16; Wc2 padded to 16 cols ----------
__global__ __launch_bounds__(256) void k_wprep_all(const float* __restrict__ W1,
                                                   const float* __restrict__ W2,
                                                   const float* __restrict__ Wc1,
                                                   const float* __restrict__ Wc2,
                                                   ushort* t1h, ushort* t2h, ushort* tch,
                                                   ushort* t2ch) {
  int t = blockIdx.x * 256 + threadIdx.x;
  if (t < (64 + 128 + 384) * 128) {
    const float* W; ushort* th; int K, idx;
    if (t < 64 * 128)              { W = W1;  th = t1h; K = 64;  idx = t; }
    else if (t < (64 + 128) * 128) { W = W2;  th = t2h; K = 128; idx = t - 64 * 128; }
    else                           { W = Wc1; th = tch; K = 384; idx = t - (64 + 128) * 128; }
    int col = idx & 127;
    int k = idx >> 7;
    th[(ll)col * K + k] = f2h(W[(ll)k * 128 + col]);
  } else if (t < (64 + 128 + 384) * 128 + 16 * 128) {
    int idx = t - (64 + 128 + 384) * 128;   // 0..2047
    int col = idx >> 7;                     // 0..15
    int k = idx & 127;
    float v = (col < OC) ? Wc2[(ll)k * OC + col] : 0.f;
    t2ch[col * 128 + k] = f2h(v);
  }
}

// ---------- MFMA GEMM (f16 direct): Y[nrows][128] = X[nrows][K] @ W[K][128] ----------
// A fp16 exact, B fp16, fp32 accumulate via mfma_f32_16x16x32_f16.
// ASRC 0: X fp32 (convert in-register). ASRC 2: X fp16 (pure copy staging).
// MODE 1: Y16 = fp16( dis[row] * Y ).  MODE 4: Y16 = fp16(relu(Y+bias)).
template<int K, int ASRC, int MODE>
__global__ __launch_bounds__(256) void k_gemm(const float* __restrict__ Xf,
                                              const ushort* __restrict__ Xh16,
                                              const ushort* __restrict__ Wth,
                                              const float* __restrict__ bias,
                                              const float* __restrict__ dis,
                                              ushort* __restrict__ Y16, int nrows) {
  __shared__ ushort sA[128][40];
  __shared__ ushort sB[128][40];
  const int t = threadIdx.x;
  const int lane = t & 63;
  const int wid = t >> 6;
  const int wr = wid >> 1, wc = wid & 1;
  const int row0 = blockIdx.x * 128;

  f32x4 acc[4][4];
#pragma unroll
  for (int m = 0; m < 4; ++m)
#pragma unroll
    for (int n = 0; n < 4; ++n) acc[m][n] = (f32x4){0.f, 0.f, 0.f, 0.f};

  const int srow = t >> 1;
  const int shalf = t & 1;

  for (int kc = 0; kc < K; kc += 32) {
    __syncthreads();
    // ---- stage A tile (128 rows x 32 k) ----
    if (ASRC == 0) {
      union { ushort u[16]; short8v v[2]; } hu;
      const ll rg = row0 + srow;
      if (rg < nrows) {
        const float4* p = (const float4*)(Xf + rg * K + kc + shalf * 16);
#pragma unroll
        for (int i = 0; i < 4; ++i) {
          float4 v = p[i];
          hu.u[i * 4]     = f2h(v.x);
          hu.u[i * 4 + 1] = f2h(v.y);
          hu.u[i * 4 + 2] = f2h(v.z);
          hu.u[i * 4 + 3] = f2h(v.w);
        }
      } else {
#pragma unroll
        for (int i = 0; i < 16; ++i) hu.u[i] = 0;
      }
      *(short8v*)&sA[srow][shalf * 16] = hu.v[0];
      *(short8v*)&sA[srow][shalf * 16 + 8] = hu.v[1];
    } else {
      short8v h0 = {0,0,0,0,0,0,0,0}, h1 = h0;
      const ll rg = row0 + srow;
      if (rg < nrows) {
        const short8v* p = (const short8v*)(Xh16 + rg * K + kc + shalf * 16);
        h0 = p[0]; h1 = p[1];
      }
      *(short8v*)&sA[srow][shalf * 16] = h0;
      *(short8v*)&sA[srow][shalf * 16 + 8] = h1;
    }
    // ---- stage B tile (fp16) ----
    {
      const short8v* ph = (const short8v*)(Wth + (ll)srow * K + kc + shalf * 16);
      short8v h0 = ph[0], h1 = ph[1];
      *(short8v*)&sB[srow][shalf * 16] = h0;
      *(short8v*)&sB[srow][shalf * 16 + 8] = h1;
    }
    __syncthreads();
    const int kq = (lane >> 4) * 8;
    const int fr = lane & 15;
    f16x8 ah[4], bh[4];
#pragma unroll
    for (int m = 0; m < 4; ++m) {
      const int r = wr * 64 + m * 16 + fr;
      ah[m] = *(const f16x8*)&sA[r][kq];
    }
#pragma unroll
    for (int n = 0; n < 4; ++n) {
      const int c = wc * 64 + n * 16 + fr;
      bh[n] = *(const f16x8*)&sB[c][kq];
    }
#pragma unroll
    for (int m = 0; m < 4; ++m)
#pragma unroll
      for (int n = 0; n < 4; ++n)
        acc[m][n] = __builtin_amdgcn_mfma_f32_16x16x32_f16(ah[m], bh[n], acc[m][n], 0, 0, 0);
  }

#pragma unroll
  for (int m = 0; m < 4; ++m)
#pragma unroll
    for (int q = 0; q < 4; ++q) {
      const int rl = wr * 64 + m * 16 + (lane >> 4) * 4 + q;
      const ll rg = row0 + rl;
      if (rg >= nrows) continue;
      const float ds = (MODE == 1) ? dis[rg] : 0.f;
#pragma unroll
      for (int n = 0; n < 4; ++n) {
        const int col = wc * 64 + n * 16 + (lane & 15);
        float v = acc[m][n][q];
        if (MODE == 1) {
          Y16[rg * HC + col] = f2h(v * ds);
        } else {
          Y16[rg * HC + col] = f2h(fmaxf(v + bias[col], 0.f));
        }
      }
    }
}

// ---------- gather: quarter-wave per node, 4-deep row loads ----------
__global__ __launch_bounds__(256) void k_gather(const ushort* __restrict__ xw16,
                                                const int* __restrict__ csr,
                                                const int* __restrict__ rp,
                                                const float* __restrict__ dis,
                                                const float* __restrict__ bias,
                                                ushort* __restrict__ h16, int n) {
  const int node = blockIdx.x * 16 + (threadIdx.x >> 4);   // 16 nodes / 256-thr block
  const int lane = threadIdx.x & 63;
  const int sl = lane & 15;                                 // sublane in 16-lane group
  if (node >= n) return;
  const int s = rp[node], e = rp[node + 1];
  const int deg = e - s;

  int myidx = 0;
  if (sl < deg) myidx = csr[s + sl];

  const uint4* xwq = (const uint4*)xw16;                    // 16 uint4 per row
  uint4 sv = xwq[(ll)node * 16 + sl];                       // self term (pre-scaled)
  float a0 = h2f((ushort)(sv.x & 0xffff)), a1 = h2f((ushort)(sv.x >> 16));
  float a2 = h2f((ushort)(sv.y & 0xffff)), a3 = h2f((ushort)(sv.y >> 16));
  float a4 = h2f((ushort)(sv.z & 0xffff)), a5 = h2f((ushort)(sv.z >> 16));
  float a6 = h2f((ushort)(sv.w & 0xffff)), a7 = h2f((ushort)(sv.w >> 16));

  const int gbase = lane & 48;
  const int dfast = (deg < 16) ? deg : 16;
  int j = 0;
  for (; j + 4 <= dfast; j += 4) {                          // 4 rows in flight per group
    const int r0 = __shfl(myidx, gbase + j);
    const int r1 = __shfl(myidx, gbase + j + 1);
    const int r2 = __shfl(myidx, gbase + j + 2);
    const int r3 = __shfl(myidx, gbase + j + 3);
    const uint4 v0 = xwq[(ll)r0 * 16 + sl];
    const uint4 v1 = xwq[(ll)r1 * 16 + sl];
    const uint4 v2 = xwq[(ll)r2 * 16 + sl];
    const uint4 v3 = xwq[(ll)r3 * 16 + sl];
    a0 += (h2f((ushort)(v0.x & 0xffff)) + h2f((ushort)(v1.x & 0xffff)))
        + (h2f((ushort)(v2.x & 0xffff)) + h2f((ushort)(v3.x & 0xffff)));
    a1 += (h2f((ushort)(v0.x >> 16)) + h2f((ushort)(v1.x >> 16)))
        + (h2f((ushort)(v2.x >> 16)) + h2f((ushort)(v3.x >> 16)));
    a2 += (h2f((ushort)(v0.y & 0xffff)) + h2f((ushort)(v1.y & 0xffff)))
        + (h2f((ushort)(v2.y & 0xffff)) + h2f((ushort)(v3.y & 0xffff)));
    a3 += (h2f((ushort)(v0.y >> 16)) + h2f((ushort)(v1.y >> 16)))
        + (h2f((ushort)(v2.y >> 16)) + h2f((ushort)(v3.y >> 16)));
    a4 += (h2f((ushort)(v0.z & 0xffff)) + h2f((ushort)(v1.z & 0xffff)))
        + (h2f((ushort)(v2.z & 0xffff)) + h2f((ushort)(v3.z & 0xffff)));
    a5 += (h2f((ushort)(v0.z >> 16)) + h2f((ushort)(v1.z >> 16)))
        + (h2f((ushort)(v2.z >> 16)) + h2f((ushort)(v3.z >> 16)));
    a6 += (h2f((ushort)(v0.w & 0xffff)) + h2f((ushort)(v1.w & 0xffff)))
        + (h2f((ushort)(v2.w & 0xffff)) + h2f((ushort)(v3.w & 0xffff)));
    a7 += (h2f((ushort)(v0.w >> 16)) + h2f((ushort)(v1.w >> 16)))
        + (h2f((ushort)(v2.w >> 16)) + h2f((ushort)(v3.w >> 16)));
  }
  for (; j < dfast; ++j) {
    const int r = __shfl(myidx, gbase + j);
    const uint4 v = xwq[(ll)r * 16 + sl];
    a0 += h2f((ushort)(v.x & 0xffff)); a1 += h2f((ushort)(v.x >> 16));
    a2 += h2f((ushort)(v.y & 0xffff)); a3 += h2f((ushort)(v.y >> 16));
    a4 += h2f((ushort)(v.z & 0xffff)); a5 += h2f((ushort)(v.z >> 16));
    a6 += h2f((ushort)(v.w & 0xffff)); a7 += h2f((ushort)(v.w >> 16));
  }
  for (j = 16; j < deg; ++j) {                              // rare spill (deg > 16)
    const uint4 v = xwq[(ll)csr[s + j] * 16 + sl];
    a0 += h2f((ushort)(v.x & 0xffff)); a1 += h2f((ushort)(v.x >> 16));
    a2 += h2f((ushort)(v.y & 0xffff)); a3 += h2f((ushort)(v.y >> 16));
    a4 += h2f((ushort)(v.z & 0xffff)); a5 += h2f((ushort)(v.z >> 16));
    a6 += h2f((ushort)(v.w & 0xffff)); a7 += h2f((ushort)(v.w >> 16));
  }

  const float dc = dis[node];
  const float4* bias4 = (const float4*)bias;
  const float4 b0 = bias4[sl * 2];
  const float4 b1 = bias4[sl * 2 + 1];
  uint4 o;
  o.x = (uint)f2h(fmaxf(fmaf(dc, a0, b0.x), 0.f)) | ((uint)f2h(fmaxf(fmaf(dc, a1, b0.y), 0.f)) << 16);
  o.y = (uint)f2h(fmaxf(fmaf(dc, a2, b0.z), 0.f)) | ((uint)f2h(fmaxf(fmaf(dc, a3, b0.w), 0.f)) << 16);
  o.z = (uint)f2h(fmaxf(fmaf(dc, a4, b1.x), 0.f)) | ((uint)f2h(fmaxf(fmaf(dc, a5, b1.y), 0.f)) << 16);
  o.w = (uint)f2h(fmaxf(fmaf(dc, a6, b1.z), 0.f)) | ((uint)f2h(fmaxf(fmaf(dc, a7, b1.w), 0.f)) << 16);
  ((uint4*)h16)[(ll)node * 16 + sl] = o;
}

// ---------- MFMA head (f16 direct): logits = z16 @ Wc2 + bc2 ; out = log_softmax ----------
__global__ __launch_bounds__(256) void k_head_mfma(const ushort* __restrict__ Z16,
                                                   const ushort* __restrict__ Wth,
                                                   const float* __restrict__ bc2,
                                                   float* __restrict__ out, int nrows) {
  __shared__ ushort sZ[128][40];
  __shared__ ushort sW[16][132];
  __shared__ float ob[128 * OC];
  const int t = threadIdx.x;
  const int lane = t & 63;
  const int wid = t >> 6;
  const int row0 = blockIdx.x * 128;

  {
    const int col = t >> 4;
    const int k0 = (t & 15) * 8;
    *(short8v*)&sW[col][k0] = *(const short8v*)(Wth + col * 128 + k0);
  }

  f32x4 acc[2];
  acc[0] = (f32x4){0.f, 0.f, 0.f, 0.f};
  acc[1] = (f32x4){0.f, 0.f, 0.f, 0.f};

  const int srow = t >> 1;
  const int shalf = t & 1;

  for (int kc = 0; kc < HC; kc += 32) {
    __syncthreads();
    {
      short8v h0 = {0,0,0,0,0,0,0,0}, h1 = h0;
      const ll rg = row0 + srow;
      if (rg < nrows) {
        const short8v* p = (const short8v*)(Z16 + rg * HC + kc + shalf * 16);
        h0 = p[0]; h1 = p[1];
      }
      *(short8v*)&sZ[srow][shalf * 16] = h0;
      *(short8v*)&sZ[srow][shalf * 16 + 8] = h1;
    }
    __syncthreads();
    const int kq = (lane >> 4) * 8;
    const int fr = lane & 15;
    const f16x8 bh = *(const f16x8*)&sW[fr][kc + kq];
#pragma unroll
    for (int mt = 0; mt < 2; ++mt) {
      const int r = wid * 32 + mt * 16 + fr;
      const f16x8 ah = *(const f16x8*)&sZ[r][kq];
      acc[mt] = __builtin_amdgcn_mfma_f32_16x16x32_f16(ah, bh, acc[mt], 0, 0, 0);
    }
  }

  const int fr = lane & 15;
  const float bcv = (fr < OC) ? bc2[fr] : -1e30f;
#pragma unroll
  for (int mt = 0; mt < 2; ++mt)
#pragma unroll
    for (int q = 0; q < 4; ++q) {
      float a = acc[mt][q] + bcv;
      float mx = a;
#pragma unroll
      for (int m = 8; m; m >>= 1) mx = fmaxf(mx, __shfl_xor(mx, m, 64));
      float ex = expf(a - mx);
#pragma unroll
      for (int m = 8; m; m >>= 1) ex += __shfl_xor(ex, m, 64);
      const float res = a - mx - logf(ex);
      const int rl = wid * 32 + mt * 16 + (lane >> 4) * 4 + q;
      if (fr < OC) ob[rl * OC + fr] = res;
    }
  __syncthreads();
  const int rem = nrows - row0;
  const int cnt = ((rem < 128) ? rem : 128) * OC;
  for (int i = t; i < cnt; i += 256) out[(ll)row0 * OC + i] = ob[i];
}

extern "C" void kernel_launch(void* const* d_in, const int* in_sizes, int n_in,
                              void* d_out, int out_size, void* d_ws, size_t ws_size,
                              hipStream_t stream) {
  const float* x   = (const float*)d_in[0];
  const int*   ei  = (const int*)d_in[1];   // [2][E] int32
  const float* W1  = (const float*)d_in[2];
  const float* b1  = (const float*)d_in[3];
  const float* W2  = (const float*)d_in[4];
  const float* b2  = (const float*)d_in[5];
  const float* Wc1 = (const float*)d_in[6];
  const float* bc1 = (const float*)d_in[7];
  const float* Wc2 = (const float*)d_in[8];
  const float* bc2 = (const float*)d_in[9];
  float* out = (float*)d_out;

  char* ws = (char*)d_ws;
  ushort* xw16 = (ushort*)(ws);                       // xw' fp16 [N][128] 38.4MB ; later z16 [BSZ][128]
  ushort* h16  = (ushort*)(ws + 38400000LL);          // h   fp16 [N][128] 38.4MB
  const ll CSRB = 76800000LL;
  float* dis  = (float*)(ws + CSRB);                  // N floats
  int*   rp   = (int*)  (ws + CSRB + 600064LL);       // N+1
  int*   csr  = (int*)  (ws + CSRB + 1200128LL);      // E
  int*   cnt  = (int*)  (ws + CSRB + 3600128LL);      // 150016
  int*   slot = (int*)  (ws + CSRB + 4200192LL);      // E
  int*   bsum = (int*)  (ws + CSRB + 6600192LL);      // 256
  ushort* Wt1h  = (ushort*)(ws + CSRB + 6601216LL);   // 64*128
  ushort* Wt2h  = (ushort*)(ws + CSRB + 6617600LL);   // 128*128
  ushort* Wtc1h = (ushort*)(ws + CSRB + 6650368LL);   // 384*128
  ushort* Wtc2h = (ushort*)(ws + CSRB + 6748672LL);   // 16*128 ; end ~83.5MB

  const int nb = (NN + 1023) / 1024;

  // CSR build
  k_zero_i<<<(150016 + 255) / 256, 256, 0, stream>>>(cnt, 150016);
  k_count<<<(EE + 255) / 256, 256, 0, stream>>>(ei + EE, cnt, slot, EE);
  k_scan1<<<nb, 256, 0, stream>>>(cnt, rp, bsum, dis, NN);
  k_scan2<<<1, 256, 0, stream>>>(bsum, nb);
  k_scan3<<<nb, 256, 0, stream>>>(rp, bsum, NN, EE);
  k_fill_csr<<<(EE + 255) / 256, 256, 0, stream>>>(ei, rp, slot, csr, EE);

  // weight transpose + fp16
  k_wprep_all<<<((64 + 128 + 384 + 16) * 128 + 255) / 256, 256, 0, stream>>>(
      W1, W2, Wc1, Wc2, Wt1h, Wt2h, Wtc1h, Wtc2h);

  // layer 1: xw' = fp16(dis.row * (x @ W1))
  k_gemm<INC, 0, 1><<<(NN + 127) / 128, 256, 0, stream>>>(x, nullptr, Wt1h, nullptr, dis, xw16, NN);
  k_gather<<<(NN + 15) / 16, 256, 0, stream>>>(xw16, csr, rp, dis, b1, h16, NN);

  // layer 2: xw' = fp16(dis.row * (h @ W2))
  k_gemm<HC, 2, 1><<<(NN + 127) / 128, 256, 0, stream>>>(nullptr, h16, Wt2h, nullptr, dis, xw16, NN);
  k_gather<<<(NN + 15) / 16, 256, 0, stream>>>(xw16, csr, rp, dis, b2, h16, NN);

  // classifier: z16 = fp16(relu(flat @ Wc1 + bc1)), flat = h16 viewed [BSZ][384]; z16 reuses xw16
  k_gemm<3 * HC, 2, 4><<<(BSZ + 127) / 128, 256, 0, stream>>>(nullptr, h16, Wtc1h, bc1, nullptr, xw16, BSZ);

  // head: out = log_softmax(z16 @ Wc2 + bc2)
  k_head_mfma<<<(BSZ + 127) / 128, 256, 0, stream>>>(xw16, Wtc2h, bc2, out, BSZ);
}

// Round 11
// 183.916 us; speedup vs baseline: 16.8526x; 1.0320x over previous
//
#include <hip/hip_runtime.h>

#define NN 150000
#define EE 600000
#define INC 64
#define HC 128
#define OC 10
#define BSZ 50000

typedef long long ll;
typedef _Float16 f16;
typedef __attribute__((ext_vector_type(8))) short short8v;
typedef __attribute__((ext_vector_type(8))) _Float16 f16x8;
typedef __attribute__((ext_vector_type(4))) float f32x4;

__device__ __forceinline__ float h2f(ushort u) {
  f16 h;
  __builtin_memcpy(&h, &u, 2);
  return (float)h;
}
__device__ __forceinline__ ushort f2h(float f) {
  f16 h = (f16)f;
  ushort u;
  __builtin_memcpy(&u, &h, 2);
  return u;
}

// ---------- merged: zero cnt + weight prep (fp16 transpose; Wc2 padded to 16 cols) ----------
__global__ __launch_bounds__(256) void k_prep(const float* __restrict__ W1,
                                              const float* __restrict__ W2,
                                              const float* __restrict__ Wc1,
                                              const float* __restrict__ Wc2,
                                              ushort* t1h, ushort* t2h, ushort* tch,
                                              ushort* t2ch, int* cnt) {
  int t = blockIdx.x * 256 + threadIdx.x;
  if (t < 150016) { cnt[t] = 0; return; }
  t -= 150016;
  if (t < (64 + 128 + 384) * 128) {
    const float* W; ushort* th; int K, idx;
    if (t < 64 * 128)              { W = W1;  th = t1h; K = 64;  idx = t; }
    else if (t < (64 + 128) * 128) { W = W2;  th = t2h; K = 128; idx = t - 64 * 128; }
    else                           { W = Wc1; th = tch; K = 384; idx = t - (64 + 128) * 128; }
    int col = idx & 127;
    int k = idx >> 7;
    th[(ll)col * K + k] = f2h(W[(ll)k * 128 + col]);
  } else if (t < (64 + 128 + 384) * 128 + 16 * 128) {
    int idx = t - (64 + 128 + 384) * 128;   // 0..2047
    int col = idx >> 7;                     // 0..15
    int k = idx & 127;
    float v = (col < OC) ? Wc2[(ll)k * OC + col] : 0.f;
    t2ch[col * 128 + k] = f2h(v);
  }
}

// count + per-edge slot in one pass (slot write coalesced)
__global__ __launch_bounds__(256) void k_count(const int* __restrict__ col, int* cnt,
                                               int* __restrict__ slot, int e) {
  int i = blockIdx.x * 256 + threadIdx.x;
  if (i < e) slot[i] = atomicAdd(&cnt[col[i]], 1);
}

__global__ __launch_bounds__(256) void k_scan1(const int* __restrict__ cnt, int* ex, int* bsum,
                                               float* __restrict__ dis, int n) {
  __shared__ int s[256];
  const int t = threadIdx.x;
  const int base = blockIdx.x * 1024 + t * 4;
  int v[4], tot = 0;
#pragma unroll
  for (int i = 0; i < 4; ++i) {
    v[i] = (base + i < n) ? cnt[base + i] : 0;
    tot += v[i];
    if (base + i < n) dis[base + i] = rsqrtf((float)(1 + v[i]));
  }
  s[t] = tot;
  __syncthreads();
#pragma unroll
  for (int off = 1; off < 256; off <<= 1) {
    int x = (t >= off) ? s[t - off] : 0;
    __syncthreads();
    s[t] += x;
    __syncthreads();
  }
  int run = s[t] - tot;
#pragma unroll
  for (int i = 0; i < 4; ++i) {
    if (base + i < n) ex[base + i] = run;
    run += v[i];
  }
  if (t == 255) bsum[blockIdx.x] = s[255];
}

// merged scan2+scan3: each block scans all block-sums in LDS, adds its exclusive prefix
__global__ __launch_bounds__(256) void k_scan23(int* rp, const int* __restrict__ bsum,
                                                int n, int e, int nb) {
  __shared__ int s[256];
  const int t = threadIdx.x;
  int v = (t < nb) ? bsum[t] : 0;
  s[t] = v;
  __syncthreads();
#pragma unroll
  for (int off = 1; off < 256; off <<= 1) {
    int x = (t >= off) ? s[t - off] : 0;
    __syncthreads();
    s[t] += x;
    __syncthreads();
  }
  const int off = (blockIdx.x == 0) ? 0 : s[blockIdx.x - 1];  // exclusive prefix of this block
  const int base = blockIdx.x * 1024 + t * 4;
#pragma unroll
  for (int i = 0; i < 4; ++i)
    if (base + i < n) rp[base + i] += off;
  if (blockIdx.x == 0 && t == 0) rp[n] = e;
}

// csr[rp[c] + slot[i]] = row  (no atomic: slot precomputed)
__global__ __launch_bounds__(256) void k_fill_csr(const int* __restrict__ ei,
                                                  const int* __restrict__ rp,
                                                  const int* __restrict__ slot,
                                                  int* csr, int e) {
  int i = blockIdx.x * 256 + threadIdx.x;
  if (i >= e) return;
  int r = ei[i];
  int c = ei[EE + i];
  csr[rp[c] + slot[i]] = r;
}

// ---------- MFMA GEMM (f16 direct): Y[nrows][128] = X[nrows][K] @ W[K][128] ----------
// A fp16 exact, B fp16, fp32 accumulate via mfma_f32_16x16x32_f16.
// ASRC 0: X fp32 (convert in-register). ASRC 2: X fp16 (pure copy staging).
// MODE 1: Y16 = fp16( dis[row] * Y ).  MODE 4: Y16 = fp16(relu(Y+bias)).
template<int K, int ASRC, int MODE>
__global__ __launch_bounds__(256) void k_gemm(const float* __restrict__ Xf,
                                              const ushort* __restrict__ Xh16,
                                              const ushort* __restrict__ Wth,
                                              const float* __restrict__ bias,
                                              const float* __restrict__ dis,
                                              ushort* __restrict__ Y16, int nrows) {
  __shared__ ushort sA[128][40];
  __shared__ ushort sB[128][40];
  const int t = threadIdx.x;
  const int lane = t & 63;
  const int wid = t >> 6;
  const int wr = wid >> 1, wc = wid & 1;
  const int row0 = blockIdx.x * 128;

  f32x4 acc[4][4];
#pragma unroll
  for (int m = 0; m < 4; ++m)
#pragma unroll
    for (int n = 0; n < 4; ++n) acc[m][n] = (f32x4){0.f, 0.f, 0.f, 0.f};

  const int srow = t >> 1;
  const int shalf = t & 1;

  for (int kc = 0; kc < K; kc += 32) {
    __syncthreads();
    // ---- stage A tile (128 rows x 32 k) ----
    if (ASRC == 0) {
      union { ushort u[16]; short8v v[2]; } hu;
      const ll rg = row0 + srow;
      if (rg < nrows) {
        const float4* p = (const float4*)(Xf + rg * K + kc + shalf * 16);
#pragma unroll
        for (int i = 0; i < 4; ++i) {
          float4 v = p[i];
          hu.u[i * 4]     = f2h(v.x);
          hu.u[i * 4 + 1] = f2h(v.y);
          hu.u[i * 4 + 2] = f2h(v.z);
          hu.u[i * 4 + 3] = f2h(v.w);
        }
      } else {
#pragma unroll
        for (int i = 0; i < 16; ++i) hu.u[i] = 0;
      }
      *(short8v*)&sA[srow][shalf * 16] = hu.v[0];
      *(short8v*)&sA[srow][shalf * 16 + 8] = hu.v[1];
    } else {
      short8v h0 = {0,0,0,0,0,0,0,0}, h1 = h0;
      const ll rg = row0 + srow;
      if (rg < nrows) {
        const short8v* p = (const short8v*)(Xh16 + rg * K + kc + shalf * 16);
        h0 = p[0]; h1 = p[1];
      }
      *(short8v*)&sA[srow][shalf * 16] = h0;
      *(short8v*)&sA[srow][shalf * 16 + 8] = h1;
    }
    // ---- stage B tile (fp16) ----
    {
      const short8v* ph = (const short8v*)(Wth + (ll)srow * K + kc + shalf * 16);
      short8v h0 = ph[0], h1 = ph[1];
      *(short8v*)&sB[srow][shalf * 16] = h0;
      *(short8v*)&sB[srow][shalf * 16 + 8] = h1;
    }
    __syncthreads();
    const int kq = (lane >> 4) * 8;
    const int fr = lane & 15;
    f16x8 ah[4], bh[4];
#pragma unroll
    for (int m = 0; m < 4; ++m) {
      const int r = wr * 64 + m * 16 + fr;
      ah[m] = *(const f16x8*)&sA[r][kq];
    }
#pragma unroll
    for (int n = 0; n < 4; ++n) {
      const int c = wc * 64 + n * 16 + fr;
      bh[n] = *(const f16x8*)&sB[c][kq];
    }
#pragma unroll
    for (int m = 0; m < 4; ++m)
#pragma unroll
      for (int n = 0; n < 4; ++n)
        acc[m][n] = __builtin_amdgcn_mfma_f32_16x16x32_f16(ah[m], bh[n], acc[m][n], 0, 0, 0);
  }

#pragma unroll
  for (int m = 0; m < 4; ++m)
#pragma unroll
    for (int q = 0; q < 4; ++q) {
      const int rl = wr * 64 + m * 16 + (lane >> 4) * 4 + q;
      const ll rg = row0 + rl;
      if (rg >= nrows) continue;
      const float ds = (MODE == 1) ? dis[rg] : 0.f;
#pragma unroll
      for (int n = 0; n < 4; ++n) {
        const int col = wc * 64 + n * 16 + (lane & 15);
        float v = acc[m][n][q];
        if (MODE == 1) {
          Y16[rg * HC + col] = f2h(v * ds);
        } else {
          Y16[rg * HC + col] = f2h(fmaxf(v + bias[col], 0.f));
        }
      }
    }
}

// ---------- gather: quarter-wave per node; always-4-wide loads with self-row dummies ----------
// Dummy lanes (>= deg) point at the node's own row (L1-hot); the ndum spurious self-adds
// are subtracted exactly at the end. Removes the serial remainder loop for deg%4 != 0.
__global__ __launch_bounds__(256) void k_gather(const ushort* __restrict__ xw16,
                                                const int* __restrict__ csr,
                                                const int* __restrict__ rp,
                                                const float* __restrict__ dis,
                                                const float* __restrict__ bias,
                                                ushort* __restrict__ h16, int n) {
  const int node = blockIdx.x * 16 + (threadIdx.x >> 4);   // 16 nodes / 256-thr block
  const int lane = threadIdx.x & 63;
  const int sl = lane & 15;                                 // sublane in 16-lane group
  if (node >= n) return;
  const int s = rp[node], e = rp[node + 1];
  const int deg = e - s;

  int myidx = node;                       // dummy index = self row (corrected below)
  if (sl < deg) myidx = csr[s + sl];

  const uint4* xwq = (const uint4*)xw16;                    // 16 uint4 per row
  const uint4 sv = xwq[(ll)node * 16 + sl];                 // self term (pre-scaled)
  float a0 = h2f((ushort)(sv.x & 0xffff)), a1 = h2f((ushort)(sv.x >> 16));
  float a2 = h2f((ushort)(sv.y & 0xffff)), a3 = h2f((ushort)(sv.y >> 16));
  float a4 = h2f((ushort)(sv.z & 0xffff)), a5 = h2f((ushort)(sv.z >> 16));
  float a6 = h2f((ushort)(sv.w & 0xffff)), a7 = h2f((ushort)(sv.w >> 16));

  const int gbase = lane & 48;
  const int dfast = (deg < 16) ? deg : 16;
  const int nblk = (dfast + 3) >> 2;
  int j = 0;
  for (int b = 0; b < nblk; ++b, j += 4) {                  // 4 rows always in flight
    const int r0 = __shfl(myidx, gbase + j);
    const int r1 = __shfl(myidx, gbase + j + 1);
    const int r2 = __shfl(myidx, gbase + j + 2);
    const int r3 = __shfl(myidx, gbase + j + 3);
    const uint4 v0 = xwq[(ll)r0 * 16 + sl];
    const uint4 v1 = xwq[(ll)r1 * 16 + sl];
    const uint4 v2 = xwq[(ll)r2 * 16 + sl];
    const uint4 v3 = xwq[(ll)r3 * 16 + sl];
    a0 += (h2f((ushort)(v0.x & 0xffff)) + h2f((ushort)(v1.x & 0xffff)))
        + (h2f((ushort)(v2.x & 0xffff)) + h2f((ushort)(v3.x & 0xffff)));
    a1 += (h2f((ushort)(v0.x >> 16)) + h2f((ushort)(v1.x >> 16)))
        + (h2f((ushort)(v2.x >> 16)) + h2f((ushort)(v3.x >> 16)));
    a2 += (h2f((ushort)(v0.y & 0xffff)) + h2f((ushort)(v1.y & 0xffff)))
        + (h2f((ushort)(v2.y & 0xffff)) + h2f((ushort)(v3.y & 0xffff)));
    a3 += (h2f((ushort)(v0.y >> 16)) + h2f((ushort)(v1.y >> 16)))
        + (h2f((ushort)(v2.y >> 16)) + h2f((ushort)(v3.y >> 16)));
    a4 += (h2f((ushort)(v0.z & 0xffff)) + h2f((ushort)(v1.z & 0xffff)))
        + (h2f((ushort)(v2.z & 0xffff)) + h2f((ushort)(v3.z & 0xffff)));
    a5 += (h2f((ushort)(v0.z >> 16)) + h2f((ushort)(v1.z >> 16)))
        + (h2f((ushort)(v2.z >> 16)) + h2f((ushort)(v3.z >> 16)));
    a6 += (h2f((ushort)(v0.w & 0xffff)) + h2f((ushort)(v1.w & 0xffff)))
        + (h2f((ushort)(v2.w & 0xffff)) + h2f((ushort)(v3.w & 0xffff)));
    a7 += (h2f((ushort)(v0.w >> 16)) + h2f((ushort)(v1.w >> 16)))
        + (h2f((ushort)(v2.w >> 16)) + h2f((ushort)(v3.w >> 16)));
  }
  const int ndum = (nblk << 2) - dfast;                     // spurious self-adds
  if (ndum) {
    const float nd = -(float)ndum;
    a0 = fmaf(nd, h2f((ushort)(sv.x & 0xffff)), a0);
    a1 = fmaf(nd, h2f((ushort)(sv.x >> 16)), a1);
    a2 = fmaf(nd, h2f((ushort)(sv.y & 0xffff)), a2);
    a3 = fmaf(nd, h2f((ushort)(sv.y >> 16)), a3);
    a4 = fmaf(nd, h2f((ushort)(sv.z & 0xffff)), a4);
    a5 = fmaf(nd, h2f((ushort)(sv.z >> 16)), a5);
    a6 = fmaf(nd, h2f((ushort)(sv.w & 0xffff)), a6);
    a7 = fmaf(nd, h2f((ushort)(sv.w >> 16)), a7);
  }
  for (j = 16; j < deg; ++j) {                              // rare spill (deg > 16)
    const uint4 v = xwq[(ll)csr[s + j] * 16 + sl];
    a0 += h2f((ushort)(v.x & 0xffff)); a1 += h2f((ushort)(v.x >> 16));
    a2 += h2f((ushort)(v.y & 0xffff)); a3 += h2f((ushort)(v.y >> 16));
    a4 += h2f((ushort)(v.z & 0xffff)); a5 += h2f((ushort)(v.z >> 16));
    a6 += h2f((ushort)(v.w & 0xffff)); a7 += h2f((ushort)(v.w >> 16));
  }

  const float dc = dis[node];
  const float4* bias4 = (const float4*)bias;
  const float4 b0 = bias4[sl * 2];
  const float4 b1 = bias4[sl * 2 + 1];
  uint4 o;
  o.x = (uint)f2h(fmaxf(fmaf(dc, a0, b0.x), 0.f)) | ((uint)f2h(fmaxf(fmaf(dc, a1, b0.y), 0.f)) << 16);
  o.y = (uint)f2h(fmaxf(fmaf(dc, a2, b0.z), 0.f)) | ((uint)f2h(fmaxf(fmaf(dc, a3, b0.w), 0.f)) << 16);
  o.z = (uint)f2h(fmaxf(fmaf(dc, a4, b1.x), 0.f)) | ((uint)f2h(fmaxf(fmaf(dc, a5, b1.y), 0.f)) << 16);
  o.w = (uint)f2h(fmaxf(fmaf(dc, a6, b1.z), 0.f)) | ((uint)f2h(fmaxf(fmaf(dc, a7, b1.w), 0.f)) << 16);
  ((uint4*)h16)[(ll)node * 16 + sl] = o;
}

// ---------- MFMA head (f16 direct): logits = z16 @ Wc2 + bc2 ; out = log_softmax ----------
__global__ __launch_bounds__(256) void k_head_mfma(const ushort* __restrict__ Z16,
                                                   const ushort* __restrict__ Wth,
                                                   const float* __restrict__ bc2,
                                                   float* __restrict__ out, int nrows) {
  __shared__ ushort sZ[128][40];
  __shared__ ushort sW[16][132];
  __shared__ float ob[128 * OC];
  const int t = threadIdx.x;
  const int lane = t & 63;
  const int wid = t >> 6;
  const int row0 = blockIdx.x * 128;

  {
    const int col = t >> 4;
    const int k0 = (t & 15) * 8;
    *(short8v*)&sW[col][k0] = *(const short8v*)(Wth + col * 128 + k0);
  }

  f32x4 acc[2];
  acc[0] = (f32x4){0.f, 0.f, 0.f, 0.f};
  acc[1] = (f32x4){0.f, 0.f, 0.f, 0.f};

  const int srow = t >> 1;
  const int shalf = t & 1;

  for (int kc = 0; kc < HC; kc += 32) {
    __syncthreads();
    {
      short8v h0 = {0,0,0,0,0,0,0,0}, h1 = h0;
      const ll rg = row0 + srow;
      if (rg < nrows) {
        const short8v* p = (const short8v*)(Z16 + rg * HC + kc + shalf * 16);
        h0 = p[0]; h1 = p[1];
      }
      *(short8v*)&sZ[srow][shalf * 16] = h0;
      *(short8v*)&sZ[srow][shalf * 16 + 8] = h1;
    }
    __syncthreads();
    const int kq = (lane >> 4) * 8;
    const int fr = lane & 15;
    const f16x8 bh = *(const f16x8*)&sW[fr][kc + kq];
#pragma unroll
    for (int mt = 0; mt < 2; ++mt) {
      const int r = wid * 32 + mt * 16 + fr;
      const f16x8 ah = *(const f16x8*)&sZ[r][kq];
      acc[mt] = __builtin_amdgcn_mfma_f32_16x16x32_f16(ah, bh, acc[mt], 0, 0, 0);
    }
  }

  const int fr = lane & 15;
  const float bcv = (fr < OC) ? bc2[fr] : -1e30f;
#pragma unroll
  for (int mt = 0; mt < 2; ++mt)
#pragma unroll
    for (int q = 0; q < 4; ++q) {
      float a = acc[mt][q] + bcv;
      float mx = a;
#pragma unroll
      for (int m = 8; m; m >>= 1) mx = fmaxf(mx, __shfl_xor(mx, m, 64));
      float ex = expf(a - mx);
#pragma unroll
      for (int m = 8; m; m >>= 1) ex += __shfl_xor(ex, m, 64);
      const float res = a - mx - logf(ex);
      const int rl = wid * 32 + mt * 16 + (lane >> 4) * 4 + q;
      if (fr < OC) ob[rl * OC + fr] = res;
    }
  __syncthreads();
  const int rem = nrows - row0;
  const int cnt = ((rem < 128) ? rem : 128) * OC;
  for (int i = t; i < cnt; i += 256) out[(ll)row0 * OC + i] = ob[i];
}

extern "C" void kernel_launch(void* const* d_in, const int* in_sizes, int n_in,
                              void* d_out, int out_size, void* d_ws, size_t ws_size,
                              hipStream_t stream) {
  const float* x   = (const float*)d_in[0];
  const int*   ei  = (const int*)d_in[1];   // [2][E] int32
  const float* W1  = (const float*)d_in[2];
  const float* b1  = (const float*)d_in[3];
  const float* W2  = (const float*)d_in[4];
  const float* b2  = (const float*)d_in[5];
  const float* Wc1 = (const float*)d_in[6];
  const float* bc1 = (const float*)d_in[7];
  const float* Wc2 = (const float*)d_in[8];
  const float* bc2 = (const float*)d_in[9];
  float* out = (float*)d_out;

  char* ws = (char*)d_ws;
  ushort* xw16 = (ushort*)(ws);                       // xw' fp16 [N][128] 38.4MB ; later z16 [BSZ][128]
  ushort* h16  = (ushort*)(ws + 38400000LL);          // h   fp16 [N][128] 38.4MB
  const ll CSRB = 76800000LL;
  float* dis  = (float*)(ws + CSRB);                  // N floats
  int*   rp   = (int*)  (ws + CSRB + 600064LL);       // N+1
  int*   csr  = (int*)  (ws + CSRB + 1200128LL);      // E
  int*   cnt  = (int*)  (ws + CSRB + 3600128LL);      // 150016
  int*   slot = (int*)  (ws + CSRB + 4200192LL);      // E
  int*   bsum = (int*)  (ws + CSRB + 6600192LL);      // 256
  ushort* Wt1h  = (ushort*)(ws + CSRB + 6601216LL);   // 64*128
  ushort* Wt2h  = (ushort*)(ws + CSRB + 6617600LL);   // 128*128
  ushort* Wtc1h = (ushort*)(ws + CSRB + 6650368LL);   // 384*128
  ushort* Wtc2h = (ushort*)(ws + CSRB + 6748672LL);   // 16*128 ; end ~83.5MB

  const int nb = (NN + 1023) / 1024;                  // 147 scan blocks

  // prep (zero cnt + weight transpose) ; CSR build
  k_prep<<<(150016 + (64 + 128 + 384 + 16) * 128 + 255) / 256, 256, 0, stream>>>(
      W1, W2, Wc1, Wc2, Wt1h, Wt2h, Wtc1h, Wtc2h, cnt);
  k_count<<<(EE + 255) / 256, 256, 0, stream>>>(ei + EE, cnt, slot, EE);
  k_scan1<<<nb, 256, 0, stream>>>(cnt, rp, bsum, dis, NN);
  k_scan23<<<nb, 256, 0, stream>>>(rp, bsum, NN, EE, nb);
  k_fill_csr<<<(EE + 255) / 256, 256, 0, stream>>>(ei, rp, slot, csr, EE);

  // layer 1: xw' = fp16(dis.row * (x @ W1))
  k_gemm<INC, 0, 1><<<(NN + 127) / 128, 256, 0, stream>>>(x, nullptr, Wt1h, nullptr, dis, xw16, NN);
  k_gather<<<(NN + 15) / 16, 256, 0, stream>>>(xw16, csr, rp, dis, b1, h16, NN);

  // layer 2: xw' = fp16(dis.row * (h @ W2))
  k_gemm<HC, 2, 1><<<(NN + 127) / 128, 256, 0, stream>>>(nullptr, h16, Wt2h, nullptr, dis, xw16, NN);
  k_gather<<<(NN + 15) / 16, 256, 0, stream>>>(xw16, csr, rp, dis, b2, h16, NN);

  // classifier: z16 = fp16(relu(flat @ Wc1 + bc1)), flat = h16 viewed [BSZ][384]; z16 reuses xw16
  k_gemm<3 * HC, 2, 4><<<(BSZ + 127) / 128, 256, 0, stream>>>(nullptr, h16, Wtc1h, bc1, nullptr, xw16, BSZ);

  // head: out = log_softmax(z16 @ Wc2 + bc2)
  k_head_mfma<<<(BSZ + 127) / 128, 256, 0, stream>>>(xw16, Wtc2h, bc2, out, BSZ);
}